// Round 1
// baseline (8490.674 us; speedup 1.0000x reference)
//
#include <hip/hip_runtime.h>

#define B_   32
#define NV_  512
#define NL_  256
#define D_   1024
#define H_   4096
#define KTOT (NL_ + NV_)   // 768
#define SCALE_ (0.03125f)  // 1/sqrt(1024)

#define BM 128
#define BN 128
#define BK 16
#define AT_STRIDE (BM + 4)   // padded to break bank conflicts on transpose writes
#define BS_STRIDE (BN + 4)

// ---------------------------------------------------------------------------
// Generic 128x128x16 fp32 tiled GEMM, 256 threads, 8x8 register blocking.
// BLAY: 0 -> B is [K,N] row-major (ldb = N stride)
//       1 -> B is [N,K] row-major (ldb = K stride), i.e. C = A @ B^T
// EPI:  0 -> C = relu(acc + bias[n])
//       1 -> C = acc + bias[n]
//       2 -> C = acc * scale
// All of M, N multiples of 128; K multiple of 16. No bounds checks.
// ---------------------------------------------------------------------------
template<int BLAY, int EPI>
__global__ __launch_bounds__(256, 2)
void gemm128(const float* __restrict__ Ap, long sAz, int lda,
             const float* __restrict__ Bp, long sBz, int ldb,
             const float* __restrict__ bias,
             float* __restrict__ Cp, long sCz, int ldc,
             int K, float scale)
{
    __shared__ float At[BK][AT_STRIDE];   // A transposed: At[k][m]
    __shared__ float Bs[BK][BS_STRIDE];   // Bs[k][n]

    const int tid = threadIdx.x;
    const int tx = tid & 15;        // output col group (tx*8)
    const int ty = tid >> 4;        // output row group (ty*8)
    const int n0 = blockIdx.x * BN;
    const int m0 = blockIdx.y * BM;
    const int z  = blockIdx.z;

    const float* A = Ap + (long)z * sAz;
    const float* Bb = Bp + (long)z * sBz;
    float* C = Cp + (long)z * sCz;

    float acc[8][8];
#pragma unroll
    for (int i = 0; i < 8; ++i)
#pragma unroll
        for (int j = 0; j < 8; ++j) acc[i][j] = 0.f;

    const int ar = tid >> 2;          // 0..63   (row within 64-row pass)
    const int ac = (tid & 3) * 4;     // 0,4,8,12 (k-col within tile)
    const int bk = tid >> 5;          // 0..7
    const int bc = (tid & 31) * 4;    // 0..124

    for (int k0 = 0; k0 < K; k0 += BK) {
        // ---- stage A tile (transposed into LDS) ----
#pragma unroll
        for (int p = 0; p < 2; ++p) {
            const int r = p * 64 + ar;
            const float4 v = *(const float4*)(A + (long)(m0 + r) * lda + (k0 + ac));
            At[ac + 0][r] = v.x; At[ac + 1][r] = v.y;
            At[ac + 2][r] = v.z; At[ac + 3][r] = v.w;
        }
        // ---- stage B tile ----
        if (BLAY == 0) {
#pragma unroll
            for (int p = 0; p < 2; ++p) {
                const int kk = p * 8 + bk;
                *(float4*)&Bs[kk][bc] =
                    *(const float4*)(Bb + (long)(k0 + kk) * ldb + (n0 + bc));
            }
        } else {
#pragma unroll
            for (int p = 0; p < 2; ++p) {
                const int r = p * 64 + ar;   // n index
                const float4 v = *(const float4*)(Bb + (long)(n0 + r) * ldb + (k0 + ac));
                Bs[ac + 0][r] = v.x; Bs[ac + 1][r] = v.y;
                Bs[ac + 2][r] = v.z; Bs[ac + 3][r] = v.w;
            }
        }
        __syncthreads();

#pragma unroll
        for (int k = 0; k < BK; ++k) {
            const float4 a0 = *(const float4*)&At[k][ty * 8];
            const float4 a1 = *(const float4*)&At[k][ty * 8 + 4];
            const float4 b0 = *(const float4*)&Bs[k][tx * 8];
            const float4 b1 = *(const float4*)&Bs[k][tx * 8 + 4];
            const float a[8] = {a0.x, a0.y, a0.z, a0.w, a1.x, a1.y, a1.z, a1.w};
            const float b[8] = {b0.x, b0.y, b0.z, b0.w, b1.x, b1.y, b1.z, b1.w};
#pragma unroll
            for (int i = 0; i < 8; ++i)
#pragma unroll
                for (int j = 0; j < 8; ++j)
                    acc[i][j] = fmaf(a[i], b[j], acc[i][j]);
        }
        __syncthreads();
    }

    // ---- epilogue ----
#pragma unroll
    for (int i = 0; i < 8; ++i) {
        const int row = m0 + ty * 8 + i;
#pragma unroll
        for (int j = 0; j < 8; j += 4) {
            const int col = n0 + tx * 8 + j;
            float4 v;
            v.x = acc[i][j + 0]; v.y = acc[i][j + 1];
            v.z = acc[i][j + 2]; v.w = acc[i][j + 3];
            if (EPI == 0 || EPI == 1) {
                const float4 bv = *(const float4*)(bias + col);
                v.x += bv.x; v.y += bv.y; v.z += bv.z; v.w += bv.w;
                if (EPI == 0) {
                    v.x = fmaxf(v.x, 0.f); v.y = fmaxf(v.y, 0.f);
                    v.z = fmaxf(v.z, 0.f); v.w = fmaxf(v.w, 0.f);
                }
            } else {
                v.x *= scale; v.y *= scale; v.z *= scale; v.w *= scale;
            }
            *(float4*)(C + (long)row * ldc + col) = v;
        }
    }
}

// ---------------------------------------------------------------------------
// Column softmax stats over axis n (rows): per (b, k) compute max and 1/sumexp.
// grid = (KTOT/256, chunk_batches); block = 256.
// ---------------------------------------------------------------------------
__global__ __launch_bounds__(256)
void col_stats(const float* __restrict__ outA, float* __restrict__ Mst,
               float* __restrict__ RS, int b0)
{
    const int k = blockIdx.x * 256 + threadIdx.x;   // 0..767
    const int gb = b0 + blockIdx.y;
    const float* base = outA + (size_t)gb * NV_ * KTOT + k;
    float m = -3.0e38f;
    for (int n = 0; n < NV_; ++n) m = fmaxf(m, base[(size_t)n * KTOT]);
    float s = 0.f;
    for (int n = 0; n < NV_; ++n) s += __expf(base[(size_t)n * KTOT] - m);
    Mst[(size_t)gb * KTOT + k] = m;
    RS[(size_t)gb * KTOT + k] = 1.f / s;
}

// ---------------------------------------------------------------------------
// V_next = softmax_col(A) @ [fL_L ; fV_V].
// A-tile staging applies exp(x - M[k]) * RS[k]. B read virtually from the
// concat (k < NL_ -> fL_L row k, else fV_V row k-NL_).
// ---------------------------------------------------------------------------
__global__ __launch_bounds__(256, 2)
void attn_gemm(const float* __restrict__ Ap,     // outA + b0 offset, z-stride NV_*KTOT
               const float* __restrict__ fLLp,   // chunk-local, z-stride NL_*D_
               const float* __restrict__ fVp,    // chunk-local, z-stride NV_*D_
               const float* __restrict__ Mstp,   // + b0*KTOT, z-stride KTOT
               const float* __restrict__ RSp,
               float* __restrict__ Cp)           // outV + b0 offset, z-stride NV_*D_
{
    __shared__ float At[BK][AT_STRIDE];
    __shared__ float Bs[BK][BS_STRIDE];

    const int tid = threadIdx.x;
    const int tx = tid & 15, ty = tid >> 4;
    const int n0 = blockIdx.x * BN;   // d dimension
    const int m0 = blockIdx.y * BM;   // n rows
    const int z  = blockIdx.z;

    const float* A  = Ap   + (long)z * NV_ * KTOT;
    const float* fL = fLLp + (long)z * NL_ * D_;
    const float* fv = fVp  + (long)z * NV_ * D_;
    const float* Mr = Mstp + (long)z * KTOT;
    const float* Rr = RSp  + (long)z * KTOT;
    float* C = Cp + (long)z * NV_ * D_;

    float acc[8][8];
#pragma unroll
    for (int i = 0; i < 8; ++i)
#pragma unroll
        for (int j = 0; j < 8; ++j) acc[i][j] = 0.f;

    const int ar = tid >> 2;
    const int ac = (tid & 3) * 4;
    const int bk = tid >> 5;
    const int bc = (tid & 31) * 4;

    for (int k0 = 0; k0 < KTOT; k0 += BK) {
        // A tile with softmax transform (columns are k -> use column stats)
        const float4 ms = *(const float4*)(Mr + k0 + ac);
        const float4 rs = *(const float4*)(Rr + k0 + ac);
#pragma unroll
        for (int p = 0; p < 2; ++p) {
            const int r = p * 64 + ar;
            const float4 v = *(const float4*)(A + (long)(m0 + r) * KTOT + (k0 + ac));
            At[ac + 0][r] = __expf(v.x - ms.x) * rs.x;
            At[ac + 1][r] = __expf(v.y - ms.y) * rs.y;
            At[ac + 2][r] = __expf(v.z - ms.z) * rs.z;
            At[ac + 3][r] = __expf(v.w - ms.w) * rs.w;
        }
        // B tile: virtual concat [fL_L ; fV_V], row k, cols n0..n0+127 (d)
#pragma unroll
        for (int p = 0; p < 2; ++p) {
            const int kk = p * 8 + bk;
            const int k = k0 + kk;
            const float* src = (k < NL_) ? (fL + (long)k * D_)
                                         : (fv + (long)(k - NL_) * D_);
            *(float4*)&Bs[kk][bc] = *(const float4*)(src + n0 + bc);
        }
        __syncthreads();

#pragma unroll
        for (int k = 0; k < BK; ++k) {
            const float4 a0 = *(const float4*)&At[k][ty * 8];
            const float4 a1 = *(const float4*)&At[k][ty * 8 + 4];
            const float4 b0 = *(const float4*)&Bs[k][tx * 8];
            const float4 b1 = *(const float4*)&Bs[k][tx * 8 + 4];
            const float a[8] = {a0.x, a0.y, a0.z, a0.w, a1.x, a1.y, a1.z, a1.w};
            const float b[8] = {b0.x, b0.y, b0.z, b0.w, b1.x, b1.y, b1.z, b1.w};
#pragma unroll
            for (int i = 0; i < 8; ++i)
#pragma unroll
                for (int j = 0; j < 8; ++j)
                    acc[i][j] = fmaf(a[i], b[j], acc[i][j]);
        }
        __syncthreads();
    }

#pragma unroll
    for (int i = 0; i < 8; ++i) {
        const int row = m0 + ty * 8 + i;
#pragma unroll
        for (int j = 0; j < 8; j += 4) {
            const int col = n0 + tx * 8 + j;
            float4 v;
            v.x = acc[i][j + 0]; v.y = acc[i][j + 1];
            v.z = acc[i][j + 2]; v.w = acc[i][j + 3];
            *(float4*)(C + (long)row * D_ + col) = v;
        }
    }
}

// ---------------------------------------------------------------------------
extern "C" void kernel_launch(void* const* d_in, const int* in_sizes, int n_in,
                              void* d_out, int out_size, void* d_ws, size_t ws_size,
                              hipStream_t stream)
{
    (void)in_sizes; (void)n_in; (void)out_size;

    const float* V   = (const float*)d_in[0];
    const float* L   = (const float*)d_in[1];
    // d_in[2], d_in[3]: masks, unused by the reference forward
    const float* w1V = (const float*)d_in[4];
    const float* b1V = (const float*)d_in[5];
    const float* w2V = (const float*)d_in[6];
    const float* b2V = (const float*)d_in[7];
    const float* w1L = (const float*)d_in[8];
    const float* b1L = (const float*)d_in[9];
    const float* w2L = (const float*)d_in[10];
    const float* b2L = (const float*)d_in[11];

    float* outA = (float*)d_out;                         // [B, NV, KTOT]
    float* outV = outA + (size_t)B_ * NV_ * KTOT;        // [B, NV, D]

    // ---- workspace layout (floats), chunk size chosen from ws_size ----
    float* ws = (float*)d_ws;
    const size_t ws_floats = ws_size / sizeof(float);
    float* Mst = ws;                          // [B, KTOT]
    float* RS  = Mst + (size_t)B_ * KTOT;     // [B, KTOT]
    float* pool = RS + (size_t)B_ * KTOT;
    const size_t stat_f = 2ul * B_ * KTOT;
    const size_t pool_f = (ws_floats > stat_f) ? (ws_floats - stat_f) : 0;
    const size_t perb = (size_t)NV_ * D_ * 2 + (size_t)NL_ * D_ + (size_t)NV_ * H_;
    int bc_n = (int)(pool_f / perb);
    if (bc_n > B_) bc_n = B_;
    if (bc_n < 1)  bc_n = 1;   // if ws is truly tiny we cannot run; assume >= ~14MB

    float* fV  = pool;                                   // [bc, NV, D]
    float* fLL = fV  + (size_t)bc_n * NV_ * D_;          // [bc, NL, D]
    float* fLV = fLL + (size_t)bc_n * NL_ * D_;          // [bc, NV, D]
    float* hid = fLV + (size_t)bc_n * NV_ * D_;          // [bc, NV, H] (reused)

    const dim3 blk(256);

    for (int b0 = 0; b0 < B_; b0 += bc_n) {
        const int cur = (B_ - b0 < bc_n) ? (B_ - b0) : bc_n;

        // ---- FFN_V(V) -> fV ----
        gemm128<0, 0><<<dim3(H_ / BN, NV_ / BM, cur), blk, 0, stream>>>(
            V + (size_t)b0 * NV_ * D_, (long)NV_ * D_, D_,
            w1V, 0, H_, b1V,
            hid, (long)NV_ * H_, H_, D_, 1.f);
        gemm128<0, 1><<<dim3(D_ / BN, NV_ / BM, cur), blk, 0, stream>>>(
            hid, (long)NV_ * H_, H_,
            w2V, 0, D_, b2V,
            fV, (long)NV_ * D_, D_, H_, 1.f);

        // ---- FFN_L(L) -> fLL ----
        gemm128<0, 0><<<dim3(H_ / BN, NL_ / BM, cur), blk, 0, stream>>>(
            L + (size_t)b0 * NL_ * D_, (long)NL_ * D_, D_,
            w1L, 0, H_, b1L,
            hid, (long)NL_ * H_, H_, D_, 1.f);
        gemm128<0, 1><<<dim3(D_ / BN, NL_ / BM, cur), blk, 0, stream>>>(
            hid, (long)NL_ * H_, H_,
            w2L, 0, D_, b2L,
            fLL, (long)NL_ * D_, D_, H_, 1.f);

        // ---- FFN_L(V) -> fLV ----
        gemm128<0, 0><<<dim3(H_ / BN, NV_ / BM, cur), blk, 0, stream>>>(
            V + (size_t)b0 * NV_ * D_, (long)NV_ * D_, D_,
            w1L, 0, H_, b1L,
            hid, (long)NV_ * H_, H_, D_, 1.f);
        gemm128<0, 1><<<dim3(D_ / BN, NV_ / BM, cur), blk, 0, stream>>>(
            hid, (long)NV_ * H_, H_,
            w2L, 0, D_, b2L,
            fLV, (long)NV_ * D_, D_, H_, 1.f);

        // ---- A_LV = (fV @ fLL^T) * scale -> outA[:, :, 0:256] ----
        gemm128<1, 2><<<dim3(NL_ / BN, NV_ / BM, cur), blk, 0, stream>>>(
            fV, (long)NV_ * D_, D_,
            fLL, (long)NL_ * D_, D_, nullptr,
            outA + (size_t)b0 * NV_ * KTOT, (long)NV_ * KTOT, KTOT, D_, SCALE_);

        // ---- A_VV = (fV @ fLV^T) * scale -> outA[:, :, 256:768] ----
        gemm128<1, 2><<<dim3(NV_ / BN, NV_ / BM, cur), blk, 0, stream>>>(
            fV, (long)NV_ * D_, D_,
            fLV, (long)NV_ * D_, D_, nullptr,
            outA + (size_t)b0 * NV_ * KTOT + NL_, (long)NV_ * KTOT, KTOT, D_, SCALE_);

        // ---- column softmax stats (over axis n) ----
        col_stats<<<dim3(KTOT / 256, cur), blk, 0, stream>>>(outA, Mst, RS, b0);

        // ---- V_next = attn @ [fLL ; fV] ----
        attn_gemm<<<dim3(D_ / BN, NV_ / BM, cur), blk, 0, stream>>>(
            outA + (size_t)b0 * NV_ * KTOT,
            fLL, fV,
            Mst + (size_t)b0 * KTOT, RS + (size_t)b0 * KTOT,
            outV + (size_t)b0 * NV_ * D_);
    }
}

// Round 2
// 1372.508 us; speedup vs baseline: 6.1862x; 6.1862x over previous
//
#include <hip/hip_runtime.h>
#include <stdint.h>

#define B_   32
#define NV_  512
#define NL_  256
#define D_   1024
#define H_   4096
#define KTOT 768
#define SCALE_ 0.03125f   // 1/sqrt(1024)

typedef __attribute__((ext_vector_type(8))) __bf16 bf8_t;
typedef __attribute__((ext_vector_type(4))) float f32x4;

__device__ __forceinline__ unsigned short f2bf(float f) {
    unsigned u = __float_as_uint(f);
    u += 0x7FFFu + ((u >> 16) & 1u);       // round-to-nearest-even
    return (unsigned short)(u >> 16);
}
__device__ __forceinline__ unsigned pk2(float lo, float hi) {
    return (unsigned)f2bf(lo) | ((unsigned)f2bf(hi) << 16);
}

// async global->LDS, 16B per lane. LDS dest = wave-uniform base + lane*16.
__device__ __forceinline__ void gl_lds16(const void* g, const void* lds) {
    __builtin_amdgcn_global_load_lds(
        (const __attribute__((address_space(1))) unsigned int*)(uintptr_t)g,
        (__attribute__((address_space(3))) unsigned int*)(unsigned)(uintptr_t)lds,
        16, 0, 0);
}

// ---------------------------------------------------------------------------
// bf16 MFMA GEMM, 128x128 tile, BK=32, 256 threads = 4 waves, wave->64x64.
// A: [M][K] bf16 row-major. B: [N][K] bf16 row-major (always "B^T" layout).
// EPI: 0 = relu(acc+bias) -> bf16 ; 1 = acc+bias -> bf16 ; 2 = acc*scale -> f32
// ---------------------------------------------------------------------------
template<int EPI>
__global__ __launch_bounds__(256)
void mgemm(const unsigned short* __restrict__ Ab, long sAz, int lda,
           const unsigned short* __restrict__ Bb, long sBz, int ldb,
           const float* __restrict__ bias, float scale,
           void* __restrict__ Cp, long sCz, int ldc, int K)
{
    __shared__ unsigned short As[128 * 32];   // [m][k], 64B rows
    __shared__ unsigned short Bs[128 * 32];   // [n][k]

    const int tid = threadIdx.x;
    const int w = tid >> 6, l = tid & 63;
    const int wr = w >> 1, wc = w & 1;
    const int l15 = l & 15, kg = l >> 4;
    const int srow = l >> 2;            // staging: row within 16-row group
    const int scol = (l & 3) * 8;       // staging: bf16 col offset (16B chunk)
    const int n0 = blockIdx.x * 128, m0 = blockIdx.y * 128, z = blockIdx.z;

    const unsigned short* A  = Ab + (long)z * sAz;
    const unsigned short* Bg = Bb + (long)z * sBz;

    f32x4 acc[4][4];
#pragma unroll
    for (int m = 0; m < 4; ++m)
#pragma unroll
        for (int n = 0; n < 4; ++n) acc[m][n] = (f32x4){0.f, 0.f, 0.f, 0.f};

    for (int k0 = 0; k0 < K; k0 += 32) {
#pragma unroll
        for (int i = 0; i < 2; ++i) {
            const int g = i * 4 + w;               // 16-row group 0..7
            gl_lds16(A  + (long)(m0 + g * 16 + srow) * lda + (k0 + scol), &As[g * 512]);
            gl_lds16(Bg + (long)(n0 + g * 16 + srow) * ldb + (k0 + scol), &Bs[g * 512]);
        }
        __syncthreads();   // drains vmcnt (global_load_lds) per barrier semantics

        bf8_t af[4], bf[4];
#pragma unroll
        for (int m = 0; m < 4; ++m)
            af[m] = *(const bf8_t*)&As[(wr * 64 + m * 16 + l15) * 32 + kg * 8];
#pragma unroll
        for (int n = 0; n < 4; ++n)
            bf[n] = *(const bf8_t*)&Bs[(wc * 64 + n * 16 + l15) * 32 + kg * 8];
#pragma unroll
        for (int m = 0; m < 4; ++m)
#pragma unroll
            for (int n = 0; n < 4; ++n)
                acc[m][n] = __builtin_amdgcn_mfma_f32_16x16x32_bf16(af[m], bf[n], acc[m][n], 0, 0, 0);
        __syncthreads();   // protect LDS before next iteration's staging
    }

    // epilogue: D[(l>>4)*4 + r][l&15] per 16x16 frag
    const int orow = wr * 64 + (l >> 4) * 4;
    const int ocol = wc * 64 + l15;
    if (EPI == 2) {
        float* C = (float*)Cp + (long)z * sCz;
#pragma unroll
        for (int m = 0; m < 4; ++m)
#pragma unroll
            for (int n = 0; n < 4; ++n)
#pragma unroll
                for (int r = 0; r < 4; ++r)
                    C[(long)(m0 + orow + m * 16 + r) * ldc + (n0 + ocol + n * 16)] =
                        acc[m][n][r] * scale;
    } else {
        unsigned short* C = (unsigned short*)Cp + (long)z * sCz;
#pragma unroll
        for (int n = 0; n < 4; ++n) {
            const float bv = bias[n0 + ocol + n * 16];
#pragma unroll
            for (int m = 0; m < 4; ++m)
#pragma unroll
                for (int r = 0; r < 4; ++r) {
                    float v = acc[m][n][r] + bv;
                    if (EPI == 0) v = fmaxf(v, 0.f);
                    C[(long)(m0 + orow + m * 16 + r) * ldc + (n0 + ocol + n * 16)] = f2bf(v);
                }
        }
    }
}

// ---------------------------------------------------------------------------
// Column softmax stats over axis n: per (z, k) max & 1/sumexp. grid (KTOT/64, cur)
// ---------------------------------------------------------------------------
__global__ __launch_bounds__(256)
void col_stats(const float* __restrict__ A, float* __restrict__ Mst, float* __restrict__ RS)
{
    __shared__ float red[4][64];
    const int t = threadIdx.x;
    const int kk = t & 63, ng = t >> 6;
    const int k = blockIdx.x * 64 + kk;
    const int z = blockIdx.y;
    const float* base = A + (long)z * NV_ * KTOT + k;
    float m = -3.0e38f;
    for (int n = ng * 128; n < ng * 128 + 128; ++n) m = fmaxf(m, base[(long)n * KTOT]);
    red[ng][kk] = m;
    __syncthreads();
    m = fmaxf(fmaxf(red[0][kk], red[1][kk]), fmaxf(red[2][kk], red[3][kk]));
    float s = 0.f;
    for (int n = ng * 128; n < ng * 128 + 128; ++n) s += __expf(base[(long)n * KTOT] - m);
    __syncthreads();
    red[ng][kk] = s;
    __syncthreads();
    if (ng == 0) {
        s = red[0][kk] + red[1][kk] + red[2][kk] + red[3][kk];
        Mst[(long)z * KTOT + k] = m;
        RS[(long)z * KTOT + k]  = 1.f / s;
    }
}

// ---------------------------------------------------------------------------
// V_next = softmax_col(A) @ KV : A reg-staged with exp transform -> bf16 LDS;
// B = KVt [D][KTOT] bf16 via global_load_lds. Output f32.
// ---------------------------------------------------------------------------
__global__ __launch_bounds__(256)
void attn_mfma(const float* __restrict__ Ap, const unsigned short* __restrict__ KVt,
               const float* __restrict__ Mstp, const float* __restrict__ RSp,
               float* __restrict__ Cp)
{
    __shared__ unsigned short As[128 * 32];
    __shared__ unsigned short Bs[128 * 32];

    const int tid = threadIdx.x;
    const int w = tid >> 6, l = tid & 63;
    const int wr = w >> 1, wc = w & 1;
    const int l15 = l & 15, kg = l >> 4;
    const int srow = l >> 2, scol = (l & 3) * 8;
    const int n0 = blockIdx.x * 128, m0 = blockIdx.y * 128, z = blockIdx.z;

    const float* A = Ap + (long)z * NV_ * KTOT;
    const unsigned short* Bg = KVt + (long)z * D_ * KTOT;
    const float* Mz = Mstp + (long)z * KTOT;
    const float* Rz = RSp  + (long)z * KTOT;
    float* C = Cp + (long)z * NV_ * D_;

    const int ar = tid >> 1;            // A-stage row 0..127
    const int ah = (tid & 1) * 16;      // col half

    f32x4 acc[4][4];
#pragma unroll
    for (int m = 0; m < 4; ++m)
#pragma unroll
        for (int n = 0; n < 4; ++n) acc[m][n] = (f32x4){0.f, 0.f, 0.f, 0.f};

    for (int k0 = 0; k0 < KTOT; k0 += 32) {
#pragma unroll
        for (int i = 0; i < 2; ++i) {
            const int g = i * 4 + w;
            gl_lds16(Bg + (long)(n0 + g * 16 + srow) * KTOT + (k0 + scol), &Bs[g * 512]);
        }
        // A stage: read f32, exp transform, pack bf16, ds_write
        const float* arow = A + (long)(m0 + ar) * KTOT + k0 + ah;
        const float4 x0 = *(const float4*)(arow);
        const float4 x1 = *(const float4*)(arow + 4);
        const float4 x2 = *(const float4*)(arow + 8);
        const float4 x3 = *(const float4*)(arow + 12);
        const float4 ma = *(const float4*)(Mz + k0 + ah);
        const float4 mb = *(const float4*)(Mz + k0 + ah + 4);
        const float4 mc = *(const float4*)(Mz + k0 + ah + 8);
        const float4 md = *(const float4*)(Mz + k0 + ah + 12);
        const float4 ra = *(const float4*)(Rz + k0 + ah);
        const float4 rb = *(const float4*)(Rz + k0 + ah + 4);
        const float4 rc = *(const float4*)(Rz + k0 + ah + 8);
        const float4 rd = *(const float4*)(Rz + k0 + ah + 12);
        const unsigned q0 = pk2(__expf(x0.x - ma.x) * ra.x, __expf(x0.y - ma.y) * ra.y);
        const unsigned q1 = pk2(__expf(x0.z - ma.z) * ra.z, __expf(x0.w - ma.w) * ra.w);
        const unsigned q2 = pk2(__expf(x1.x - mb.x) * rb.x, __expf(x1.y - mb.y) * rb.y);
        const unsigned q3 = pk2(__expf(x1.z - mb.z) * rb.z, __expf(x1.w - mb.w) * rb.w);
        const unsigned q4 = pk2(__expf(x2.x - mc.x) * rc.x, __expf(x2.y - mc.y) * rc.y);
        const unsigned q5 = pk2(__expf(x2.z - mc.z) * rc.z, __expf(x2.w - mc.w) * rc.w);
        const unsigned q6 = pk2(__expf(x3.x - md.x) * rd.x, __expf(x3.y - md.y) * rd.y);
        const unsigned q7 = pk2(__expf(x3.z - md.z) * rd.z, __expf(x3.w - md.w) * rd.w);
        *(uint4*)&As[ar * 32 + ah]     = make_uint4(q0, q1, q2, q3);
        *(uint4*)&As[ar * 32 + ah + 8] = make_uint4(q4, q5, q6, q7);
        __syncthreads();

        bf8_t af[4], bf[4];
#pragma unroll
        for (int m = 0; m < 4; ++m)
            af[m] = *(const bf8_t*)&As[(wr * 64 + m * 16 + l15) * 32 + kg * 8];
#pragma unroll
        for (int n = 0; n < 4; ++n)
            bf[n] = *(const bf8_t*)&Bs[(wc * 64 + n * 16 + l15) * 32 + kg * 8];
#pragma unroll
        for (int m = 0; m < 4; ++m)
#pragma unroll
            for (int n = 0; n < 4; ++n)
                acc[m][n] = __builtin_amdgcn_mfma_f32_16x16x32_bf16(af[m], bf[n], acc[m][n], 0, 0, 0);
        __syncthreads();
    }

    const int orow = wr * 64 + (l >> 4) * 4;
    const int ocol = wc * 64 + l15;
#pragma unroll
    for (int m = 0; m < 4; ++m)
#pragma unroll
        for (int n = 0; n < 4; ++n)
#pragma unroll
            for (int r = 0; r < 4; ++r)
                C[(long)(m0 + orow + m * 16 + r) * D_ + (n0 + ocol + n * 16)] = acc[m][n][r];
}

// ---------------------------------------------------------------------------
// transpose + convert to bf16: dst[(c0+i)*ldD + r0+j] = bf16(src[(r0+j)*ldS + c0+i])
// grid (R/64, C/64, Z), 256 threads, 64x64 tiles.
// ---------------------------------------------------------------------------
__global__ __launch_bounds__(256)
void tr2bf_f(const float* __restrict__ src, long sSz, int ldS,
             unsigned short* __restrict__ dst, long sDz, int ldD)
{
    __shared__ unsigned short T[64][65];
    const int t = threadIdx.x;
    const int rr = t >> 2, cc = (t & 3) * 16;
    const int r0 = blockIdx.x * 64, c0 = blockIdx.y * 64, z = blockIdx.z;
    const float* S = src + (long)z * sSz + (long)(r0 + rr) * ldS + c0 + cc;
    const float4 a = *(const float4*)(S);
    const float4 b = *(const float4*)(S + 4);
    const float4 c = *(const float4*)(S + 8);
    const float4 d = *(const float4*)(S + 12);
    unsigned short* Tr = &T[rr][cc];
    Tr[0] = f2bf(a.x); Tr[1] = f2bf(a.y); Tr[2]  = f2bf(a.z); Tr[3]  = f2bf(a.w);
    Tr[4] = f2bf(b.x); Tr[5] = f2bf(b.y); Tr[6]  = f2bf(b.z); Tr[7]  = f2bf(b.w);
    Tr[8] = f2bf(c.x); Tr[9] = f2bf(c.y); Tr[10] = f2bf(c.z); Tr[11] = f2bf(c.w);
    Tr[12] = f2bf(d.x); Tr[13] = f2bf(d.y); Tr[14] = f2bf(d.z); Tr[15] = f2bf(d.w);
    __syncthreads();
    unsigned short v[16];
#pragma unroll
    for (int j = 0; j < 16; ++j) v[j] = T[cc + j][rr];
    unsigned q[8];
#pragma unroll
    for (int j = 0; j < 8; ++j) q[j] = (unsigned)v[2 * j] | ((unsigned)v[2 * j + 1] << 16);
    unsigned short* Dp = dst + (long)z * sDz + (long)(c0 + rr) * ldD + r0 + cc;
    *(uint4*)Dp       = make_uint4(q[0], q[1], q[2], q[3]);
    *(uint4*)(Dp + 8) = make_uint4(q[4], q[5], q[6], q[7]);
}

__global__ __launch_bounds__(256)
void tr2bf_h(const unsigned short* __restrict__ src, long sSz, int ldS,
             unsigned short* __restrict__ dst, long sDz, int ldD)
{
    __shared__ unsigned short T[64][65];
    const int t = threadIdx.x;
    const int rr = t >> 2, cc = (t & 3) * 16;
    const int r0 = blockIdx.x * 64, c0 = blockIdx.y * 64, z = blockIdx.z;
    const unsigned short* S = src + (long)z * sSz + (long)(r0 + rr) * ldS + c0 + cc;
    const uint4 qa = *(const uint4*)(S);
    const uint4 qb = *(const uint4*)(S + 8);
    unsigned short* Tr = &T[rr][cc];
    Tr[0]  = qa.x & 0xFFFF; Tr[1]  = qa.x >> 16; Tr[2]  = qa.y & 0xFFFF; Tr[3]  = qa.y >> 16;
    Tr[4]  = qa.z & 0xFFFF; Tr[5]  = qa.z >> 16; Tr[6]  = qa.w & 0xFFFF; Tr[7]  = qa.w >> 16;
    Tr[8]  = qb.x & 0xFFFF; Tr[9]  = qb.x >> 16; Tr[10] = qb.y & 0xFFFF; Tr[11] = qb.y >> 16;
    Tr[12] = qb.z & 0xFFFF; Tr[13] = qb.z >> 16; Tr[14] = qb.w & 0xFFFF; Tr[15] = qb.w >> 16;
    __syncthreads();
    unsigned short v[16];
#pragma unroll
    for (int j = 0; j < 16; ++j) v[j] = T[cc + j][rr];
    unsigned q[8];
#pragma unroll
    for (int j = 0; j < 8; ++j) q[j] = (unsigned)v[2 * j] | ((unsigned)v[2 * j + 1] << 16);
    unsigned short* Dp = dst + (long)z * sDz + (long)(c0 + rr) * ldD + r0 + cc;
    *(uint4*)Dp       = make_uint4(q[0], q[1], q[2], q[3]);
    *(uint4*)(Dp + 8) = make_uint4(q[4], q[5], q[6], q[7]);
}

__global__ __launch_bounds__(256)
void cvt_bf(const float* __restrict__ src, unsigned short* __restrict__ dst, long n)
{
    const long i = ((long)blockIdx.x * 256 + threadIdx.x) * 8;
    if (i >= n) return;
    const float4 a = *(const float4*)(src + i);
    const float4 b = *(const float4*)(src + i + 4);
    *(uint4*)(dst + i) = make_uint4(pk2(a.x, a.y), pk2(a.z, a.w), pk2(b.x, b.y), pk2(b.z, b.w));
}

// ---------------------------------------------------------------------------
extern "C" void kernel_launch(void* const* d_in, const int* in_sizes, int n_in,
                              void* d_out, int out_size, void* d_ws, size_t ws_size,
                              hipStream_t stream)
{
    (void)in_sizes; (void)n_in; (void)out_size;

    const float* V   = (const float*)d_in[0];
    const float* L   = (const float*)d_in[1];
    const float* w1V = (const float*)d_in[4];
    const float* b1V = (const float*)d_in[5];
    const float* w2V = (const float*)d_in[6];
    const float* b2V = (const float*)d_in[7];
    const float* w1L = (const float*)d_in[8];
    const float* b1L = (const float*)d_in[9];
    const float* w2L = (const float*)d_in[10];
    const float* b2L = (const float*)d_in[11];

    float* outA = (float*)d_out;                      // [B, NV, KTOT]
    float* outV = outA + (size_t)B_ * NV_ * KTOT;     // [B, NV, D]

    // ws layout: 4 transposed bf16 weights (persistent) + per-chunk pool
    unsigned short* w1Vt = (unsigned short*)d_ws;                 // [H][D]
    unsigned short* w2Vt = w1Vt + (size_t)H_ * D_;                // [D][H]
    unsigned short* w1Lt = w2Vt + (size_t)D_ * H_;
    unsigned short* w2Lt = w1Lt + (size_t)H_ * D_;
    unsigned short* pool = w2Lt + (size_t)D_ * H_;

    const size_t perb_us = (size_t)NV_ * D_ + (size_t)NL_ * D_ + (size_t)NV_ * H_ +
                           (size_t)NV_ * D_ + (size_t)NL_ * D_ + (size_t)NV_ * D_ +
                           (size_t)D_ * KTOT;
    const size_t perb_bytes = perb_us * 2 + 2 * (size_t)KTOT * sizeof(float);
    const size_t persist_bytes = (size_t)4 * H_ * D_ * 2;
    const size_t avail = (ws_size > persist_bytes + 256) ? ws_size - persist_bytes - 256 : 0;
    int bc = (int)(avail / perb_bytes);
    if (bc > B_) bc = B_;
    if (bc < 1)  bc = 1;

    unsigned short* Vb  = pool;                                   // [bc][NV][D]
    unsigned short* Lb  = Vb  + (size_t)bc * NV_ * D_;            // [bc][NL][D]
    unsigned short* hid = Lb  + (size_t)bc * NL_ * D_;            // [bc][NV][H]
    unsigned short* fV  = hid + (size_t)bc * NV_ * H_;            // [bc][NV][D]
    unsigned short* fLL = fV  + (size_t)bc * NV_ * D_;            // [bc][NL][D]
    unsigned short* fLV = fLL + (size_t)bc * NL_ * D_;            // [bc][NV][D]
    unsigned short* KVt = fLV + (size_t)bc * NV_ * D_;            // [bc][D][KTOT]
    float* Mst = (float*)(KVt + (size_t)bc * D_ * KTOT);          // [bc][KTOT]
    float* RS  = Mst + (size_t)bc * KTOT;

    const dim3 blk(256);

    // weight conversion + transpose (once per launch)
    tr2bf_f<<<dim3(D_ / 64, H_ / 64, 1), blk, 0, stream>>>(w1V, 0, H_, w1Vt, 0, D_);
    tr2bf_f<<<dim3(H_ / 64, D_ / 64, 1), blk, 0, stream>>>(w2V, 0, D_, w2Vt, 0, H_);
    tr2bf_f<<<dim3(D_ / 64, H_ / 64, 1), blk, 0, stream>>>(w1L, 0, H_, w1Lt, 0, D_);
    tr2bf_f<<<dim3(H_ / 64, D_ / 64, 1), blk, 0, stream>>>(w2L, 0, D_, w2Lt, 0, H_);

    for (int b0 = 0; b0 < B_; b0 += bc) {
        const int cur = (B_ - b0 < bc) ? (B_ - b0) : bc;

        cvt_bf<<<dim3(cur * NV_ * D_ / 2048), blk, 0, stream>>>(
            V + (size_t)b0 * NV_ * D_, Vb, (long)cur * NV_ * D_);
        cvt_bf<<<dim3(cur * NL_ * D_ / 2048), blk, 0, stream>>>(
            L + (size_t)b0 * NL_ * D_, Lb, (long)cur * NL_ * D_);

        // FFN_V(V) -> fV
        mgemm<0><<<dim3(H_ / 128, NV_ / 128, cur), blk, 0, stream>>>(
            Vb, (long)NV_ * D_, D_, w1Vt, 0, D_, b1V, 0.f, hid, (long)NV_ * H_, H_, D_);
        mgemm<1><<<dim3(D_ / 128, NV_ / 128, cur), blk, 0, stream>>>(
            hid, (long)NV_ * H_, H_, w2Vt, 0, H_, b2V, 0.f, fV, (long)NV_ * D_, D_, H_);
        // FFN_L(L) -> fLL
        mgemm<0><<<dim3(H_ / 128, NL_ / 128, cur), blk, 0, stream>>>(
            Lb, (long)NL_ * D_, D_, w1Lt, 0, D_, b1L, 0.f, hid, (long)NV_ * H_, H_, D_);
        mgemm<1><<<dim3(D_ / 128, NL_ / 128, cur), blk, 0, stream>>>(
            hid, (long)NV_ * H_, H_, w2Lt, 0, H_, b2L, 0.f, fLL, (long)NL_ * D_, D_, H_);
        // FFN_L(V) -> fLV
        mgemm<0><<<dim3(H_ / 128, NV_ / 128, cur), blk, 0, stream>>>(
            Vb, (long)NV_ * D_, D_, w1Lt, 0, D_, b1L, 0.f, hid, (long)NV_ * H_, H_, D_);
        mgemm<1><<<dim3(D_ / 128, NV_ / 128, cur), blk, 0, stream>>>(
            hid, (long)NV_ * H_, H_, w2Lt, 0, H_, b2L, 0.f, fLV, (long)NV_ * D_, D_, H_);

        // A_LV / A_VV -> outA (f32, scaled)
        mgemm<2><<<dim3(NL_ / 128, NV_ / 128, cur), blk, 0, stream>>>(
            fV, (long)NV_ * D_, D_, fLL, (long)NL_ * D_, D_, nullptr, SCALE_,
            outA + (size_t)b0 * NV_ * KTOT, (long)NV_ * KTOT, KTOT, D_);
        mgemm<2><<<dim3(NV_ / 128, NV_ / 128, cur), blk, 0, stream>>>(
            fV, (long)NV_ * D_, D_, fLV, (long)NV_ * D_, D_, nullptr, SCALE_,
            outA + (size_t)b0 * NV_ * KTOT + NL_, (long)NV_ * KTOT, KTOT, D_);

        // KVt = [fLL ; fV]^T  (bf16 [D][KTOT])
        tr2bf_h<<<dim3(NL_ / 64, D_ / 64, cur), blk, 0, stream>>>(
            fLL, (long)NL_ * D_, D_, KVt, (long)D_ * KTOT, KTOT);
        tr2bf_h<<<dim3(NV_ / 64, D_ / 64, cur), blk, 0, stream>>>(
            fV, (long)NV_ * D_, D_, KVt + NL_, (long)D_ * KTOT, KTOT);

        col_stats<<<dim3(KTOT / 64, cur), blk, 0, stream>>>(
            outA + (size_t)b0 * NV_ * KTOT, Mst, RS);

        attn_mfma<<<dim3(D_ / 128, NV_ / 128, cur), blk, 0, stream>>>(
            outA + (size_t)b0 * NV_ * KTOT, KVt, Mst, RS, outV + (size_t)b0 * NV_ * D_);
    }
}

// Round 3
// 1262.309 us; speedup vs baseline: 6.7263x; 1.0873x over previous
//
#include <hip/hip_runtime.h>
#include <stdint.h>

#define B_   32
#define NV_  512
#define NL_  256
#define D_   1024
#define H_   4096
#define KTOT 768
#define SCALE_ 0.03125f   // 1/sqrt(1024)

typedef __attribute__((ext_vector_type(8))) __bf16 bf8_t;
typedef __attribute__((ext_vector_type(4))) float f32x4;

__device__ __forceinline__ unsigned short f2bf(float f) {
    unsigned u = __float_as_uint(f);
    u += 0x7FFFu + ((u >> 16) & 1u);       // round-to-nearest-even
    return (unsigned short)(u >> 16);
}
__device__ __forceinline__ unsigned pk2(float lo, float hi) {
    return (unsigned)f2bf(lo) | ((unsigned)f2bf(hi) << 16);
}

// async global->LDS, 16B per lane. LDS dest = wave-uniform base + lane*16.
__device__ __forceinline__ void gl_lds16(const void* g, const void* lds) {
    __builtin_amdgcn_global_load_lds(
        (const __attribute__((address_space(1))) unsigned int*)(uintptr_t)g,
        (__attribute__((address_space(3))) unsigned int*)(unsigned)(uintptr_t)lds,
        16, 0, 0);
}

// XCD-chunked supertile decode. Flat grid of total blocks (total % 8 == 0).
// Each XCD gets a contiguous chunk of (tile, z) work:
//   chunk = total/8 ids; within a chunk: z outer, tile inner (tpc tiles/chunk)
// so an XCD sweeps the SAME tpc tiles for every z -> weight panels stay in
// that XCD's L2; A panel (z,m) is reused across the inner tile sweep.
__device__ __forceinline__ void supertile(int nx, int tpc, int& n0, int& m0, int& z)
{
    const int bid = blockIdx.x;
    const int r = bid >> 3, c = bid & 7;     // assumes round-robin block->XCD
    z = r / tpc;
    const int t = c * tpc + (r % tpc);
    n0 = (t % nx) * 128;
    m0 = (t / nx) * 128;
}

// ---------------------------------------------------------------------------
// bf16 MFMA GEMM, 128x128 tile, BK=32, 256 threads = 4 waves, wave->64x64.
// A: [M][K] bf16 row-major. B: [N][K] bf16 row-major (always "B^T" layout).
// EPI: 0 = relu(acc+bias) -> bf16 ; 1 = acc+bias -> bf16 ; 2 = acc*scale -> f32
// ---------------------------------------------------------------------------
template<int EPI>
__global__ __launch_bounds__(256)
void mgemm(const unsigned short* __restrict__ Ab, long sAz, int lda,
           const unsigned short* __restrict__ Bb, long sBz, int ldb,
           const float* __restrict__ bias, float scale,
           void* __restrict__ Cp, long sCz, int ldc, int K,
           int nx, int tpc)
{
    __shared__ unsigned short As[128 * 32];   // [m][k], 64B rows
    __shared__ unsigned short Bs[128 * 32];   // [n][k]

    const int tid = threadIdx.x;
    const int w = tid >> 6, l = tid & 63;
    const int wr = w >> 1, wc = w & 1;
    const int l15 = l & 15, kg = l >> 4;
    const int srow = l >> 2;            // staging: row within 16-row group
    const int scol = (l & 3) * 8;       // staging: bf16 col offset (16B chunk)
    int n0, m0, z;
    supertile(nx, tpc, n0, m0, z);

    const unsigned short* A  = Ab + (long)z * sAz;
    const unsigned short* Bg = Bb + (long)z * sBz;

    f32x4 acc[4][4];
#pragma unroll
    for (int m = 0; m < 4; ++m)
#pragma unroll
        for (int n = 0; n < 4; ++n) acc[m][n] = (f32x4){0.f, 0.f, 0.f, 0.f};

    for (int k0 = 0; k0 < K; k0 += 32) {
#pragma unroll
        for (int i = 0; i < 2; ++i) {
            const int g = i * 4 + w;               // 16-row group 0..7
            gl_lds16(A  + (long)(m0 + g * 16 + srow) * lda + (k0 + scol), &As[g * 512]);
            gl_lds16(Bg + (long)(n0 + g * 16 + srow) * ldb + (k0 + scol), &Bs[g * 512]);
        }
        __syncthreads();   // drains vmcnt (global_load_lds) per barrier semantics

        bf8_t af[4], bf[4];
#pragma unroll
        for (int m = 0; m < 4; ++m)
            af[m] = *(const bf8_t*)&As[(wr * 64 + m * 16 + l15) * 32 + kg * 8];
#pragma unroll
        for (int n = 0; n < 4; ++n)
            bf[n] = *(const bf8_t*)&Bs[(wc * 64 + n * 16 + l15) * 32 + kg * 8];
#pragma unroll
        for (int m = 0; m < 4; ++m)
#pragma unroll
            for (int n = 0; n < 4; ++n)
                acc[m][n] = __builtin_amdgcn_mfma_f32_16x16x32_bf16(af[m], bf[n], acc[m][n], 0, 0, 0);
        __syncthreads();   // protect LDS before next iteration's staging
    }

    // epilogue: D[(l>>4)*4 + r][l&15] per 16x16 frag
    const int orow = wr * 64 + (l >> 4) * 4;
    const int ocol = wc * 64 + l15;
    if (EPI == 2) {
        float* C = (float*)Cp + (long)z * sCz;
#pragma unroll
        for (int m = 0; m < 4; ++m)
#pragma unroll
            for (int n = 0; n < 4; ++n)
#pragma unroll
                for (int r = 0; r < 4; ++r)
                    C[(long)(m0 + orow + m * 16 + r) * ldc + (n0 + ocol + n * 16)] =
                        acc[m][n][r] * scale;
    } else {
        unsigned short* C = (unsigned short*)Cp + (long)z * sCz;
#pragma unroll
        for (int n = 0; n < 4; ++n) {
            const float bv = bias[n0 + ocol + n * 16];
#pragma unroll
            for (int m = 0; m < 4; ++m)
#pragma unroll
                for (int r = 0; r < 4; ++r) {
                    float v = acc[m][n][r] + bv;
                    if (EPI == 0) v = fmaxf(v, 0.f);
                    C[(long)(m0 + orow + m * 16 + r) * ldc + (n0 + ocol + n * 16)] = f2bf(v);
                }
        }
    }
}

// ---------------------------------------------------------------------------
// Column softmax stats over axis n: per (z, k) max & 1/sumexp. grid (KTOT/64, cur)
// ---------------------------------------------------------------------------
__global__ __launch_bounds__(256)
void col_stats(const float* __restrict__ A, float* __restrict__ Mst, float* __restrict__ RS)
{
    __shared__ float red[4][64];
    const int t = threadIdx.x;
    const int kk = t & 63, ng = t >> 6;
    const int k = blockIdx.x * 64 + kk;
    const int z = blockIdx.y;
    const float* base = A + (long)z * NV_ * KTOT + k;
    float m = -3.0e38f;
    for (int n = ng * 128; n < ng * 128 + 128; ++n) m = fmaxf(m, base[(long)n * KTOT]);
    red[ng][kk] = m;
    __syncthreads();
    m = fmaxf(fmaxf(red[0][kk], red[1][kk]), fmaxf(red[2][kk], red[3][kk]));
    float s = 0.f;
    for (int n = ng * 128; n < ng * 128 + 128; ++n) s += __expf(base[(long)n * KTOT] - m);
    __syncthreads();
    red[ng][kk] = s;
    __syncthreads();
    if (ng == 0) {
        s = red[0][kk] + red[1][kk] + red[2][kk] + red[3][kk];
        Mst[(long)z * KTOT + k] = m;
        RS[(long)z * KTOT + k]  = 1.f / s;
    }
}

// ---------------------------------------------------------------------------
// V_next = softmax_col(A) @ KV : A reg-staged with exp transform -> bf16 LDS;
// B = KVt [D][KTOT] bf16 via global_load_lds. Output f32.
// ---------------------------------------------------------------------------
__global__ __launch_bounds__(256)
void attn_mfma(const float* __restrict__ Ap, const unsigned short* __restrict__ KVt,
               const float* __restrict__ Mstp, const float* __restrict__ RSp,
               float* __restrict__ Cp, int nx, int tpc)
{
    __shared__ unsigned short As[128 * 32];
    __shared__ unsigned short Bs[128 * 32];

    const int tid = threadIdx.x;
    const int w = tid >> 6, l = tid & 63;
    const int wr = w >> 1, wc = w & 1;
    const int l15 = l & 15, kg = l >> 4;
    const int srow = l >> 2, scol = (l & 3) * 8;
    int n0, m0, z;
    supertile(nx, tpc, n0, m0, z);

    const float* A = Ap + (long)z * NV_ * KTOT;
    const unsigned short* Bg = KVt + (long)z * D_ * KTOT;
    const float* Mz = Mstp + (long)z * KTOT;
    const float* Rz = RSp  + (long)z * KTOT;
    float* C = Cp + (long)z * NV_ * D_;

    const int ar = tid >> 1;            // A-stage row 0..127
    const int ah = (tid & 1) * 16;      // col half

    f32x4 acc[4][4];
#pragma unroll
    for (int m = 0; m < 4; ++m)
#pragma unroll
        for (int n = 0; n < 4; ++n) acc[m][n] = (f32x4){0.f, 0.f, 0.f, 0.f};

    for (int k0 = 0; k0 < KTOT; k0 += 32) {
#pragma unroll
        for (int i = 0; i < 2; ++i) {
            const int g = i * 4 + w;
            gl_lds16(Bg + (long)(n0 + g * 16 + srow) * KTOT + (k0 + scol), &Bs[g * 512]);
        }
        // A stage: read f32, exp transform, pack bf16, ds_write
        const float* arow = A + (long)(m0 + ar) * KTOT + k0 + ah;
        const float4 x0 = *(const float4*)(arow);
        const float4 x1 = *(const float4*)(arow + 4);
        const float4 x2 = *(const float4*)(arow + 8);
        const float4 x3 = *(const float4*)(arow + 12);
        const float4 ma = *(const float4*)(Mz + k0 + ah);
        const float4 mb = *(const float4*)(Mz + k0 + ah + 4);
        const float4 mc = *(const float4*)(Mz + k0 + ah + 8);
        const float4 md = *(const float4*)(Mz + k0 + ah + 12);
        const float4 ra = *(const float4*)(Rz + k0 + ah);
        const float4 rb = *(const float4*)(Rz + k0 + ah + 4);
        const float4 rc = *(const float4*)(Rz + k0 + ah + 8);
        const float4 rd = *(const float4*)(Rz + k0 + ah + 12);
        const unsigned q0 = pk2(__expf(x0.x - ma.x) * ra.x, __expf(x0.y - ma.y) * ra.y);
        const unsigned q1 = pk2(__expf(x0.z - ma.z) * ra.z, __expf(x0.w - ma.w) * ra.w);
        const unsigned q2 = pk2(__expf(x1.x - mb.x) * rb.x, __expf(x1.y - mb.y) * rb.y);
        const unsigned q3 = pk2(__expf(x1.z - mb.z) * rb.z, __expf(x1.w - mb.w) * rb.w);
        const unsigned q4 = pk2(__expf(x2.x - mc.x) * rc.x, __expf(x2.y - mc.y) * rc.y);
        const unsigned q5 = pk2(__expf(x2.z - mc.z) * rc.z, __expf(x2.w - mc.w) * rc.w);
        const unsigned q6 = pk2(__expf(x3.x - md.x) * rd.x, __expf(x3.y - md.y) * rd.y);
        const unsigned q7 = pk2(__expf(x3.z - md.z) * rd.z, __expf(x3.w - md.w) * rd.w);
        *(uint4*)&As[ar * 32 + ah]     = make_uint4(q0, q1, q2, q3);
        *(uint4*)&As[ar * 32 + ah + 8] = make_uint4(q4, q5, q6, q7);
        __syncthreads();

        bf8_t af[4], bf[4];
#pragma unroll
        for (int m = 0; m < 4; ++m)
            af[m] = *(const bf8_t*)&As[(wr * 64 + m * 16 + l15) * 32 + kg * 8];
#pragma unroll
        for (int n = 0; n < 4; ++n)
            bf[n] = *(const bf8_t*)&Bs[(wc * 64 + n * 16 + l15) * 32 + kg * 8];
#pragma unroll
        for (int m = 0; m < 4; ++m)
#pragma unroll
            for (int n = 0; n < 4; ++n)
                acc[m][n] = __builtin_amdgcn_mfma_f32_16x16x32_bf16(af[m], bf[n], acc[m][n], 0, 0, 0);
        __syncthreads();
    }

    const int orow = wr * 64 + (l >> 4) * 4;
    const int ocol = wc * 64 + l15;
#pragma unroll
    for (int m = 0; m < 4; ++m)
#pragma unroll
        for (int n = 0; n < 4; ++n)
#pragma unroll
            for (int r = 0; r < 4; ++r)
                C[(long)(m0 + orow + m * 16 + r) * D_ + (n0 + ocol + n * 16)] = acc[m][n][r];
}

// ---------------------------------------------------------------------------
// transpose + convert to bf16: dst[(c0+i)*ldD + r0+j] = bf16(src[(r0+j)*ldS + c0+i])
// grid (R/64, C/64, Z), 256 threads, 64x64 tiles.
// ---------------------------------------------------------------------------
__global__ __launch_bounds__(256)
void tr2bf_f(const float* __restrict__ src, long sSz, int ldS,
             unsigned short* __restrict__ dst, long sDz, int ldD)
{
    __shared__ unsigned short T[64][65];
    const int t = threadIdx.x;
    const int rr = t >> 2, cc = (t & 3) * 16;
    const int r0 = blockIdx.x * 64, c0 = blockIdx.y * 64, z = blockIdx.z;
    const float* S = src + (long)z * sSz + (long)(r0 + rr) * ldS + c0 + cc;
    const float4 a = *(const float4*)(S);
    const float4 b = *(const float4*)(S + 4);
    const float4 c = *(const float4*)(S + 8);
    const float4 d = *(const float4*)(S + 12);
    unsigned short* Tr = &T[rr][cc];
    Tr[0] = f2bf(a.x); Tr[1] = f2bf(a.y); Tr[2]  = f2bf(a.z); Tr[3]  = f2bf(a.w);
    Tr[4] = f2bf(b.x); Tr[5] = f2bf(b.y); Tr[6]  = f2bf(b.z); Tr[7]  = f2bf(b.w);
    Tr[8] = f2bf(c.x); Tr[9] = f2bf(c.y); Tr[10] = f2bf(c.z); Tr[11] = f2bf(c.w);
    Tr[12] = f2bf(d.x); Tr[13] = f2bf(d.y); Tr[14] = f2bf(d.z); Tr[15] = f2bf(d.w);
    __syncthreads();
    unsigned short v[16];
#pragma unroll
    for (int j = 0; j < 16; ++j) v[j] = T[cc + j][rr];
    unsigned q[8];
#pragma unroll
    for (int j = 0; j < 8; ++j) q[j] = (unsigned)v[2 * j] | ((unsigned)v[2 * j + 1] << 16);
    unsigned short* Dp = dst + (long)z * sDz + (long)(c0 + rr) * ldD + r0 + cc;
    *(uint4*)Dp       = make_uint4(q[0], q[1], q[2], q[3]);
    *(uint4*)(Dp + 8) = make_uint4(q[4], q[5], q[6], q[7]);
}

__global__ __launch_bounds__(256)
void tr2bf_h(const unsigned short* __restrict__ src, long sSz, int ldS,
             unsigned short* __restrict__ dst, long sDz, int ldD)
{
    __shared__ unsigned short T[64][65];
    const int t = threadIdx.x;
    const int rr = t >> 2, cc = (t & 3) * 16;
    const int r0 = blockIdx.x * 64, c0 = blockIdx.y * 64, z = blockIdx.z;
    const unsigned short* S = src + (long)z * sSz + (long)(r0 + rr) * ldS + c0 + cc;
    const uint4 qa = *(const uint4*)(S);
    const uint4 qb = *(const uint4*)(S + 8);
    unsigned short* Tr = &T[rr][cc];
    Tr[0]  = qa.x & 0xFFFF; Tr[1]  = qa.x >> 16; Tr[2]  = qa.y & 0xFFFF; Tr[3]  = qa.y >> 16;
    Tr[4]  = qa.z & 0xFFFF; Tr[5]  = qa.z >> 16; Tr[6]  = qa.w & 0xFFFF; Tr[7]  = qa.w >> 16;
    Tr[8]  = qb.x & 0xFFFF; Tr[9]  = qb.x >> 16; Tr[10] = qb.y & 0xFFFF; Tr[11] = qb.y >> 16;
    Tr[12] = qb.z & 0xFFFF; Tr[13] = qb.z >> 16; Tr[14] = qb.w & 0xFFFF; Tr[15] = qb.w >> 16;
    __syncthreads();
    unsigned short v[16];
#pragma unroll
    for (int j = 0; j < 16; ++j) v[j] = T[cc + j][rr];
    unsigned q[8];
#pragma unroll
    for (int j = 0; j < 8; ++j) q[j] = (unsigned)v[2 * j] | ((unsigned)v[2 * j + 1] << 16);
    unsigned short* Dp = dst + (long)z * sDz + (long)(c0 + rr) * ldD + r0 + cc;
    *(uint4*)Dp       = make_uint4(q[0], q[1], q[2], q[3]);
    *(uint4*)(Dp + 8) = make_uint4(q[4], q[5], q[6], q[7]);
}

__global__ __launch_bounds__(256)
void cvt_bf(const float* __restrict__ src, unsigned short* __restrict__ dst, long n)
{
    const long i = ((long)blockIdx.x * 256 + threadIdx.x) * 8;
    if (i >= n) return;
    const float4 a = *(const float4*)(src + i);
    const float4 b = *(const float4*)(src + i + 4);
    *(uint4*)(dst + i) = make_uint4(pk2(a.x, a.y), pk2(a.z, a.w), pk2(b.x, b.y), pk2(b.z, b.w));
}

// ---------------------------------------------------------------------------
extern "C" void kernel_launch(void* const* d_in, const int* in_sizes, int n_in,
                              void* d_out, int out_size, void* d_ws, size_t ws_size,
                              hipStream_t stream)
{
    (void)in_sizes; (void)n_in; (void)out_size;

    const float* V   = (const float*)d_in[0];
    const float* L   = (const float*)d_in[1];
    const float* w1V = (const float*)d_in[4];
    const float* b1V = (const float*)d_in[5];
    const float* w2V = (const float*)d_in[6];
    const float* b2V = (const float*)d_in[7];
    const float* w1L = (const float*)d_in[8];
    const float* b1L = (const float*)d_in[9];
    const float* w2L = (const float*)d_in[10];
    const float* b2L = (const float*)d_in[11];

    float* outA = (float*)d_out;                      // [B, NV, KTOT]
    float* outV = outA + (size_t)B_ * NV_ * KTOT;     // [B, NV, D]

    // ws layout: 4 transposed bf16 weights (persistent) + per-chunk pool
    unsigned short* w1Vt = (unsigned short*)d_ws;                 // [H][D]
    unsigned short* w2Vt = w1Vt + (size_t)H_ * D_;                // [D][H]
    unsigned short* w1Lt = w2Vt + (size_t)D_ * H_;
    unsigned short* w2Lt = w1Lt + (size_t)H_ * D_;
    unsigned short* pool = w2Lt + (size_t)D_ * H_;

    const size_t perb_us = (size_t)NV_ * D_ + (size_t)NL_ * D_ + (size_t)NV_ * H_ +
                           (size_t)NV_ * D_ + (size_t)NL_ * D_ + (size_t)NV_ * D_ +
                           (size_t)D_ * KTOT;
    const size_t perb_bytes = perb_us * 2 + 2 * (size_t)KTOT * sizeof(float);
    const size_t persist_bytes = (size_t)4 * H_ * D_ * 2;
    const size_t avail = (ws_size > persist_bytes + 256) ? ws_size - persist_bytes - 256 : 0;
    int bc = (int)(avail / perb_bytes);
    if (bc > B_) bc = B_;
    if (bc < 1)  bc = 1;
    // supertile decode requires total blocks % 8 == 0 -> need cur % 8 == 0 or cur
    // handled via tpc math below (nx*ny always % 8 == 0 here, any cur works).

    unsigned short* Vb  = pool;                                   // [bc][NV][D]
    unsigned short* Lb  = Vb  + (size_t)bc * NV_ * D_;            // [bc][NL][D]
    unsigned short* hid = Lb  + (size_t)bc * NL_ * D_;            // [bc][NV][H]
    unsigned short* fV  = hid + (size_t)bc * NV_ * H_;            // [bc][NV][D]
    unsigned short* fLL = fV  + (size_t)bc * NV_ * D_;            // [bc][NL][D]
    unsigned short* fLV = fLL + (size_t)bc * NL_ * D_;            // [bc][NV][D]
    unsigned short* KVt = fLV + (size_t)bc * NV_ * D_;            // [bc][D][KTOT]
    float* Mst = (float*)(KVt + (size_t)bc * D_ * KTOT);          // [bc][KTOT]
    float* RS  = Mst + (size_t)bc * KTOT;

    const dim3 blk(256);

    // weight conversion + transpose (once per launch)
    tr2bf_f<<<dim3(D_ / 64, H_ / 64, 1), blk, 0, stream>>>(w1V, 0, H_, w1Vt, 0, D_);
    tr2bf_f<<<dim3(H_ / 64, D_ / 64, 1), blk, 0, stream>>>(w2V, 0, D_, w2Vt, 0, H_);
    tr2bf_f<<<dim3(D_ / 64, H_ / 64, 1), blk, 0, stream>>>(w1L, 0, H_, w1Lt, 0, D_);
    tr2bf_f<<<dim3(H_ / 64, D_ / 64, 1), blk, 0, stream>>>(w2L, 0, D_, w2Lt, 0, H_);

    for (int b0 = 0; b0 < B_; b0 += bc) {
        const int cur = (B_ - b0 < bc) ? (B_ - b0) : bc;

        cvt_bf<<<dim3(cur * NV_ * D_ / 2048), blk, 0, stream>>>(
            V + (size_t)b0 * NV_ * D_, Vb, (long)cur * NV_ * D_);
        cvt_bf<<<dim3(cur * NL_ * D_ / 2048), blk, 0, stream>>>(
            L + (size_t)b0 * NL_ * D_, Lb, (long)cur * NL_ * D_);

        // helper to build flat grids: total = nx*ny*cur, tpc = nx*ny/8
        #define GRID(nx, ny) dim3((unsigned)((nx) * (ny) * cur)), blk
        #define SWZ(nx, ny)  (nx), ((nx) * (ny) / 8)

        // FFN_V(V) -> fV
        mgemm<0><<<GRID(H_ / 128, NV_ / 128), 0, stream>>>(
            Vb, (long)NV_ * D_, D_, w1Vt, 0, D_, b1V, 0.f,
            hid, (long)NV_ * H_, H_, D_, SWZ(H_ / 128, NV_ / 128));
        mgemm<1><<<GRID(D_ / 128, NV_ / 128), 0, stream>>>(
            hid, (long)NV_ * H_, H_, w2Vt, 0, H_, b2V, 0.f,
            fV, (long)NV_ * D_, D_, H_, SWZ(D_ / 128, NV_ / 128));
        // FFN_L(L) -> fLL
        mgemm<0><<<GRID(H_ / 128, NL_ / 128), 0, stream>>>(
            Lb, (long)NL_ * D_, D_, w1Lt, 0, D_, b1L, 0.f,
            hid, (long)NV_ * H_, H_, D_, SWZ(H_ / 128, NL_ / 128));
        mgemm<1><<<GRID(D_ / 128, NL_ / 128), 0, stream>>>(
            hid, (long)NV_ * H_, H_, w2Lt, 0, H_, b2L, 0.f,
            fLL, (long)NL_ * D_, D_, H_, SWZ(D_ / 128, NL_ / 128));
        // FFN_L(V) -> fLV
        mgemm<0><<<GRID(H_ / 128, NV_ / 128), 0, stream>>>(
            Vb, (long)NV_ * D_, D_, w1Lt, 0, D_, b1L, 0.f,
            hid, (long)NV_ * H_, H_, D_, SWZ(H_ / 128, NV_ / 128));
        mgemm<1><<<GRID(D_ / 128, NV_ / 128), 0, stream>>>(
            hid, (long)NV_ * H_, H_, w2Lt, 0, H_, b2L, 0.f,
            fLV, (long)NV_ * D_, D_, H_, SWZ(D_ / 128, NV_ / 128));

        // A_LV / A_VV -> outA (f32, scaled)
        mgemm<2><<<GRID(NL_ / 128, NV_ / 128), 0, stream>>>(
            fV, (long)NV_ * D_, D_, fLL, (long)NL_ * D_, D_, nullptr, SCALE_,
            outA + (size_t)b0 * NV_ * KTOT, (long)NV_ * KTOT, KTOT, D_,
            SWZ(NL_ / 128, NV_ / 128));
        mgemm<2><<<GRID(NV_ / 128, NV_ / 128), 0, stream>>>(
            fV, (long)NV_ * D_, D_, fLV, (long)NV_ * D_, D_, nullptr, SCALE_,
            outA + (size_t)b0 * NV_ * KTOT + NL_, (long)NV_ * KTOT, KTOT, D_,
            SWZ(NV_ / 128, NV_ / 128));

        // KVt = [fLL ; fV]^T  (bf16 [D][KTOT])
        tr2bf_h<<<dim3(NL_ / 64, D_ / 64, cur), blk, 0, stream>>>(
            fLL, (long)NL_ * D_, D_, KVt, (long)D_ * KTOT, KTOT);
        tr2bf_h<<<dim3(NV_ / 64, D_ / 64, cur), blk, 0, stream>>>(
            fV, (long)NV_ * D_, D_, KVt + NL_, (long)D_ * KTOT, KTOT);

        col_stats<<<dim3(KTOT / 64, cur), blk, 0, stream>>>(
            outA + (size_t)b0 * NV_ * KTOT, Mst, RS);

        attn_mfma<<<GRID(D_ / 128, NV_ / 128), 0, stream>>>(
            outA + (size_t)b0 * NV_ * KTOT, KVt, Mst, RS,
            outV + (size_t)b0 * NV_ * D_, SWZ(D_ / 128, NV_ / 128));

        #undef GRID
        #undef SWZ
    }
}

// Round 4
// 975.425 us; speedup vs baseline: 8.7046x; 1.2941x over previous
//
#include <hip/hip_runtime.h>
#include <stdint.h>

#define B_   32
#define NV_  512
#define NL_  256
#define D_   1024
#define H_   4096
#define KTOT 768
#define SCALE_ 0.03125f   // 1/sqrt(1024)

typedef __attribute__((ext_vector_type(8))) __bf16 bf8_t;
typedef __attribute__((ext_vector_type(4))) float f32x4;

__device__ __forceinline__ unsigned short f2bf(float f) {
    unsigned u = __float_as_uint(f);
    u += 0x7FFFu + ((u >> 16) & 1u);       // round-to-nearest-even
    return (unsigned short)(u >> 16);
}
__device__ __forceinline__ unsigned pk2(float lo, float hi) {
    return (unsigned)f2bf(lo) | ((unsigned)f2bf(hi) << 16);
}

// async global->LDS, 16B per lane. LDS dest = wave-uniform base + lane*16.
__device__ __forceinline__ void gl_lds16(const void* g, const void* lds) {
    __builtin_amdgcn_global_load_lds(
        (const __attribute__((address_space(1))) unsigned int*)(uintptr_t)g,
        (__attribute__((address_space(3))) unsigned int*)(unsigned)(uintptr_t)lds,
        16, 0, 0);
}

#define SBAR() asm volatile("s_barrier" ::: "memory")
#define VMC4() asm volatile("s_waitcnt vmcnt(4)" ::: "memory")
#define VMC0() asm volatile("s_waitcnt vmcnt(0)" ::: "memory")

// ===========================================================================
// 256x256 8-phase bf16 MFMA GEMM (T2+T3+T4+T5). 512 threads = 8 waves (2Mx4N).
// A: [M][K] bf16 row-major, B: [N][K] bf16 row-major (B^T layout).
// Per wave: 128x64 output = 8 m-frags x 4 n-frags of 16x16, BK=64 (2 k-slices).
// LDS 128 KiB dynamic: A[buf][half] + B[buf][half], 16 KiB each region,
// rows 128B; element (r,c) at byte r*128 + ((2c) ^ ((r&7)<<4))  (bank swizzle).
// Staged via global_load_lds with inverse-swizzled SOURCE address (linear dest).
// Schedule: iteration computes tiles t (buf0, phases 0-3) and t+1 (buf1, 4-7);
// phase p stages half-tile g=4t+6+p (parts per tile: 0=Bh0,1=Bh1,2=Ah0,3=Ah1;
// B frees after q1, A after q2 -> every stage lands >=1 barrier after last read).
// vmcnt(4) before closing barrier of phases 3 and 7 only (counted, never 0).
// EPI: 0 = relu(acc+bias)->bf16 ; 1 = acc+bias->bf16
// ===========================================================================
template<int EPI>
__global__ __launch_bounds__(512, 1)
void gemm256(const unsigned short* __restrict__ Ab, long sAz, int lda,
             const unsigned short* __restrict__ Bb, long sBz, int ldb,
             const float* __restrict__ bias,
             unsigned short* __restrict__ Cp, long sCz, int ldc, int K,
             int nx, int ntile, int tpc)
{
    extern __shared__ unsigned char lds[];
    unsigned char* const ldsA = lds;            // (buf*2+half)*16384
    unsigned char* const ldsB = lds + 65536;    // (buf*2+half)*16384

    const int tid = threadIdx.x;
    const int w = tid >> 6, l = tid & 63;
    const int wr = w >> 2, wc = w & 3;          // 2 x 4 wave grid
    const int lrow = l & 15;

    // XCD-chunked tile decode (tpc = ntile/8 when ntile%8==0, else 0 -> plain)
    int t_, z;
    {
        const int bid = blockIdx.x;
        if (tpc > 0) { const int r = bid >> 3, c = bid & 7; z = r / tpc; t_ = c * tpc + r % tpc; }
        else         { z = bid / ntile; t_ = bid - z * ntile; }
    }
    const int n0 = (t_ % nx) * 256, m0 = (t_ / nx) * 256;

    const unsigned short* A  = Ab + (long)z * sAz;
    const unsigned short* Bg = Bb + (long)z * sBz;

    // staging geometry: thread tid covers linear LDS bytes [tid*16, +16) per issue
    const int srow = tid >> 3;                               // row 0..63 within 64-row block
    const int scol = ((tid & 7) * 8) ^ ((srow & 7) << 3);    // inverse-swizzled src col (bf16)
    const int ntk = K >> 6;                                  // # K-tiles (even)

    // ds-read swizzled column byte offsets for k-slice 0 / 1
    const int cs0 = (((l >> 4) * 16)) ^ ((l & 7) << 4);
    const int cs1 = (64 + ((l >> 4) * 16)) ^ ((l & 7) << 4);

    f32x4 acc[8][4];
#pragma unroll
    for (int i = 0; i < 8; ++i)
#pragma unroll
        for (int j = 0; j < 4; ++j) acc[i][j] = (f32x4){0.f, 0.f, 0.f, 0.f};

    auto stage = [&](int tau, int part) {
        const int buf = tau & 1;                         // parity from UNclamped tau
        const int kt = (tau < ntk) ? tau : (ntk - 1);    // clamp source only
        const unsigned short* s; unsigned char* d; int ld;
        if (part < 2) { ld = ldb;
            s = Bg + (long)(n0 + part * 128 + srow) * ldb + kt * 64 + scol;
            d = ldsB + (buf * 2 + part) * 16384 + w * 1024;
        } else { ld = lda; const int h = part - 2;
            s = A + (long)(m0 + h * 128 + srow) * lda + kt * 64 + scol;
            d = ldsA + (buf * 2 + h) * 16384 + w * 1024;
        }
        gl_lds16(s, d);
        gl_lds16(s + (long)64 * ld, d + 8192);
    };
    auto rdA = [&](int buf, int mf, int cs) -> bf8_t {
        return *(const bf8_t*)(ldsA + (buf * 2 + wr) * 16384 + (mf * 16 + lrow) * 128 + cs);
    };
    auto rdB = [&](int buf, int nf, int cs) -> bf8_t {
        return *(const bf8_t*)(ldsB + (buf * 2 + (wc >> 1)) * 16384 +
                               ((wc & 1) * 64 + nf * 16 + lrow) * 128 + cs);
    };

    // ---- prologue: tile0 all parts, tile1 B halves; wait tile0 landed ----
    stage(0, 0); stage(0, 1); stage(0, 2); stage(0, 3);
    stage(1, 0); stage(1, 1);
    VMC4();
    SBAR();

    bf8_t aR[4][2], bR0[2][2], bR1[2][2];

    for (int t = 0; t < ntk; t += 2) {
        // ================= tile t (buf0) =================
        // p0 (q0): read A mf0-3 + B nf0-1; stage (t+1, A h0)
#pragma unroll
        for (int mf = 0; mf < 4; ++mf) { aR[mf][0] = rdA(0, mf, cs0); aR[mf][1] = rdA(0, mf, cs1); }
#pragma unroll
        for (int nf = 0; nf < 2; ++nf) { bR0[nf][0] = rdB(0, nf, cs0); bR0[nf][1] = rdB(0, nf, cs1); }
        stage(t + 1, 2);
        SBAR();
        __builtin_amdgcn_s_setprio(1);
#pragma unroll
        for (int mf = 0; mf < 4; ++mf)
#pragma unroll
            for (int nf = 0; nf < 2; ++nf) {
                acc[mf][nf] = __builtin_amdgcn_mfma_f32_16x16x32_bf16(aR[mf][0], bR0[nf][0], acc[mf][nf], 0, 0, 0);
                acc[mf][nf] = __builtin_amdgcn_mfma_f32_16x16x32_bf16(aR[mf][1], bR0[nf][1], acc[mf][nf], 0, 0, 0);
            }
        __builtin_amdgcn_s_setprio(0);
        SBAR();

        // p1 (q1): read B nf2-3; stage (t+1, A h1)
#pragma unroll
        for (int nf = 0; nf < 2; ++nf) { bR1[nf][0] = rdB(0, nf + 2, cs0); bR1[nf][1] = rdB(0, nf + 2, cs1); }
        stage(t + 1, 3);
        SBAR();
        __builtin_amdgcn_s_setprio(1);
#pragma unroll
        for (int mf = 0; mf < 4; ++mf)
#pragma unroll
            for (int nf = 0; nf < 2; ++nf) {
                acc[mf][nf + 2] = __builtin_amdgcn_mfma_f32_16x16x32_bf16(aR[mf][0], bR1[nf][0], acc[mf][nf + 2], 0, 0, 0);
                acc[mf][nf + 2] = __builtin_amdgcn_mfma_f32_16x16x32_bf16(aR[mf][1], bR1[nf][1], acc[mf][nf + 2], 0, 0, 0);
            }
        __builtin_amdgcn_s_setprio(0);
        SBAR();

        // p2 (q2): read A mf4-7; stage (t+2, B h0)
#pragma unroll
        for (int mf = 0; mf < 4; ++mf) { aR[mf][0] = rdA(0, mf + 4, cs0); aR[mf][1] = rdA(0, mf + 4, cs1); }
        stage(t + 2, 0);
        SBAR();
        __builtin_amdgcn_s_setprio(1);
#pragma unroll
        for (int mf = 0; mf < 4; ++mf)
#pragma unroll
            for (int nf = 0; nf < 2; ++nf) {
                acc[mf + 4][nf] = __builtin_amdgcn_mfma_f32_16x16x32_bf16(aR[mf][0], bR0[nf][0], acc[mf + 4][nf], 0, 0, 0);
                acc[mf + 4][nf] = __builtin_amdgcn_mfma_f32_16x16x32_bf16(aR[mf][1], bR0[nf][1], acc[mf + 4][nf], 0, 0, 0);
            }
        __builtin_amdgcn_s_setprio(0);
        SBAR();

        // p3 (q3): stage (t+2, B h1); vmcnt(4) -> tile t+1 fully landed
        stage(t + 2, 1);
        SBAR();
        __builtin_amdgcn_s_setprio(1);
#pragma unroll
        for (int mf = 0; mf < 4; ++mf)
#pragma unroll
            for (int nf = 0; nf < 2; ++nf) {
                acc[mf + 4][nf + 2] = __builtin_amdgcn_mfma_f32_16x16x32_bf16(aR[mf][0], bR1[nf][0], acc[mf + 4][nf + 2], 0, 0, 0);
                acc[mf + 4][nf + 2] = __builtin_amdgcn_mfma_f32_16x16x32_bf16(aR[mf][1], bR1[nf][1], acc[mf + 4][nf + 2], 0, 0, 0);
            }
        __builtin_amdgcn_s_setprio(0);
        VMC4();
        SBAR();

        // ================= tile t+1 (buf1) =================
        // p4 (q0): stage (t+2, A h0)
#pragma unroll
        for (int mf = 0; mf < 4; ++mf) { aR[mf][0] = rdA(1, mf, cs0); aR[mf][1] = rdA(1, mf, cs1); }
#pragma unroll
        for (int nf = 0; nf < 2; ++nf) { bR0[nf][0] = rdB(1, nf, cs0); bR0[nf][1] = rdB(1, nf, cs1); }
        stage(t + 2, 2);
        SBAR();
        __builtin_amdgcn_s_setprio(1);
#pragma unroll
        for (int mf = 0; mf < 4; ++mf)
#pragma unroll
            for (int nf = 0; nf < 2; ++nf) {
                acc[mf][nf] = __builtin_amdgcn_mfma_f32_16x16x32_bf16(aR[mf][0], bR0[nf][0], acc[mf][nf], 0, 0, 0);
                acc[mf][nf] = __builtin_amdgcn_mfma_f32_16x16x32_bf16(aR[mf][1], bR0[nf][1], acc[mf][nf], 0, 0, 0);
            }
        __builtin_amdgcn_s_setprio(0);
        SBAR();

        // p5 (q1): stage (t+2, A h1)
#pragma unroll
        for (int nf = 0; nf < 2; ++nf) { bR1[nf][0] = rdB(1, nf + 2, cs0); bR1[nf][1] = rdB(1, nf + 2, cs1); }
        stage(t + 2, 3);
        SBAR();
        __builtin_amdgcn_s_setprio(1);
#pragma unroll
        for (int mf = 0; mf < 4; ++mf)
#pragma unroll
            for (int nf = 0; nf < 2; ++nf) {
                acc[mf][nf + 2] = __builtin_amdgcn_mfma_f32_16x16x32_bf16(aR[mf][0], bR1[nf][0], acc[mf][nf + 2], 0, 0, 0);
                acc[mf][nf + 2] = __builtin_amdgcn_mfma_f32_16x16x32_bf16(aR[mf][1], bR1[nf][1], acc[mf][nf + 2], 0, 0, 0);
            }
        __builtin_amdgcn_s_setprio(0);
        SBAR();

        // p6 (q2): stage (t+3, B h0)
#pragma unroll
        for (int mf = 0; mf < 4; ++mf) { aR[mf][0] = rdA(1, mf + 4, cs0); aR[mf][1] = rdA(1, mf + 4, cs1); }
        stage(t + 3, 0);
        SBAR();
        __builtin_amdgcn_s_setprio(1);
#pragma unroll
        for (int mf = 0; mf < 4; ++mf)
#pragma unroll
            for (int nf = 0; nf < 2; ++nf) {
                acc[mf + 4][nf] = __builtin_amdgcn_mfma_f32_16x16x32_bf16(aR[mf][0], bR0[nf][0], acc[mf + 4][nf], 0, 0, 0);
                acc[mf + 4][nf] = __builtin_amdgcn_mfma_f32_16x16x32_bf16(aR[mf][1], bR0[nf][1], acc[mf + 4][nf], 0, 0, 0);
            }
        __builtin_amdgcn_s_setprio(0);
        SBAR();

        // p7 (q3): stage (t+3, B h1); vmcnt(4) -> tile t+2 fully landed
        stage(t + 3, 1);
        SBAR();
        __builtin_amdgcn_s_setprio(1);
#pragma unroll
        for (int mf = 0; mf < 4; ++mf)
#pragma unroll
            for (int nf = 0; nf < 2; ++nf) {
                acc[mf + 4][nf + 2] = __builtin_amdgcn_mfma_f32_16x16x32_bf16(aR[mf][0], bR1[nf][0], acc[mf + 4][nf + 2], 0, 0, 0);
                acc[mf + 4][nf + 2] = __builtin_amdgcn_mfma_f32_16x16x32_bf16(aR[mf][1], bR1[nf][1], acc[mf + 4][nf + 2], 0, 0, 0);
            }
        __builtin_amdgcn_s_setprio(0);
        VMC4();
        SBAR();
    }

    VMC0();   // drain tail garbage staging before LDS dealloc / kernel end

    // ---- epilogue: bias (+relu) -> bf16 ----
    unsigned short* C = Cp + (long)z * sCz;
    const int c0 = n0 + wc * 64;
    const int r0 = m0 + wr * 128 + (l >> 4) * 4;
#pragma unroll
    for (int nf = 0; nf < 4; ++nf) {
        const int col = c0 + nf * 16 + lrow;
        const float bv = bias[col];
#pragma unroll
        for (int mf = 0; mf < 8; ++mf)
#pragma unroll
            for (int r = 0; r < 4; ++r) {
                float v = acc[mf][nf][r] + bv;
                if (EPI == 0) v = fmaxf(v, 0.f);
                C[(long)(r0 + mf * 16 + r) * ldc + col] = f2bf(v);
            }
    }
}

// ===========================================================================
// 128-tile kernels from round 3 (used for A_LV/A_VV + attn) — unchanged.
// ===========================================================================
__device__ __forceinline__ void supertile(int nx, int tpc, int& n0, int& m0, int& z)
{
    const int bid = blockIdx.x;
    const int r = bid >> 3, c = bid & 7;
    z = r / tpc;
    const int t = c * tpc + (r % tpc);
    n0 = (t % nx) * 128;
    m0 = (t / nx) * 128;
}

template<int EPI>   // only EPI=2 used now: C = acc*scale -> f32
__global__ __launch_bounds__(256)
void mgemm(const unsigned short* __restrict__ Ab, long sAz, int lda,
           const unsigned short* __restrict__ Bb, long sBz, int ldb,
           const float* __restrict__ bias, float scale,
           void* __restrict__ Cp, long sCz, int ldc, int K,
           int nx, int tpc)
{
    __shared__ unsigned short As[128 * 32];
    __shared__ unsigned short Bs[128 * 32];

    const int tid = threadIdx.x;
    const int w = tid >> 6, l = tid & 63;
    const int wr = w >> 1, wc = w & 1;
    const int l15 = l & 15, kg = l >> 4;
    const int srow = l >> 2, scol = (l & 3) * 8;
    int n0, m0, z;
    supertile(nx, tpc, n0, m0, z);

    const unsigned short* A  = Ab + (long)z * sAz;
    const unsigned short* Bg = Bb + (long)z * sBz;

    f32x4 acc[4][4];
#pragma unroll
    for (int m = 0; m < 4; ++m)
#pragma unroll
        for (int n = 0; n < 4; ++n) acc[m][n] = (f32x4){0.f, 0.f, 0.f, 0.f};

    for (int k0 = 0; k0 < K; k0 += 32) {
#pragma unroll
        for (int i = 0; i < 2; ++i) {
            const int g = i * 4 + w;
            gl_lds16(A  + (long)(m0 + g * 16 + srow) * lda + (k0 + scol), &As[g * 512]);
            gl_lds16(Bg + (long)(n0 + g * 16 + srow) * ldb + (k0 + scol), &Bs[g * 512]);
        }
        __syncthreads();

        bf8_t af[4], bf[4];
#pragma unroll
        for (int m = 0; m < 4; ++m)
            af[m] = *(const bf8_t*)&As[(wr * 64 + m * 16 + l15) * 32 + kg * 8];
#pragma unroll
        for (int n = 0; n < 4; ++n)
            bf[n] = *(const bf8_t*)&Bs[(wc * 64 + n * 16 + l15) * 32 + kg * 8];
#pragma unroll
        for (int m = 0; m < 4; ++m)
#pragma unroll
            for (int n = 0; n < 4; ++n)
                acc[m][n] = __builtin_amdgcn_mfma_f32_16x16x32_bf16(af[m], bf[n], acc[m][n], 0, 0, 0);
        __syncthreads();
    }

    const int orow = wr * 64 + (l >> 4) * 4;
    const int ocol = wc * 64 + l15;
    if (EPI == 2) {
        float* C = (float*)Cp + (long)z * sCz;
#pragma unroll
        for (int m = 0; m < 4; ++m)
#pragma unroll
            for (int n = 0; n < 4; ++n)
#pragma unroll
                for (int r = 0; r < 4; ++r)
                    C[(long)(m0 + orow + m * 16 + r) * ldc + (n0 + ocol + n * 16)] =
                        acc[m][n][r] * scale;
    } else {
        unsigned short* C = (unsigned short*)Cp + (long)z * sCz;
#pragma unroll
        for (int n = 0; n < 4; ++n) {
            const float bv = bias[n0 + ocol + n * 16];
#pragma unroll
            for (int m = 0; m < 4; ++m)
#pragma unroll
                for (int r = 0; r < 4; ++r) {
                    float v = acc[m][n][r] + bv;
                    if (EPI == 0) v = fmaxf(v, 0.f);
                    C[(long)(m0 + orow + m * 16 + r) * ldc + (n0 + ocol + n * 16)] = f2bf(v);
                }
        }
    }
}

__global__ __launch_bounds__(256)
void col_stats(const float* __restrict__ A, float* __restrict__ Mst, float* __restrict__ RS)
{
    __shared__ float red[4][64];
    const int t = threadIdx.x;
    const int kk = t & 63, ng = t >> 6;
    const int k = blockIdx.x * 64 + kk;
    const int z = blockIdx.y;
    const float* base = A + (long)z * NV_ * KTOT + k;
    float m = -3.0e38f;
    for (int n = ng * 128; n < ng * 128 + 128; ++n) m = fmaxf(m, base[(long)n * KTOT]);
    red[ng][kk] = m;
    __syncthreads();
    m = fmaxf(fmaxf(red[0][kk], red[1][kk]), fmaxf(red[2][kk], red[3][kk]));
    float s = 0.f;
    for (int n = ng * 128; n < ng * 128 + 128; ++n) s += __expf(base[(long)n * KTOT] - m);
    __syncthreads();
    red[ng][kk] = s;
    __syncthreads();
    if (ng == 0) {
        s = red[0][kk] + red[1][kk] + red[2][kk] + red[3][kk];
        Mst[(long)z * KTOT + k] = m;
        RS[(long)z * KTOT + k]  = 1.f / s;
    }
}

__global__ __launch_bounds__(256)
void attn_mfma(const float* __restrict__ Ap, const unsigned short* __restrict__ KVt,
               const float* __restrict__ Mstp, const float* __restrict__ RSp,
               float* __restrict__ Cp, int nx, int tpc)
{
    __shared__ unsigned short As[128 * 32];
    __shared__ unsigned short Bs[128 * 32];

    const int tid = threadIdx.x;
    const int w = tid >> 6, l = tid & 63;
    const int wr = w >> 1, wc = w & 1;
    const int l15 = l & 15, kg = l >> 4;
    const int srow = l >> 2, scol = (l & 3) * 8;
    int n0, m0, z;
    supertile(nx, tpc, n0, m0, z);

    const float* A = Ap + (long)z * NV_ * KTOT;
    const unsigned short* Bg = KVt + (long)z * D_ * KTOT;
    const float* Mz = Mstp + (long)z * KTOT;
    const float* Rz = RSp  + (long)z * KTOT;
    float* C = Cp + (long)z * NV_ * D_;

    const int ar = tid >> 1;
    const int ah = (tid & 1) * 16;

    f32x4 acc[4][4];
#pragma unroll
    for (int m = 0; m < 4; ++m)
#pragma unroll
        for (int n = 0; n < 4; ++n) acc[m][n] = (f32x4){0.f, 0.f, 0.f, 0.f};

    for (int k0 = 0; k0 < KTOT; k0 += 32) {
#pragma unroll
        for (int i = 0; i < 2; ++i) {
            const int g = i * 4 + w;
            gl_lds16(Bg + (long)(n0 + g * 16 + srow) * KTOT + (k0 + scol), &Bs[g * 512]);
        }
        const float* arow = A + (long)(m0 + ar) * KTOT + k0 + ah;
        const float4 x0 = *(const float4*)(arow);
        const float4 x1 = *(const float4*)(arow + 4);
        const float4 x2 = *(const float4*)(arow + 8);
        const float4 x3 = *(const float4*)(arow + 12);
        const float4 ma = *(const float4*)(Mz + k0 + ah);
        const float4 mb = *(const float4*)(Mz + k0 + ah + 4);
        const float4 mc = *(const float4*)(Mz + k0 + ah + 8);
        const float4 md = *(const float4*)(Mz + k0 + ah + 12);
        const float4 ra = *(const float4*)(Rz + k0 + ah);
        const float4 rb = *(const float4*)(Rz + k0 + ah + 4);
        const float4 rc = *(const float4*)(Rz + k0 + ah + 8);
        const float4 rd = *(const float4*)(Rz + k0 + ah + 12);
        const unsigned q0 = pk2(__expf(x0.x - ma.x) * ra.x, __expf(x0.y - ma.y) * ra.y);
        const unsigned q1 = pk2(__expf(x0.z - ma.z) * ra.z, __expf(x0.w - ma.w) * ra.w);
        const unsigned q2 = pk2(__expf(x1.x - mb.x) * rb.x, __expf(x1.y - mb.y) * rb.y);
        const unsigned q3 = pk2(__expf(x1.z - mb.z) * rb.z, __expf(x1.w - mb.w) * rb.w);
        const unsigned q4 = pk2(__expf(x2.x - mc.x) * rc.x, __expf(x2.y - mc.y) * rc.y);
        const unsigned q5 = pk2(__expf(x2.z - mc.z) * rc.z, __expf(x2.w - mc.w) * rc.w);
        const unsigned q6 = pk2(__expf(x3.x - md.x) * rd.x, __expf(x3.y - md.y) * rd.y);
        const unsigned q7 = pk2(__expf(x3.z - md.z) * rd.z, __expf(x3.w - md.w) * rd.w);
        *(uint4*)&As[ar * 32 + ah]     = make_uint4(q0, q1, q2, q3);
        *(uint4*)&As[ar * 32 + ah + 8] = make_uint4(q4, q5, q6, q7);
        __syncthreads();

        bf8_t af[4], bf[4];
#pragma unroll
        for (int m = 0; m < 4; ++m)
            af[m] = *(const bf8_t*)&As[(wr * 64 + m * 16 + l15) * 32 + kg * 8];
#pragma unroll
        for (int n = 0; n < 4; ++n)
            bf[n] = *(const bf8_t*)&Bs[(wc * 64 + n * 16 + l15) * 32 + kg * 8];
#pragma unroll
        for (int m = 0; m < 4; ++m)
#pragma unroll
            for (int n = 0; n < 4; ++n)
                acc[m][n] = __builtin_amdgcn_mfma_f32_16x16x32_bf16(af[m], bf[n], acc[m][n], 0, 0, 0);
        __syncthreads();
    }

    const int orow = wr * 64 + (l >> 4) * 4;
    const int ocol = wc * 64 + l15;
#pragma unroll
    for (int m = 0; m < 4; ++m)
#pragma unroll
        for (int n = 0; n < 4; ++n)
#pragma unroll
            for (int r = 0; r < 4; ++r)
                C[(long)(m0 + orow + m * 16 + r) * D_ + (n0 + ocol + n * 16)] = acc[m][n][r];
}

__global__ __launch_bounds__(256)
void tr2bf_f(const float* __restrict__ src, long sSz, int ldS,
             unsigned short* __restrict__ dst, long sDz, int ldD)
{
    __shared__ unsigned short T[64][65];
    const int t = threadIdx.x;
    const int rr = t >> 2, cc = (t & 3) * 16;
    const int r0 = blockIdx.x * 64, c0 = blockIdx.y * 64, z = blockIdx.z;
    const float* S = src + (long)z * sSz + (long)(r0 + rr) * ldS + c0 + cc;
    const float4 a = *(const float4*)(S);
    const float4 b = *(const float4*)(S + 4);
    const float4 c = *(const float4*)(S + 8);
    const float4 d = *(const float4*)(S + 12);
    unsigned short* Tr = &T[rr][cc];
    Tr[0] = f2bf(a.x); Tr[1] = f2bf(a.y); Tr[2]  = f2bf(a.z); Tr[3]  = f2bf(a.w);
    Tr[4] = f2bf(b.x); Tr[5] = f2bf(b.y); Tr[6]  = f2bf(b.z); Tr[7]  = f2bf(b.w);
    Tr[8] = f2bf(c.x); Tr[9] = f2bf(c.y); Tr[10] = f2bf(c.z); Tr[11] = f2bf(c.w);
    Tr[12] = f2bf(d.x); Tr[13] = f2bf(d.y); Tr[14] = f2bf(d.z); Tr[15] = f2bf(d.w);
    __syncthreads();
    unsigned short v[16];
#pragma unroll
    for (int j = 0; j < 16; ++j) v[j] = T[cc + j][rr];
    unsigned q[8];
#pragma unroll
    for (int j = 0; j < 8; ++j) q[j] = (unsigned)v[2 * j] | ((unsigned)v[2 * j + 1] << 16);
    unsigned short* Dp = dst + (long)z * sDz + (long)(c0 + rr) * ldD + r0 + cc;
    *(uint4*)Dp       = make_uint4(q[0], q[1], q[2], q[3]);
    *(uint4*)(Dp + 8) = make_uint4(q[4], q[5], q[6], q[7]);
}

__global__ __launch_bounds__(256)
void tr2bf_h(const unsigned short* __restrict__ src, long sSz, int ldS,
             unsigned short* __restrict__ dst, long sDz, int ldD)
{
    __shared__ unsigned short T[64][65];
    const int t = threadIdx.x;
    const int rr = t >> 2, cc = (t & 3) * 16;
    const int r0 = blockIdx.x * 64, c0 = blockIdx.y * 64, z = blockIdx.z;
    const unsigned short* S = src + (long)z * sSz + (long)(r0 + rr) * ldS + c0 + cc;
    const uint4 qa = *(const uint4*)(S);
    const uint4 qb = *(const uint4*)(S + 8);
    unsigned short* Tr = &T[rr][cc];
    Tr[0]  = qa.x & 0xFFFF; Tr[1]  = qa.x >> 16; Tr[2]  = qa.y & 0xFFFF; Tr[3]  = qa.y >> 16;
    Tr[4]  = qa.z & 0xFFFF; Tr[5]  = qa.z >> 16; Tr[6]  = qa.w & 0xFFFF; Tr[7]  = qa.w >> 16;
    Tr[8]  = qb.x & 0xFFFF; Tr[9]  = qb.x >> 16; Tr[10] = qb.y & 0xFFFF; Tr[11] = qb.y >> 16;
    Tr[12] = qb.z & 0xFFFF; Tr[13] = qb.z >> 16; Tr[14] = qb.w & 0xFFFF; Tr[15] = qb.w >> 16;
    __syncthreads();
    unsigned short v[16];
#pragma unroll
    for (int j = 0; j < 16; ++j) v[j] = T[cc + j][rr];
    unsigned q[8];
#pragma unroll
    for (int j = 0; j < 8; ++j) q[j] = (unsigned)v[2 * j] | ((unsigned)v[2 * j + 1] << 16);
    unsigned short* Dp = dst + (long)z * sDz + (long)(c0 + rr) * ldD + r0 + cc;
    *(uint4*)Dp       = make_uint4(q[0], q[1], q[2], q[3]);
    *(uint4*)(Dp + 8) = make_uint4(q[4], q[5], q[6], q[7]);
}

__global__ __launch_bounds__(256)
void cvt_bf(const float* __restrict__ src, unsigned short* __restrict__ dst, long n)
{
    const long i = ((long)blockIdx.x * 256 + threadIdx.x) * 8;
    if (i >= n) return;
    const float4 a = *(const float4*)(src + i);
    const float4 b = *(const float4*)(src + i + 4);
    *(uint4*)(dst + i) = make_uint4(pk2(a.x, a.y), pk2(a.z, a.w), pk2(b.x, b.y), pk2(b.z, b.w));
}

// ---------------------------------------------------------------------------
extern "C" void kernel_launch(void* const* d_in, const int* in_sizes, int n_in,
                              void* d_out, int out_size, void* d_ws, size_t ws_size,
                              hipStream_t stream)
{
    (void)in_sizes; (void)n_in; (void)out_size;

    const float* V   = (const float*)d_in[0];
    const float* L   = (const float*)d_in[1];
    const float* w1V = (const float*)d_in[4];
    const float* b1V = (const float*)d_in[5];
    const float* w2V = (const float*)d_in[6];
    const float* b2V = (const float*)d_in[7];
    const float* w1L = (const float*)d_in[8];
    const float* b1L = (const float*)d_in[9];
    const float* w2L = (const float*)d_in[10];
    const float* b2L = (const float*)d_in[11];

    float* outA = (float*)d_out;                      // [B, NV, KTOT]
    float* outV = outA + (size_t)B_ * NV_ * KTOT;     // [B, NV, D]

    unsigned short* w1Vt = (unsigned short*)d_ws;                 // [H][D]
    unsigned short* w2Vt = w1Vt + (size_t)H_ * D_;                // [D][H]
    unsigned short* w1Lt = w2Vt + (size_t)D_ * H_;
    unsigned short* w2Lt = w1Lt + (size_t)H_ * D_;
    unsigned short* pool = w2Lt + (size_t)D_ * H_;

    const size_t perb_us = (size_t)NV_ * D_ + (size_t)NL_ * D_ + (size_t)NV_ * H_ +
                           (size_t)NV_ * D_ + (size_t)NL_ * D_ + (size_t)NV_ * D_ +
                           (size_t)D_ * KTOT;
    const size_t perb_bytes = perb_us * 2 + 2 * (size_t)KTOT * sizeof(float);
    const size_t persist_bytes = (size_t)4 * H_ * D_ * 2;
    const size_t avail = (ws_size > persist_bytes + 256) ? ws_size - persist_bytes - 256 : 0;
    int bc = (int)(avail / perb_bytes);
    if (bc > B_) bc = B_;
    if (bc < 1)  bc = 1;

    unsigned short* Vb  = pool;
    unsigned short* Lb  = Vb  + (size_t)bc * NV_ * D_;
    unsigned short* hid = Lb  + (size_t)bc * NL_ * D_;
    unsigned short* fV  = hid + (size_t)bc * NV_ * H_;
    unsigned short* fLL = fV  + (size_t)bc * NV_ * D_;
    unsigned short* fLV = fLL + (size_t)bc * NL_ * D_;
    unsigned short* KVt = fLV + (size_t)bc * NV_ * D_;
    float* Mst = (float*)(KVt + (size_t)bc * D_ * KTOT);
    float* RS  = Mst + (size_t)bc * KTOT;

    const dim3 blk(256);
    const dim3 blk5(512);

    // allow 128 KiB dynamic LDS for the 8-phase GEMM (idempotent; first call
    // happens on the pre-capture correctness invocation)
    {
        auto* f0 = gemm256<0>;
        auto* f1 = gemm256<1>;
        hipFuncSetAttribute((const void*)f0, hipFuncAttributeMaxDynamicSharedMemorySize, 131072);
        hipFuncSetAttribute((const void*)f1, hipFuncAttributeMaxDynamicSharedMemorySize, 131072);
    }

    tr2bf_f<<<dim3(D_ / 64, H_ / 64, 1), blk, 0, stream>>>(w1V, 0, H_, w1Vt, 0, D_);
    tr2bf_f<<<dim3(H_ / 64, D_ / 64, 1), blk, 0, stream>>>(w2V, 0, D_, w2Vt, 0, H_);
    tr2bf_f<<<dim3(D_ / 64, H_ / 64, 1), blk, 0, stream>>>(w1L, 0, H_, w1Lt, 0, D_);
    tr2bf_f<<<dim3(H_ / 64, D_ / 64, 1), blk, 0, stream>>>(w2L, 0, D_, w2Lt, 0, H_);

    for (int b0 = 0; b0 < B_; b0 += bc) {
        const int cur = (B_ - b0 < bc) ? (B_ - b0) : bc;

        cvt_bf<<<dim3(cur * NV_ * D_ / 2048), blk, 0, stream>>>(
            V + (size_t)b0 * NV_ * D_, Vb, (long)cur * NV_ * D_);
        cvt_bf<<<dim3(cur * NL_ * D_ / 2048), blk, 0, stream>>>(
            L + (size_t)b0 * NL_ * D_, Lb, (long)cur * NL_ * D_);

        // ---- 256x256 8-phase FFN GEMMs ----
        // grid helper: ntile = (N/256)*(M/256); tpc = ntile/8 (0 if not divisible)
        #define G256(M, N) dim3((unsigned)(((N) / 256) * ((M) / 256) * cur)), blk5, 131072, stream
        #define P256(M, N) (N) / 256, (((N) / 256) * ((M) / 256)), \
                           ((((N) / 256) * ((M) / 256)) % 8 == 0 ? (((N) / 256) * ((M) / 256)) / 8 : 0)

        // FFN_V(V) -> fV
        gemm256<0><<<G256(NV_, H_)>>>(Vb, (long)NV_ * D_, D_, w1Vt, 0, D_, b1V,
                                      hid, (long)NV_ * H_, H_, D_, P256(NV_, H_));
        gemm256<1><<<G256(NV_, D_)>>>(hid, (long)NV_ * H_, H_, w2Vt, 0, H_, b2V,
                                      fV, (long)NV_ * D_, D_, H_, P256(NV_, D_));
        // FFN_L(L) -> fLL
        gemm256<0><<<G256(NL_, H_)>>>(Lb, (long)NL_ * D_, D_, w1Lt, 0, D_, b1L,
                                      hid, (long)NV_ * H_, H_, D_, P256(NL_, H_));
        gemm256<1><<<G256(NL_, D_)>>>(hid, (long)NV_ * H_, H_, w2Lt, 0, H_, b2L,
                                      fLL, (long)NL_ * D_, D_, H_, P256(NL_, D_));
        // FFN_L(V) -> fLV
        gemm256<0><<<G256(NV_, H_)>>>(Vb, (long)NV_ * D_, D_, w1Lt, 0, D_, b1L,
                                      hid, (long)NV_ * H_, H_, D_, P256(NV_, H_));
        gemm256<1><<<G256(NV_, D_)>>>(hid, (long)NV_ * H_, H_, w2Lt, 0, H_, b2L,
                                      fLV, (long)NV_ * D_, D_, H_, P256(NV_, D_));
        #undef G256
        #undef P256

        // ---- A_LV / A_VV -> outA (f32, scaled), 128-tile path ----
        #define GRID(nx, ny) dim3((unsigned)((nx) * (ny) * cur)), blk
        #define SWZ(nx, ny)  (nx), ((nx) * (ny) / 8)
        mgemm<2><<<GRID(NL_ / 128, NV_ / 128), 0, stream>>>(
            fV, (long)NV_ * D_, D_, fLL, (long)NL_ * D_, D_, nullptr, SCALE_,
            outA + (size_t)b0 * NV_ * KTOT, (long)NV_ * KTOT, KTOT, D_,
            SWZ(NL_ / 128, NV_ / 128));
        mgemm<2><<<GRID(NV_ / 128, NV_ / 128), 0, stream>>>(
            fV, (long)NV_ * D_, D_, fLV, (long)NV_ * D_, D_, nullptr, SCALE_,
            outA + (size_t)b0 * NV_ * KTOT + NL_, (long)NV_ * KTOT, KTOT, D_,
            SWZ(NV_ / 128, NV_ / 128));

        tr2bf_h<<<dim3(NL_ / 64, D_ / 64, cur), blk, 0, stream>>>(
            fLL, (long)NL_ * D_, D_, KVt, (long)D_ * KTOT, KTOT);
        tr2bf_h<<<dim3(NV_ / 64, D_ / 64, cur), blk, 0, stream>>>(
            fV, (long)NV_ * D_, D_, KVt + NL_, (long)D_ * KTOT, KTOT);

        col_stats<<<dim3(KTOT / 64, cur), blk, 0, stream>>>(
            outA + (size_t)b0 * NV_ * KTOT, Mst, RS);

        attn_mfma<<<GRID(D_ / 128, NV_ / 128), 0, stream>>>(
            outA + (size_t)b0 * NV_ * KTOT, KVt, Mst, RS,
            outV + (size_t)b0 * NV_ * D_, SWZ(D_ / 128, NV_ / 128));
        #undef GRID
        #undef SWZ
    }
}

// Round 5
// 938.407 us; speedup vs baseline: 9.0480x; 1.0394x over previous
//
#include <hip/hip_runtime.h>
#include <stdint.h>

#define B_   32
#define NV_  512
#define NL_  256
#define D_   1024
#define H_   4096
#define KTOT 768
#define SCALE_ 0.03125f   // 1/sqrt(1024)

typedef __attribute__((ext_vector_type(8))) __bf16 bf8_t;
typedef __attribute__((ext_vector_type(4))) float f32x4;

__device__ __forceinline__ unsigned short f2bf(float f) {
    unsigned u = __float_as_uint(f);
    u += 0x7FFFu + ((u >> 16) & 1u);       // round-to-nearest-even
    return (unsigned short)(u >> 16);
}
__device__ __forceinline__ unsigned pk2(float lo, float hi) {
    return (unsigned)f2bf(lo) | ((unsigned)f2bf(hi) << 16);
}

// async global->LDS, 16B per lane. LDS dest = wave-uniform base + lane*16.
__device__ __forceinline__ void gl_lds16(const void* g, const void* lds) {
    __builtin_amdgcn_global_load_lds(
        (const __attribute__((address_space(1))) unsigned int*)(uintptr_t)g,
        (__attribute__((address_space(3))) unsigned int*)(unsigned)(uintptr_t)lds,
        16, 0, 0);
}

#define SBAR() asm volatile("s_barrier" ::: "memory")
#define VMC4() asm volatile("s_waitcnt vmcnt(4)" ::: "memory")
#define VMC0() asm volatile("s_waitcnt vmcnt(0)" ::: "memory")

// ===========================================================================
// 256x256 8-phase bf16 MFMA GEMM (T2+T3+T4+T5). 512 threads = 8 waves (2Mx4N).
// A: [M][K] bf16 row-major, B: [N][K] bf16 row-major (B^T layout).
// Per wave: 128x64 output = 8 m-frags x 4 n-frags of 16x16, BK=64 (2 k-slices).
// LDS 128 KiB dynamic: A[buf][half] + B[buf][half], 16 KiB each region,
// rows 128B; element (r,c) at byte r*128 + ((2c) ^ ((r&7)<<4))  (bank swizzle).
// Staged via global_load_lds with inverse-swizzled SOURCE address (linear dest).
// Schedule: iteration computes tiles t (buf0, phases 0-3) and t+1 (buf1, 4-7);
// phase p stages half-tile g=4t+6+p (parts per tile: 0=Bh0,1=Bh1,2=Ah0,3=Ah1;
// B frees after q1, A after q2 -> every stage lands >=1 barrier after last read).
// vmcnt(4) before closing barrier of phases 3 and 7 only (counted, never 0).
// Epilogue: per-wave LDS repack (bias+relu+f2bf -> ds_write_b16 conflict-free
// 136B-stride scratch; ds_read_b128 + uint4 stores = full-cacheline writes).
// EPI: 0 = relu(acc+bias)->bf16 ; 1 = acc+bias->bf16
// ===========================================================================
template<int EPI>
__global__ __launch_bounds__(512, 1)
void gemm256(const unsigned short* __restrict__ Ab, long sAz, int lda,
             const unsigned short* __restrict__ Bb, long sBz, int ldb,
             const float* __restrict__ bias,
             unsigned short* __restrict__ Cp, long sCz, int ldc, int K,
             int nx, int ntile, int tpc)
{
    extern __shared__ unsigned char lds[];
    unsigned char* const ldsA = lds;            // (buf*2+half)*16384
    unsigned char* const ldsB = lds + 65536;    // (buf*2+half)*16384

    const int tid = threadIdx.x;
    const int w = tid >> 6, l = tid & 63;
    const int wr = w >> 2, wc = w & 3;          // 2 x 4 wave grid
    const int lrow = l & 15;
    const int kg = l >> 4;

    // XCD-chunked tile decode (tpc = ntile/8 when ntile%8==0, else 0 -> plain)
    int t_, z;
    {
        const int bid = blockIdx.x;
        if (tpc > 0) { const int r = bid >> 3, c = bid & 7; z = r / tpc; t_ = c * tpc + r % tpc; }
        else         { z = bid / ntile; t_ = bid - z * ntile; }
    }
    const int n0 = (t_ % nx) * 256, m0 = (t_ / nx) * 256;

    const unsigned short* A  = Ab + (long)z * sAz;
    const unsigned short* Bg = Bb + (long)z * sBz;

    // staging geometry: thread tid covers linear LDS bytes [tid*16, +16) per issue
    const int srow = tid >> 3;                               // row 0..63 within 64-row block
    const int scol = ((tid & 7) * 8) ^ ((srow & 7) << 3);    // inverse-swizzled src col (bf16)
    const int ntk = K >> 6;                                  // # K-tiles (even)

    // ds-read swizzled column byte offsets for k-slice 0 / 1
    const int cs0 = (((l >> 4) * 16)) ^ ((l & 7) << 4);
    const int cs1 = (64 + ((l >> 4) * 16)) ^ ((l & 7) << 4);

    f32x4 acc[8][4];
#pragma unroll
    for (int i = 0; i < 8; ++i)
#pragma unroll
        for (int j = 0; j < 4; ++j) acc[i][j] = (f32x4){0.f, 0.f, 0.f, 0.f};

    auto stage = [&](int tau, int part) {
        const int buf = tau & 1;                         // parity from UNclamped tau
        const int kt = (tau < ntk) ? tau : (ntk - 1);    // clamp source only
        const unsigned short* s; unsigned char* d; int ld;
        if (part < 2) { ld = ldb;
            s = Bg + (long)(n0 + part * 128 + srow) * ldb + kt * 64 + scol;
            d = ldsB + (buf * 2 + part) * 16384 + w * 1024;
        } else { ld = lda; const int h = part - 2;
            s = A + (long)(m0 + h * 128 + srow) * lda + kt * 64 + scol;
            d = ldsA + (buf * 2 + h) * 16384 + w * 1024;
        }
        gl_lds16(s, d);
        gl_lds16(s + (long)64 * ld, d + 8192);
    };
    auto rdA = [&](int buf, int mf, int cs) -> bf8_t {
        return *(const bf8_t*)(ldsA + (buf * 2 + wr) * 16384 + (mf * 16 + lrow) * 128 + cs);
    };
    auto rdB = [&](int buf, int nf, int cs) -> bf8_t {
        return *(const bf8_t*)(ldsB + (buf * 2 + (wc >> 1)) * 16384 +
                               ((wc & 1) * 64 + nf * 16 + lrow) * 128 + cs);
    };

    // ---- prologue: tile0 all parts, tile1 B halves; wait tile0 landed ----
    stage(0, 0); stage(0, 1); stage(0, 2); stage(0, 3);
    stage(1, 0); stage(1, 1);
    VMC4();
    SBAR();

    bf8_t aR[4][2], bR0[2][2], bR1[2][2];

    for (int t = 0; t < ntk; t += 2) {
        // ================= tile t (buf0) =================
        // p0 (q0): read A mf0-3 + B nf0-1; stage (t+1, A h0)
#pragma unroll
        for (int mf = 0; mf < 4; ++mf) { aR[mf][0] = rdA(0, mf, cs0); aR[mf][1] = rdA(0, mf, cs1); }
#pragma unroll
        for (int nf = 0; nf < 2; ++nf) { bR0[nf][0] = rdB(0, nf, cs0); bR0[nf][1] = rdB(0, nf, cs1); }
        stage(t + 1, 2);
        SBAR();
        __builtin_amdgcn_s_setprio(1);
#pragma unroll
        for (int mf = 0; mf < 4; ++mf)
#pragma unroll
            for (int nf = 0; nf < 2; ++nf) {
                acc[mf][nf] = __builtin_amdgcn_mfma_f32_16x16x32_bf16(aR[mf][0], bR0[nf][0], acc[mf][nf], 0, 0, 0);
                acc[mf][nf] = __builtin_amdgcn_mfma_f32_16x16x32_bf16(aR[mf][1], bR0[nf][1], acc[mf][nf], 0, 0, 0);
            }
        __builtin_amdgcn_s_setprio(0);
        SBAR();

        // p1 (q1): read B nf2-3; stage (t+1, A h1)
#pragma unroll
        for (int nf = 0; nf < 2; ++nf) { bR1[nf][0] = rdB(0, nf + 2, cs0); bR1[nf][1] = rdB(0, nf + 2, cs1); }
        stage(t + 1, 3);
        SBAR();
        __builtin_amdgcn_s_setprio(1);
#pragma unroll
        for (int mf = 0; mf < 4; ++mf)
#pragma unroll
            for (int nf = 0; nf < 2; ++nf) {
                acc[mf][nf + 2] = __builtin_amdgcn_mfma_f32_16x16x32_bf16(aR[mf][0], bR1[nf][0], acc[mf][nf + 2], 0, 0, 0);
                acc[mf][nf + 2] = __builtin_amdgcn_mfma_f32_16x16x32_bf16(aR[mf][1], bR1[nf][1], acc[mf][nf + 2], 0, 0, 0);
            }
        __builtin_amdgcn_s_setprio(0);
        SBAR();

        // p2 (q2): read A mf4-7; stage (t+2, B h0)
#pragma unroll
        for (int mf = 0; mf < 4; ++mf) { aR[mf][0] = rdA(0, mf + 4, cs0); aR[mf][1] = rdA(0, mf + 4, cs1); }
        stage(t + 2, 0);
        SBAR();
        __builtin_amdgcn_s_setprio(1);
#pragma unroll
        for (int mf = 0; mf < 4; ++mf)
#pragma unroll
            for (int nf = 0; nf < 2; ++nf) {
                acc[mf + 4][nf] = __builtin_amdgcn_mfma_f32_16x16x32_bf16(aR[mf][0], bR0[nf][0], acc[mf + 4][nf], 0, 0, 0);
                acc[mf + 4][nf] = __builtin_amdgcn_mfma_f32_16x16x32_bf16(aR[mf][1], bR0[nf][1], acc[mf + 4][nf], 0, 0, 0);
            }
        __builtin_amdgcn_s_setprio(0);
        SBAR();

        // p3 (q3): stage (t+2, B h1); vmcnt(4) -> tile t+1 fully landed
        stage(t + 2, 1);
        SBAR();
        __builtin_amdgcn_s_setprio(1);
#pragma unroll
        for (int mf = 0; mf < 4; ++mf)
#pragma unroll
            for (int nf = 0; nf < 2; ++nf) {
                acc[mf + 4][nf + 2] = __builtin_amdgcn_mfma_f32_16x16x32_bf16(aR[mf][0], bR1[nf][0], acc[mf + 4][nf + 2], 0, 0, 0);
                acc[mf + 4][nf + 2] = __builtin_amdgcn_mfma_f32_16x16x32_bf16(aR[mf][1], bR1[nf][1], acc[mf + 4][nf + 2], 0, 0, 0);
            }
        __builtin_amdgcn_s_setprio(0);
        VMC4();
        SBAR();

        // ================= tile t+1 (buf1) =================
        // p4 (q0): stage (t+2, A h0)
#pragma unroll
        for (int mf = 0; mf < 4; ++mf) { aR[mf][0] = rdA(1, mf, cs0); aR[mf][1] = rdA(1, mf, cs1); }
#pragma unroll
        for (int nf = 0; nf < 2; ++nf) { bR0[nf][0] = rdB(1, nf, cs0); bR0[nf][1] = rdB(1, nf, cs1); }
        stage(t + 2, 2);
        SBAR();
        __builtin_amdgcn_s_setprio(1);
#pragma unroll
        for (int mf = 0; mf < 4; ++mf)
#pragma unroll
            for (int nf = 0; nf < 2; ++nf) {
                acc[mf][nf] = __builtin_amdgcn_mfma_f32_16x16x32_bf16(aR[mf][0], bR0[nf][0], acc[mf][nf], 0, 0, 0);
                acc[mf][nf] = __builtin_amdgcn_mfma_f32_16x16x32_bf16(aR[mf][1], bR0[nf][1], acc[mf][nf], 0, 0, 0);
            }
        __builtin_amdgcn_s_setprio(0);
        SBAR();

        // p5 (q1): stage (t+2, A h1)
#pragma unroll
        for (int nf = 0; nf < 2; ++nf) { bR1[nf][0] = rdB(1, nf + 2, cs0); bR1[nf][1] = rdB(1, nf + 2, cs1); }
        stage(t + 2, 3);
        SBAR();
        __builtin_amdgcn_s_setprio(1);
#pragma unroll
        for (int mf = 0; mf < 4; ++mf)
#pragma unroll
            for (int nf = 0; nf < 2; ++nf) {
                acc[mf][nf + 2] = __builtin_amdgcn_mfma_f32_16x16x32_bf16(aR[mf][0], bR1[nf][0], acc[mf][nf + 2], 0, 0, 0);
                acc[mf][nf + 2] = __builtin_amdgcn_mfma_f32_16x16x32_bf16(aR[mf][1], bR1[nf][1], acc[mf][nf + 2], 0, 0, 0);
            }
        __builtin_amdgcn_s_setprio(0);
        SBAR();

        // p6 (q2): stage (t+3, B h0)
#pragma unroll
        for (int mf = 0; mf < 4; ++mf) { aR[mf][0] = rdA(1, mf + 4, cs0); aR[mf][1] = rdA(1, mf + 4, cs1); }
        stage(t + 3, 0);
        SBAR();
        __builtin_amdgcn_s_setprio(1);
#pragma unroll
        for (int mf = 0; mf < 4; ++mf)
#pragma unroll
            for (int nf = 0; nf < 2; ++nf) {
                acc[mf + 4][nf] = __builtin_amdgcn_mfma_f32_16x16x32_bf16(aR[mf][0], bR0[nf][0], acc[mf + 4][nf], 0, 0, 0);
                acc[mf + 4][nf] = __builtin_amdgcn_mfma_f32_16x16x32_bf16(aR[mf][1], bR0[nf][1], acc[mf + 4][nf], 0, 0, 0);
            }
        __builtin_amdgcn_s_setprio(0);
        SBAR();

        // p7 (q3): stage (t+3, B h1); vmcnt(4) -> tile t+2 fully landed
        stage(t + 3, 1);
        SBAR();
        __builtin_amdgcn_s_setprio(1);
#pragma unroll
        for (int mf = 0; mf < 4; ++mf)
#pragma unroll
            for (int nf = 0; nf < 2; ++nf) {
                acc[mf + 4][nf + 2] = __builtin_amdgcn_mfma_f32_16x16x32_bf16(aR[mf][0], bR1[nf][0], acc[mf + 4][nf + 2], 0, 0, 0);
                acc[mf + 4][nf + 2] = __builtin_amdgcn_mfma_f32_16x16x32_bf16(aR[mf][1], bR1[nf][1], acc[mf + 4][nf + 2], 0, 0, 0);
            }
        __builtin_amdgcn_s_setprio(0);
        VMC4();
        SBAR();
    }

    // ---- epilogue: per-wave LDS repack -> full-cacheline bf16 stores ----
    VMC0();   // own garbage tail stages landed
    SBAR();   // every wave drained -> LDS safe to repurpose

    unsigned short* C = Cp + (long)z * sCz;
    unsigned char* const scr = lds + w * 16384;   // 16 KiB per-wave scratch

    float bv[4];
#pragma unroll
    for (int nf = 0; nf < 4; ++nf) bv[nf] = bias[n0 + wc * 64 + nf * 16 + lrow];

#pragma unroll
    for (int p = 0; p < 2; ++p) {
        // pack 64 rows (mf = 4p..4p+3) into scratch, stride 136B (bank-spread)
#pragma unroll
        for (int mf = 0; mf < 4; ++mf)
#pragma unroll
            for (int nf = 0; nf < 4; ++nf)
#pragma unroll
                for (int r = 0; r < 4; ++r) {
                    float v = acc[4 * p + mf][nf][r] + bv[nf];
                    if (EPI == 0) v = fmaxf(v, 0.f);
                    *(unsigned short*)(scr + (mf * 16 + kg * 4 + r) * 136 +
                                       (nf * 16 + lrow) * 2) = f2bf(v);
                }
        // coalesced out: 8 lanes x 16B = 128B contiguous per row
#pragma unroll
        for (int it = 0; it < 8; ++it) {
            const int rr = it * 8 + (l >> 3);
            const uint4 q = *(const uint4*)(scr + rr * 136 + (l & 7) * 16);
            *(uint4*)(C + (long)(m0 + wr * 128 + p * 64 + rr) * ldc +
                      (n0 + wc * 64 + (l & 7) * 8)) = q;
        }
    }
}

// ===========================================================================
// 128-tile kernels (A_LV/A_VV + attn) — unchanged from round 3.
// ===========================================================================
__device__ __forceinline__ void supertile(int nx, int tpc, int& n0, int& m0, int& z)
{
    const int bid = blockIdx.x;
    const int r = bid >> 3, c = bid & 7;
    z = r / tpc;
    const int t = c * tpc + (r % tpc);
    n0 = (t % nx) * 128;
    m0 = (t / nx) * 128;
}

template<int EPI>   // only EPI=2 used: C = acc*scale -> f32
__global__ __launch_bounds__(256)
void mgemm(const unsigned short* __restrict__ Ab, long sAz, int lda,
           const unsigned short* __restrict__ Bb, long sBz, int ldb,
           const float* __restrict__ bias, float scale,
           void* __restrict__ Cp, long sCz, int ldc, int K,
           int nx, int tpc)
{
    __shared__ unsigned short As[128 * 32];
    __shared__ unsigned short Bs[128 * 32];

    const int tid = threadIdx.x;
    const int w = tid >> 6, l = tid & 63;
    const int wr = w >> 1, wc = w & 1;
    const int l15 = l & 15, kg = l >> 4;
    const int srow = l >> 2, scol = (l & 3) * 8;
    int n0, m0, z;
    supertile(nx, tpc, n0, m0, z);

    const unsigned short* A  = Ab + (long)z * sAz;
    const unsigned short* Bg = Bb + (long)z * sBz;

    f32x4 acc[4][4];
#pragma unroll
    for (int m = 0; m < 4; ++m)
#pragma unroll
        for (int n = 0; n < 4; ++n) acc[m][n] = (f32x4){0.f, 0.f, 0.f, 0.f};

    for (int k0 = 0; k0 < K; k0 += 32) {
#pragma unroll
        for (int i = 0; i < 2; ++i) {
            const int g = i * 4 + w;
            gl_lds16(A  + (long)(m0 + g * 16 + srow) * lda + (k0 + scol), &As[g * 512]);
            gl_lds16(Bg + (long)(n0 + g * 16 + srow) * ldb + (k0 + scol), &Bs[g * 512]);
        }
        __syncthreads();

        bf8_t af[4], bf[4];
#pragma unroll
        for (int m = 0; m < 4; ++m)
            af[m] = *(const bf8_t*)&As[(wr * 64 + m * 16 + l15) * 32 + kg * 8];
#pragma unroll
        for (int n = 0; n < 4; ++n)
            bf[n] = *(const bf8_t*)&Bs[(wc * 64 + n * 16 + l15) * 32 + kg * 8];
#pragma unroll
        for (int m = 0; m < 4; ++m)
#pragma unroll
            for (int n = 0; n < 4; ++n)
                acc[m][n] = __builtin_amdgcn_mfma_f32_16x16x32_bf16(af[m], bf[n], acc[m][n], 0, 0, 0);
        __syncthreads();
    }

    const int orow = wr * 64 + (l >> 4) * 4;
    const int ocol = wc * 64 + l15;
    if (EPI == 2) {
        float* C = (float*)Cp + (long)z * sCz;
#pragma unroll
        for (int m = 0; m < 4; ++m)
#pragma unroll
            for (int n = 0; n < 4; ++n)
#pragma unroll
                for (int r = 0; r < 4; ++r)
                    C[(long)(m0 + orow + m * 16 + r) * ldc + (n0 + ocol + n * 16)] =
                        acc[m][n][r] * scale;
    } else {
        unsigned short* C = (unsigned short*)Cp + (long)z * sCz;
#pragma unroll
        for (int n = 0; n < 4; ++n) {
            const float bvv = bias[n0 + ocol + n * 16];
#pragma unroll
            for (int m = 0; m < 4; ++m)
#pragma unroll
                for (int r = 0; r < 4; ++r) {
                    float v = acc[m][n][r] + bvv;
                    if (EPI == 0) v = fmaxf(v, 0.f);
                    C[(long)(m0 + orow + m * 16 + r) * ldc + (n0 + ocol + n * 16)] = f2bf(v);
                }
        }
    }
}

__global__ __launch_bounds__(256)
void col_stats(const float* __restrict__ A, float* __restrict__ Mst, float* __restrict__ RS)
{
    __shared__ float red[4][64];
    const int t = threadIdx.x;
    const int kk = t & 63, ng = t >> 6;
    const int k = blockIdx.x * 64 + kk;
    const int z = blockIdx.y;
    const float* base = A + (long)z * NV_ * KTOT + k;
    float m = -3.0e38f;
    for (int n = ng * 128; n < ng * 128 + 128; ++n) m = fmaxf(m, base[(long)n * KTOT]);
    red[ng][kk] = m;
    __syncthreads();
    m = fmaxf(fmaxf(red[0][kk], red[1][kk]), fmaxf(red[2][kk], red[3][kk]));
    float s = 0.f;
    for (int n = ng * 128; n < ng * 128 + 128; ++n) s += __expf(base[(long)n * KTOT] - m);
    __syncthreads();
    red[ng][kk] = s;
    __syncthreads();
    if (ng == 0) {
        s = red[0][kk] + red[1][kk] + red[2][kk] + red[3][kk];
        Mst[(long)z * KTOT + k] = m;
        RS[(long)z * KTOT + k]  = 1.f / s;
    }
}

__global__ __launch_bounds__(256)
void attn_mfma(const float* __restrict__ Ap, const unsigned short* __restrict__ KVt,
               const float* __restrict__ Mstp, const float* __restrict__ RSp,
               float* __restrict__ Cp, int nx, int tpc)
{
    __shared__ unsigned short As[128 * 32];
    __shared__ unsigned short Bs[128 * 32];

    const int tid = threadIdx.x;
    const int w = tid >> 6, l = tid & 63;
    const int wr = w >> 1, wc = w & 1;
    const int l15 = l & 15, kg = l >> 4;
    const int srow = l >> 2, scol = (l & 3) * 8;
    int n0, m0, z;
    supertile(nx, tpc, n0, m0, z);

    const float* A = Ap + (long)z * NV_ * KTOT;
    const unsigned short* Bg = KVt + (long)z * D_ * KTOT;
    const float* Mz = Mstp + (long)z * KTOT;
    const float* Rz = RSp  + (long)z * KTOT;
    float* C = Cp + (long)z * NV_ * D_;

    const int ar = tid >> 1;
    const int ah = (tid & 1) * 16;

    f32x4 acc[4][4];
#pragma unroll
    for (int m = 0; m < 4; ++m)
#pragma unroll
        for (int n = 0; n < 4; ++n) acc[m][n] = (f32x4){0.f, 0.f, 0.f, 0.f};

    for (int k0 = 0; k0 < KTOT; k0 += 32) {
#pragma unroll
        for (int i = 0; i < 2; ++i) {
            const int g = i * 4 + w;
            gl_lds16(Bg + (long)(n0 + g * 16 + srow) * KTOT + (k0 + scol), &Bs[g * 512]);
        }
        const float* arow = A + (long)(m0 + ar) * KTOT + k0 + ah;
        const float4 x0 = *(const float4*)(arow);
        const float4 x1 = *(const float4*)(arow + 4);
        const float4 x2 = *(const float4*)(arow + 8);
        const float4 x3 = *(const float4*)(arow + 12);
        const float4 ma = *(const float4*)(Mz + k0 + ah);
        const float4 mb = *(const float4*)(Mz + k0 + ah + 4);
        const float4 mc = *(const float4*)(Mz + k0 + ah + 8);
        const float4 md = *(const float4*)(Mz + k0 + ah + 12);
        const float4 ra = *(const float4*)(Rz + k0 + ah);
        const float4 rb = *(const float4*)(Rz + k0 + ah + 4);
        const float4 rc = *(const float4*)(Rz + k0 + ah + 8);
        const float4 rd = *(const float4*)(Rz + k0 + ah + 12);
        const unsigned q0 = pk2(__expf(x0.x - ma.x) * ra.x, __expf(x0.y - ma.y) * ra.y);
        const unsigned q1 = pk2(__expf(x0.z - ma.z) * ra.z, __expf(x0.w - ma.w) * ra.w);
        const unsigned q2 = pk2(__expf(x1.x - mb.x) * rb.x, __expf(x1.y - mb.y) * rb.y);
        const unsigned q3 = pk2(__expf(x1.z - mb.z) * rb.z, __expf(x1.w - mb.w) * rb.w);
        const unsigned q4 = pk2(__expf(x2.x - mc.x) * rc.x, __expf(x2.y - mc.y) * rc.y);
        const unsigned q5 = pk2(__expf(x2.z - mc.z) * rc.z, __expf(x2.w - mc.w) * rc.w);
        const unsigned q6 = pk2(__expf(x3.x - md.x) * rd.x, __expf(x3.y - md.y) * rd.y);
        const unsigned q7 = pk2(__expf(x3.z - md.z) * rd.z, __expf(x3.w - md.w) * rd.w);
        *(uint4*)&As[ar * 32 + ah]     = make_uint4(q0, q1, q2, q3);
        *(uint4*)&As[ar * 32 + ah + 8] = make_uint4(q4, q5, q6, q7);
        __syncthreads();

        bf8_t af[4], bf[4];
#pragma unroll
        for (int m = 0; m < 4; ++m)
            af[m] = *(const bf8_t*)&As[(wr * 64 + m * 16 + l15) * 32 + kg * 8];
#pragma unroll
        for (int n = 0; n < 4; ++n)
            bf[n] = *(const bf8_t*)&Bs[(wc * 64 + n * 16 + l15) * 32 + kg * 8];
#pragma unroll
        for (int m = 0; m < 4; ++m)
#pragma unroll
            for (int n = 0; n < 4; ++n)
                acc[m][n] = __builtin_amdgcn_mfma_f32_16x16x32_bf16(af[m], bf[n], acc[m][n], 0, 0, 0);
        __syncthreads();
    }

    const int orow = wr * 64 + (l >> 4) * 4;
    const int ocol = wc * 64 + l15;
#pragma unroll
    for (int m = 0; m < 4; ++m)
#pragma unroll
        for (int n = 0; n < 4; ++n)
#pragma unroll
            for (int r = 0; r < 4; ++r)
                C[(long)(m0 + orow + m * 16 + r) * D_ + (n0 + ocol + n * 16)] = acc[m][n][r];
}

__global__ __launch_bounds__(256)
void tr2bf_f(const float* __restrict__ src, long sSz, int ldS,
             unsigned short* __restrict__ dst, long sDz, int ldD)
{
    __shared__ unsigned short T[64][65];
    const int t = threadIdx.x;
    const int rr = t >> 2, cc = (t & 3) * 16;
    const int r0 = blockIdx.x * 64, c0 = blockIdx.y * 64, z = blockIdx.z;
    const float* S = src + (long)z * sSz + (long)(r0 + rr) * ldS + c0 + cc;
    const float4 a = *(const float4*)(S);
    const float4 b = *(const float4*)(S + 4);
    const float4 c = *(const float4*)(S + 8);
    const float4 d = *(const float4*)(S + 12);
    unsigned short* Tr = &T[rr][cc];
    Tr[0] = f2bf(a.x); Tr[1] = f2bf(a.y); Tr[2]  = f2bf(a.z); Tr[3]  = f2bf(a.w);
    Tr[4] = f2bf(b.x); Tr[5] = f2bf(b.y); Tr[6]  = f2bf(b.z); Tr[7]  = f2bf(b.w);
    Tr[8] = f2bf(c.x); Tr[9] = f2bf(c.y); Tr[10] = f2bf(c.z); Tr[11] = f2bf(c.w);
    Tr[12] = f2bf(d.x); Tr[13] = f2bf(d.y); Tr[14] = f2bf(d.z); Tr[15] = f2bf(d.w);
    __syncthreads();
    unsigned short v[16];
#pragma unroll
    for (int j = 0; j < 16; ++j) v[j] = T[cc + j][rr];
    unsigned q[8];
#pragma unroll
    for (int j = 0; j < 8; ++j) q[j] = (unsigned)v[2 * j] | ((unsigned)v[2 * j + 1] << 16);
    unsigned short* Dp = dst + (long)z * sDz + (long)(c0 + rr) * ldD + r0 + cc;
    *(uint4*)Dp       = make_uint4(q[0], q[1], q[2], q[3]);
    *(uint4*)(Dp + 8) = make_uint4(q[4], q[5], q[6], q[7]);
}

__global__ __launch_bounds__(256)
void tr2bf_h(const unsigned short* __restrict__ src, long sSz, int ldS,
             unsigned short* __restrict__ dst, long sDz, int ldD)
{
    __shared__ unsigned short T[64][65];
    const int t = threadIdx.x;
    const int rr = t >> 2, cc = (t & 3) * 16;
    const int r0 = blockIdx.x * 64, c0 = blockIdx.y * 64, z = blockIdx.z;
    const unsigned short* S = src + (long)z * sSz + (long)(r0 + rr) * ldS + c0 + cc;
    const uint4 qa = *(const uint4*)(S);
    const uint4 qb = *(const uint4*)(S + 8);
    unsigned short* Tr = &T[rr][cc];
    Tr[0]  = qa.x & 0xFFFF; Tr[1]  = qa.x >> 16; Tr[2]  = qa.y & 0xFFFF; Tr[3]  = qa.y >> 16;
    Tr[4]  = qa.z & 0xFFFF; Tr[5]  = qa.z >> 16; Tr[6]  = qa.w & 0xFFFF; Tr[7]  = qa.w >> 16;
    Tr[8]  = qb.x & 0xFFFF; Tr[9]  = qb.x >> 16; Tr[10] = qb.y & 0xFFFF; Tr[11] = qb.y >> 16;
    Tr[12] = qb.z & 0xFFFF; Tr[13] = qb.z >> 16; Tr[14] = qb.w & 0xFFFF; Tr[15] = qb.w >> 16;
    __syncthreads();
    unsigned short v[16];
#pragma unroll
    for (int j = 0; j < 16; ++j) v[j] = T[cc + j][rr];
    unsigned q[8];
#pragma unroll
    for (int j = 0; j < 8; ++j) q[j] = (unsigned)v[2 * j] | ((unsigned)v[2 * j + 1] << 16);
    unsigned short* Dp = dst + (long)z * sDz + (long)(c0 + rr) * ldD + r0 + cc;
    *(uint4*)Dp       = make_uint4(q[0], q[1], q[2], q[3]);
    *(uint4*)(Dp + 8) = make_uint4(q[4], q[5], q[6], q[7]);
}

__global__ __launch_bounds__(256)
void cvt_bf(const float* __restrict__ src, unsigned short* __restrict__ dst, long n)
{
    const long i = ((long)blockIdx.x * 256 + threadIdx.x) * 8;
    if (i >= n) return;
    const float4 a = *(const float4*)(src + i);
    const float4 b = *(const float4*)(src + i + 4);
    *(uint4*)(dst + i) = make_uint4(pk2(a.x, a.y), pk2(a.z, a.w), pk2(b.x, b.y), pk2(b.z, b.w));
}

// ---------------------------------------------------------------------------
extern "C" void kernel_launch(void* const* d_in, const int* in_sizes, int n_in,
                              void* d_out, int out_size, void* d_ws, size_t ws_size,
                              hipStream_t stream)
{
    (void)in_sizes; (void)n_in; (void)out_size;

    const float* V   = (const float*)d_in[0];
    const float* L   = (const float*)d_in[1];
    const float* w1V = (const float*)d_in[4];
    const float* b1V = (const float*)d_in[5];
    const float* w2V = (const float*)d_in[6];
    const float* b2V = (const float*)d_in[7];
    const float* w1L = (const float*)d_in[8];
    const float* b1L = (const float*)d_in[9];
    const float* w2L = (const float*)d_in[10];
    const float* b2L = (const float*)d_in[11];

    float* outA = (float*)d_out;                      // [B, NV, KTOT]
    float* outV = outA + (size_t)B_ * NV_ * KTOT;     // [B, NV, D]

    unsigned short* w1Vt = (unsigned short*)d_ws;                 // [H][D]
    unsigned short* w2Vt = w1Vt + (size_t)H_ * D_;                // [D][H]
    unsigned short* w1Lt = w2Vt + (size_t)D_ * H_;
    unsigned short* w2Lt = w1Lt + (size_t)H_ * D_;
    unsigned short* pool = w2Lt + (size_t)D_ * H_;

    const size_t perb_us = (size_t)NV_ * D_ + (size_t)NL_ * D_ + (size_t)NV_ * H_ +
                           (size_t)NV_ * D_ + (size_t)NL_ * D_ + (size_t)NV_ * D_ +
                           (size_t)D_ * KTOT;
    const size_t perb_bytes = perb_us * 2 + 2 * (size_t)KTOT * sizeof(float);
    const size_t persist_bytes = (size_t)4 * H_ * D_ * 2;
    const size_t avail = (ws_size > persist_bytes + 256) ? ws_size - persist_bytes - 256 : 0;
    int bc = (int)(avail / perb_bytes);
    if (bc > B_) bc = B_;
    if (bc < 1)  bc = 1;

    unsigned short* Vb  = pool;
    unsigned short* Lb  = Vb  + (size_t)bc * NV_ * D_;
    unsigned short* hid = Lb  + (size_t)bc * NL_ * D_;
    unsigned short* fV  = hid + (size_t)bc * NV_ * H_;
    unsigned short* fLL = fV  + (size_t)bc * NV_ * D_;
    unsigned short* fLV = fLL + (size_t)bc * NL_ * D_;
    unsigned short* KVt = fLV + (size_t)bc * NV_ * D_;
    float* Mst = (float*)(KVt + (size_t)bc * D_ * KTOT);
    float* RS  = Mst + (size_t)bc * KTOT;

    const dim3 blk(256);
    const dim3 blk5(512);

    {
        auto* f0 = gemm256<0>;
        auto* f1 = gemm256<1>;
        hipFuncSetAttribute((const void*)f0, hipFuncAttributeMaxDynamicSharedMemorySize, 131072);
        hipFuncSetAttribute((const void*)f1, hipFuncAttributeMaxDynamicSharedMemorySize, 131072);
    }

    tr2bf_f<<<dim3(D_ / 64, H_ / 64, 1), blk, 0, stream>>>(w1V, 0, H_, w1Vt, 0, D_);
    tr2bf_f<<<dim3(H_ / 64, D_ / 64, 1), blk, 0, stream>>>(w2V, 0, D_, w2Vt, 0, H_);
    tr2bf_f<<<dim3(D_ / 64, H_ / 64, 1), blk, 0, stream>>>(w1L, 0, H_, w1Lt, 0, D_);
    tr2bf_f<<<dim3(H_ / 64, D_ / 64, 1), blk, 0, stream>>>(w2L, 0, D_, w2Lt, 0, H_);

    for (int b0 = 0; b0 < B_; b0 += bc) {
        const int cur = (B_ - b0 < bc) ? (B_ - b0) : bc;

        cvt_bf<<<dim3(cur * NV_ * D_ / 2048), blk, 0, stream>>>(
            V + (size_t)b0 * NV_ * D_, Vb, (long)cur * NV_ * D_);
        cvt_bf<<<dim3(cur * NL_ * D_ / 2048), blk, 0, stream>>>(
            L + (size_t)b0 * NL_ * D_, Lb, (long)cur * NL_ * D_);

        #define G256(M, N) dim3((unsigned)(((N) / 256) * ((M) / 256) * cur)), blk5, 131072, stream
        #define P256(M, N) (N) / 256, (((N) / 256) * ((M) / 256)), \
                           ((((N) / 256) * ((M) / 256)) % 8 == 0 ? (((N) / 256) * ((M) / 256)) / 8 : 0)

        // FFN_V(V) -> fV
        gemm256<0><<<G256(NV_, H_)>>>(Vb, (long)NV_ * D_, D_, w1Vt, 0, D_, b1V,
                                      hid, (long)NV_ * H_, H_, D_, P256(NV_, H_));
        gemm256<1><<<G256(NV_, D_)>>>(hid, (long)NV_ * H_, H_, w2Vt, 0, H_, b2V,
                                      fV, (long)NV_ * D_, D_, H_, P256(NV_, D_));
        // FFN_L(L) -> fLL
        gemm256<0><<<G256(NL_, H_)>>>(Lb, (long)NL_ * D_, D_, w1Lt, 0, D_, b1L,
                                      hid, (long)NV_ * H_, H_, D_, P256(NL_, H_));
        gemm256<1><<<G256(NL_, D_)>>>(hid, (long)NV_ * H_, H_, w2Lt, 0, H_, b2L,
                                      fLL, (long)NL_ * D_, D_, H_, P256(NL_, D_));
        // FFN_L(V) -> fLV
        gemm256<0><<<G256(NV_, H_)>>>(Vb, (long)NV_ * D_, D_, w1Lt, 0, D_, b1L,
                                      hid, (long)NV_ * H_, H_, D_, P256(NV_, H_));
        gemm256<1><<<G256(NV_, D_)>>>(hid, (long)NV_ * H_, H_, w2Lt, 0, H_, b2L,
                                      fLV, (long)NV_ * D_, D_, H_, P256(NV_, D_));
        #undef G256
        #undef P256

        #define GRID(nx, ny) dim3((unsigned)((nx) * (ny) * cur)), blk
        #define SWZ(nx, ny)  (nx), ((nx) * (ny) / 8)
        mgemm<2><<<GRID(NL_ / 128, NV_ / 128), 0, stream>>>(
            fV, (long)NV_ * D_, D_, fLL, (long)NL_ * D_, D_, nullptr, SCALE_,
            outA + (size_t)b0 * NV_ * KTOT, (long)NV_ * KTOT, KTOT, D_,
            SWZ(NL_ / 128, NV_ / 128));
        mgemm<2><<<GRID(NV_ / 128, NV_ / 128), 0, stream>>>(
            fV, (long)NV_ * D_, D_, fLV, (long)NV_ * D_, D_, nullptr, SCALE_,
            outA + (size_t)b0 * NV_ * KTOT + NL_, (long)NV_ * KTOT, KTOT, D_,
            SWZ(NV_ / 128, NV_ / 128));

        tr2bf_h<<<dim3(NL_ / 64, D_ / 64, cur), blk, 0, stream>>>(
            fLL, (long)NL_ * D_, D_, KVt, (long)D_ * KTOT, KTOT);
        tr2bf_h<<<dim3(NV_ / 64, D_ / 64, cur), blk, 0, stream>>>(
            fV, (long)NV_ * D_, D_, KVt + NL_, (long)D_ * KTOT, KTOT);

        col_stats<<<dim3(KTOT / 64, cur), blk, 0, stream>>>(
            outA + (size_t)b0 * NV_ * KTOT, Mst, RS);

        attn_mfma<<<GRID(D_ / 128, NV_ / 128), 0, stream>>>(
            outA + (size_t)b0 * NV_ * KTOT, KVt, Mst, RS,
            outV + (size_t)b0 * NV_ * D_, SWZ(D_ / 128, NV_ / 128));
        #undef GRID
        #undef SWZ
    }
}

// Round 6
// 937.053 us; speedup vs baseline: 9.0610x; 1.0014x over previous
//
#include <hip/hip_runtime.h>
#include <stdint.h>

#define B_   32
#define NV_  512
#define NL_  256
#define D_   1024
#define H_   4096
#define KTOT 768
#define SCALE_ 0.03125f   // 1/sqrt(1024)

typedef __attribute__((ext_vector_type(8))) __bf16 bf8_t;
typedef __attribute__((ext_vector_type(4))) float f32x4;

__device__ __forceinline__ unsigned short f2bf(float f) {
    unsigned u = __float_as_uint(f);
    u += 0x7FFFu + ((u >> 16) & 1u);       // round-to-nearest-even
    return (unsigned short)(u >> 16);
}
__device__ __forceinline__ unsigned pk2(float lo, float hi) {
    return (unsigned)f2bf(lo) | ((unsigned)f2bf(hi) << 16);
}

// async global->LDS, 16B per lane. LDS dest = wave-uniform base + lane*16.
__device__ __forceinline__ void gl_lds16(const void* g, const void* lds) {
    __builtin_amdgcn_global_load_lds(
        (const __attribute__((address_space(1))) unsigned int*)(uintptr_t)g,
        (__attribute__((address_space(3))) unsigned int*)(unsigned)(uintptr_t)lds,
        16, 0, 0);
}

#define SBAR() asm volatile("s_barrier" ::: "memory")
#define VMC4() asm volatile("s_waitcnt vmcnt(4)" ::: "memory")
#define VMC0() asm volatile("s_waitcnt vmcnt(0)" ::: "memory")

// ===========================================================================
// 256x256 8-phase bf16 MFMA GEMM (T2+T3+T4+T5). 512 threads = 8 waves (2Mx4N).
// A: [M][K] bf16 row-major, B: [N][K] bf16 row-major (B^T layout).
// Round-6 changes vs round-5:
//  * bR1 reads moved INSIDE q0's MFMA window (overlap LDS with matrix pipe);
//    legal: next write to that region (stage t+2 Bh*) issues >=2 barriers later.
//  * staging source addresses hoisted: per-part per-thread pointer + kt*128B.
//  * vmcnt(4) moved before q3/q7 MFMA (equivalent drain point, same ledger).
// Everything else (swizzle, stage ledger, LDS-repack epilogue) unchanged.
// ===========================================================================
template<int EPI>
__global__ __launch_bounds__(512, 1)
void gemm256(const unsigned short* __restrict__ Ab, long sAz, int lda,
             const unsigned short* __restrict__ Bb, long sBz, int ldb,
             const float* __restrict__ bias,
             unsigned short* __restrict__ Cp, long sCz, int ldc, int K,
             int nx, int ntile, int tpc)
{
    extern __shared__ unsigned char lds[];
    unsigned char* const ldsA = lds;            // (buf*2+half)*16384
    unsigned char* const ldsB = lds + 65536;    // (buf*2+half)*16384

    const int tid = threadIdx.x;
    const int w = tid >> 6, l = tid & 63;
    const int wr = w >> 2, wc = w & 3;          // 2 x 4 wave grid
    const int lrow = l & 15;
    const int kg = l >> 4;

    int t_, z;
    {
        const int bid = blockIdx.x;
        if (tpc > 0) { const int r = bid >> 3, c = bid & 7; z = r / tpc; t_ = c * tpc + r % tpc; }
        else         { z = bid / ntile; t_ = bid - z * ntile; }
    }
    const int n0 = (t_ % nx) * 256, m0 = (t_ / nx) * 256;

    const unsigned short* A  = Ab + (long)z * sAz;
    const unsigned short* Bg = Bb + (long)z * sBz;

    const int srow = tid >> 3;                               // row 0..63 in 64-row block
    const int scol = ((tid & 7) * 8) ^ ((srow & 7) << 3);    // inverse-swizzled src col
    const int ntk = K >> 6;                                  // # K-tiles (even)

    const int cs0 = (((l >> 4) * 16)) ^ ((l & 7) << 4);
    const int cs1 = (64 + ((l >> 4) * 16)) ^ ((l & 7) << 4);

    // hoisted per-part staging source pointers (thread-specific, loop-invariant)
    const unsigned short* const sp0 = Bg + (long)(n0 +   0 + srow) * ldb + scol;
    const unsigned short* const sp1 = Bg + (long)(n0 + 128 + srow) * ldb + scol;
    const unsigned short* const sp2 = A  + (long)(m0 +   0 + srow) * lda + scol;
    const unsigned short* const sp3 = A  + (long)(m0 + 128 + srow) * lda + scol;
    const long stB = (long)64 * ldb, stA = (long)64 * lda;

    f32x4 acc[8][4];
#pragma unroll
    for (int i = 0; i < 8; ++i)
#pragma unroll
        for (int j = 0; j < 4; ++j) acc[i][j] = (f32x4){0.f, 0.f, 0.f, 0.f};

#define STG(tau, part) do {                                                   \
        const int buf_ = (tau) & 1;                                           \
        const int kt_ = ((tau) < ntk ? (tau) : ntk - 1);                      \
        if ((part) < 2) {                                                     \
            const unsigned short* s_ = ((part) == 0 ? sp0 : sp1) + (long)kt_ * 64; \
            unsigned char* d_ = ldsB + (buf_ * 2 + (part)) * 16384 + w * 1024;\
            gl_lds16(s_, d_); gl_lds16(s_ + stB, d_ + 8192);                  \
        } else {                                                              \
            const unsigned short* s_ = ((part) == 2 ? sp2 : sp3) + (long)kt_ * 64; \
            unsigned char* d_ = ldsA + (buf_ * 2 + (part) - 2) * 16384 + w * 1024; \
            gl_lds16(s_, d_); gl_lds16(s_ + stA, d_ + 8192);                  \
        } } while (0)

    auto rdA = [&](int buf, int mf, int cs) -> bf8_t {
        return *(const bf8_t*)(ldsA + (buf * 2 + wr) * 16384 + (mf * 16 + lrow) * 128 + cs);
    };
    auto rdB = [&](int buf, int nf, int cs) -> bf8_t {
        return *(const bf8_t*)(ldsB + (buf * 2 + (wc >> 1)) * 16384 +
                               ((wc & 1) * 64 + nf * 16 + lrow) * 128 + cs);
    };

#define MQ(MO, NO, AREG, BREG)                                                \
    _Pragma("unroll")                                                         \
    for (int mf = 0; mf < 4; ++mf)                                            \
    _Pragma("unroll")                                                         \
        for (int nf = 0; nf < 2; ++nf) {                                      \
            acc[(MO)+mf][(NO)+nf] = __builtin_amdgcn_mfma_f32_16x16x32_bf16(  \
                AREG[mf][0], BREG[nf][0], acc[(MO)+mf][(NO)+nf], 0, 0, 0);    \
            acc[(MO)+mf][(NO)+nf] = __builtin_amdgcn_mfma_f32_16x16x32_bf16(  \
                AREG[mf][1], BREG[nf][1], acc[(MO)+mf][(NO)+nf], 0, 0, 0);    \
        }

    // ---- prologue: tile0 all parts, tile1 B halves; wait tile0 landed ----
    STG(0, 0); STG(0, 1); STG(0, 2); STG(0, 3);
    STG(1, 0); STG(1, 1);
    VMC4();
    SBAR();

    bf8_t a0[4][2], b0r[2][2], b1r[2][2];

#define TILE4(BUF, TAU)                                                       \
    /* q0: pre-reads a0+b0r (gated by prev vmcnt+barrier) */                  \
    _Pragma("unroll")                                                         \
    for (int mf = 0; mf < 4; ++mf) { a0[mf][0] = rdA(BUF, mf, cs0);           \
                                     a0[mf][1] = rdA(BUF, mf, cs1); }         \
    _Pragma("unroll")                                                         \
    for (int nf = 0; nf < 2; ++nf) { b0r[nf][0] = rdB(BUF, nf, cs0);          \
                                     b0r[nf][1] = rdB(BUF, nf, cs1); }        \
    STG((TAU) + 1, 2);                                                        \
    SBAR();                                                                   \
    __builtin_amdgcn_s_setprio(1);                                            \
    _Pragma("unroll")                                                         \
    for (int nf = 0; nf < 2; ++nf) { b1r[nf][0] = rdB(BUF, nf + 2, cs0);      \
                                     b1r[nf][1] = rdB(BUF, nf + 2, cs1); }    \
    MQ(0, 0, a0, b0r)                                                         \
    __builtin_amdgcn_s_setprio(0);                                            \
    SBAR();                                                                   \
    /* q1 */                                                                  \
    STG((TAU) + 1, 3);                                                        \
    SBAR();                                                                   \
    __builtin_amdgcn_s_setprio(1);                                            \
    MQ(0, 2, a0, b1r)                                                         \
    __builtin_amdgcn_s_setprio(0);                                            \
    SBAR();                                                                   \
    /* q2: pre-reads a0 <- mf4..7 (a0 dead after q1) */                       \
    _Pragma("unroll")                                                         \
    for (int mf = 0; mf < 4; ++mf) { a0[mf][0] = rdA(BUF, mf + 4, cs0);       \
                                     a0[mf][1] = rdA(BUF, mf + 4, cs1); }     \
    STG((TAU) + 2, 0);                                                        \
    SBAR();                                                                   \
    __builtin_amdgcn_s_setprio(1);                                            \
    MQ(4, 0, a0, b0r)                                                         \
    __builtin_amdgcn_s_setprio(0);                                            \
    SBAR();                                                                   \
    /* q3 */                                                                  \
    STG((TAU) + 2, 1);                                                        \
    SBAR();                                                                   \
    VMC4();                                                                   \
    __builtin_amdgcn_s_setprio(1);                                            \
    MQ(4, 2, a0, b1r)                                                         \
    __builtin_amdgcn_s_setprio(0);                                            \
    SBAR();

    for (int t = 0; t < ntk; t += 2) {
        TILE4(0, t)
        TILE4(1, t + 1)
    }
#undef TILE4
#undef MQ
#undef STG

    // ---- epilogue: per-wave LDS repack -> full-cacheline bf16 stores ----
    VMC0();   // own garbage tail stages landed
    SBAR();   // every wave drained -> LDS safe to repurpose

    unsigned short* C = Cp + (long)z * sCz;
    unsigned char* const scr = lds + w * 16384;   // 16 KiB per-wave scratch

    float bv[4];
#pragma unroll
    for (int nf = 0; nf < 4; ++nf) bv[nf] = bias[n0 + wc * 64 + nf * 16 + lrow];

#pragma unroll
    for (int p = 0; p < 2; ++p) {
#pragma unroll
        for (int mf = 0; mf < 4; ++mf)
#pragma unroll
            for (int nf = 0; nf < 4; ++nf)
#pragma unroll
                for (int r = 0; r < 4; ++r) {
                    float v = acc[4 * p + mf][nf][r] + bv[nf];
                    if (EPI == 0) v = fmaxf(v, 0.f);
                    *(unsigned short*)(scr + (mf * 16 + kg * 4 + r) * 136 +
                                       (nf * 16 + lrow) * 2) = f2bf(v);
                }
#pragma unroll
        for (int it = 0; it < 8; ++it) {
            const int rr = it * 8 + (l >> 3);
            const uint4 q = *(const uint4*)(scr + rr * 136 + (l & 7) * 16);
            *(uint4*)(C + (long)(m0 + wr * 128 + p * 64 + rr) * ldc +
                      (n0 + wc * 64 + (l & 7) * 8)) = q;
        }
    }
}

// ===========================================================================
// 128-tile kernels (A_LV/A_VV + attn) — unchanged.
// ===========================================================================
__device__ __forceinline__ void supertile(int nx, int tpc, int& n0, int& m0, int& z)
{
    const int bid = blockIdx.x;
    const int r = bid >> 3, c = bid & 7;
    z = r / tpc;
    const int t = c * tpc + (r % tpc);
    n0 = (t % nx) * 128;
    m0 = (t / nx) * 128;
}

template<int EPI>   // only EPI=2 used: C = acc*scale -> f32
__global__ __launch_bounds__(256)
void mgemm(const unsigned short* __restrict__ Ab, long sAz, int lda,
           const unsigned short* __restrict__ Bb, long sBz, int ldb,
           const float* __restrict__ bias, float scale,
           void* __restrict__ Cp, long sCz, int ldc, int K,
           int nx, int tpc)
{
    __shared__ unsigned short As[128 * 32];
    __shared__ unsigned short Bs[128 * 32];

    const int tid = threadIdx.x;
    const int w = tid >> 6, l = tid & 63;
    const int wr = w >> 1, wc = w & 1;
    const int l15 = l & 15, kg = l >> 4;
    const int srow = l >> 2, scol = (l & 3) * 8;
    int n0, m0, z;
    supertile(nx, tpc, n0, m0, z);

    const unsigned short* A  = Ab + (long)z * sAz;
    const unsigned short* Bg = Bb + (long)z * sBz;

    f32x4 acc[4][4];
#pragma unroll
    for (int m = 0; m < 4; ++m)
#pragma unroll
        for (int n = 0; n < 4; ++n) acc[m][n] = (f32x4){0.f, 0.f, 0.f, 0.f};

    for (int k0 = 0; k0 < K; k0 += 32) {
#pragma unroll
        for (int i = 0; i < 2; ++i) {
            const int g = i * 4 + w;
            gl_lds16(A  + (long)(m0 + g * 16 + srow) * lda + (k0 + scol), &As[g * 512]);
            gl_lds16(Bg + (long)(n0 + g * 16 + srow) * ldb + (k0 + scol), &Bs[g * 512]);
        }
        __syncthreads();

        bf8_t af[4], bf[4];
#pragma unroll
        for (int m = 0; m < 4; ++m)
            af[m] = *(const bf8_t*)&As[(wr * 64 + m * 16 + l15) * 32 + kg * 8];
#pragma unroll
        for (int n = 0; n < 4; ++n)
            bf[n] = *(const bf8_t*)&Bs[(wc * 64 + n * 16 + l15) * 32 + kg * 8];
#pragma unroll
        for (int m = 0; m < 4; ++m)
#pragma unroll
            for (int n = 0; n < 4; ++n)
                acc[m][n] = __builtin_amdgcn_mfma_f32_16x16x32_bf16(af[m], bf[n], acc[m][n], 0, 0, 0);
        __syncthreads();
    }

    const int orow = wr * 64 + (l >> 4) * 4;
    const int ocol = wc * 64 + l15;
    if (EPI == 2) {
        float* C = (float*)Cp + (long)z * sCz;
#pragma unroll
        for (int m = 0; m < 4; ++m)
#pragma unroll
            for (int n = 0; n < 4; ++n)
#pragma unroll
                for (int r = 0; r < 4; ++r)
                    C[(long)(m0 + orow + m * 16 + r) * ldc + (n0 + ocol + n * 16)] =
                        acc[m][n][r] * scale;
    } else {
        unsigned short* C = (unsigned short*)Cp + (long)z * sCz;
#pragma unroll
        for (int n = 0; n < 4; ++n) {
            const float bvv = bias[n0 + ocol + n * 16];
#pragma unroll
            for (int m = 0; m < 4; ++m)
#pragma unroll
                for (int r = 0; r < 4; ++r) {
                    float v = acc[m][n][r] + bvv;
                    if (EPI == 0) v = fmaxf(v, 0.f);
                    C[(long)(m0 + orow + m * 16 + r) * ldc + (n0 + ocol + n * 16)] = f2bf(v);
                }
        }
    }
}

__global__ __launch_bounds__(256)
void col_stats(const float* __restrict__ A, float* __restrict__ Mst, float* __restrict__ RS)
{
    __shared__ float red[4][64];
    const int t = threadIdx.x;
    const int kk = t & 63, ng = t >> 6;
    const int k = blockIdx.x * 64 + kk;
    const int z = blockIdx.y;
    const float* base = A + (long)z * NV_ * KTOT + k;
    float m = -3.0e38f;
    for (int n = ng * 128; n < ng * 128 + 128; ++n) m = fmaxf(m, base[(long)n * KTOT]);
    red[ng][kk] = m;
    __syncthreads();
    m = fmaxf(fmaxf(red[0][kk], red[1][kk]), fmaxf(red[2][kk], red[3][kk]));
    float s = 0.f;
    for (int n = ng * 128; n < ng * 128 + 128; ++n) s += __expf(base[(long)n * KTOT] - m);
    __syncthreads();
    red[ng][kk] = s;
    __syncthreads();
    if (ng == 0) {
        s = red[0][kk] + red[1][kk] + red[2][kk] + red[3][kk];
        Mst[(long)z * KTOT + k] = m;
        RS[(long)z * KTOT + k]  = 1.f / s;
    }
}

__global__ __launch_bounds__(256)
void attn_mfma(const float* __restrict__ Ap, const unsigned short* __restrict__ KVt,
               const float* __restrict__ Mstp, const float* __restrict__ RSp,
               float* __restrict__ Cp, int nx, int tpc)
{
    __shared__ unsigned short As[128 * 32];
    __shared__ unsigned short Bs[128 * 32];

    const int tid = threadIdx.x;
    const int w = tid >> 6, l = tid & 63;
    const int wr = w >> 1, wc = w & 1;
    const int l15 = l & 15, kg = l >> 4;
    const int srow = l >> 2, scol = (l & 3) * 8;
    int n0, m0, z;
    supertile(nx, tpc, n0, m0, z);

    const float* A = Ap + (long)z * NV_ * KTOT;
    const unsigned short* Bg = KVt + (long)z * D_ * KTOT;
    const float* Mz = Mstp + (long)z * KTOT;
    const float* Rz = RSp  + (long)z * KTOT;
    float* C = Cp + (long)z * NV_ * D_;

    const int ar = tid >> 1;
    const int ah = (tid & 1) * 16;

    f32x4 acc[4][4];
#pragma unroll
    for (int m = 0; m < 4; ++m)
#pragma unroll
        for (int n = 0; n < 4; ++n) acc[m][n] = (f32x4){0.f, 0.f, 0.f, 0.f};

    for (int k0 = 0; k0 < KTOT; k0 += 32) {
#pragma unroll
        for (int i = 0; i < 2; ++i) {
            const int g = i * 4 + w;
            gl_lds16(Bg + (long)(n0 + g * 16 + srow) * KTOT + (k0 + scol), &Bs[g * 512]);
        }
        const float* arow = A + (long)(m0 + ar) * KTOT + k0 + ah;
        const float4 x0 = *(const float4*)(arow);
        const float4 x1 = *(const float4*)(arow + 4);
        const float4 x2 = *(const float4*)(arow + 8);
        const float4 x3 = *(const float4*)(arow + 12);
        const float4 ma = *(const float4*)(Mz + k0 + ah);
        const float4 mb = *(const float4*)(Mz + k0 + ah + 4);
        const float4 mc = *(const float4*)(Mz + k0 + ah + 8);
        const float4 md = *(const float4*)(Mz + k0 + ah + 12);
        const float4 ra = *(const float4*)(Rz + k0 + ah);
        const float4 rb = *(const float4*)(Rz + k0 + ah + 4);
        const float4 rc = *(const float4*)(Rz + k0 + ah + 8);
        const float4 rd = *(const float4*)(Rz + k0 + ah + 12);
        const unsigned q0 = pk2(__expf(x0.x - ma.x) * ra.x, __expf(x0.y - ma.y) * ra.y);
        const unsigned q1 = pk2(__expf(x0.z - ma.z) * ra.z, __expf(x0.w - ma.w) * ra.w);
        const unsigned q2 = pk2(__expf(x1.x - mb.x) * rb.x, __expf(x1.y - mb.y) * rb.y);
        const unsigned q3 = pk2(__expf(x1.z - mb.z) * rb.z, __expf(x1.w - mb.w) * rb.w);
        const unsigned q4 = pk2(__expf(x2.x - mc.x) * rc.x, __expf(x2.y - mc.y) * rc.y);
        const unsigned q5 = pk2(__expf(x2.z - mc.z) * rc.z, __expf(x2.w - mc.w) * rc.w);
        const unsigned q6 = pk2(__expf(x3.x - md.x) * rd.x, __expf(x3.y - md.y) * rd.y);
        const unsigned q7 = pk2(__expf(x3.z - md.z) * rd.z, __expf(x3.w - md.w) * rd.w);
        *(uint4*)&As[ar * 32 + ah]     = make_uint4(q0, q1, q2, q3);
        *(uint4*)&As[ar * 32 + ah + 8] = make_uint4(q4, q5, q6, q7);
        __syncthreads();

        bf8_t af[4], bf[4];
#pragma unroll
        for (int m = 0; m < 4; ++m)
            af[m] = *(const bf8_t*)&As[(wr * 64 + m * 16 + l15) * 32 + kg * 8];
#pragma unroll
        for (int n = 0; n < 4; ++n)
            bf[n] = *(const bf8_t*)&Bs[(wc * 64 + n * 16 + l15) * 32 + kg * 8];
#pragma unroll
        for (int m = 0; m < 4; ++m)
#pragma unroll
            for (int n = 0; n < 4; ++n)
                acc[m][n] = __builtin_amdgcn_mfma_f32_16x16x32_bf16(af[m], bf[n], acc[m][n], 0, 0, 0);
        __syncthreads();
    }

    const int orow = wr * 64 + (l >> 4) * 4;
    const int ocol = wc * 64 + l15;
#pragma unroll
    for (int m = 0; m < 4; ++m)
#pragma unroll
        for (int n = 0; n < 4; ++n)
#pragma unroll
            for (int r = 0; r < 4; ++r)
                C[(long)(m0 + orow + m * 16 + r) * D_ + (n0 + ocol + n * 16)] = acc[m][n][r];
}

__global__ __launch_bounds__(256)
void tr2bf_f(const float* __restrict__ src, long sSz, int ldS,
             unsigned short* __restrict__ dst, long sDz, int ldD)
{
    __shared__ unsigned short T[64][65];
    const int t = threadIdx.x;
    const int rr = t >> 2, cc = (t & 3) * 16;
    const int r0 = blockIdx.x * 64, c0 = blockIdx.y * 64, z = blockIdx.z;
    const float* S = src + (long)z * sSz + (long)(r0 + rr) * ldS + c0 + cc;
    const float4 a = *(const float4*)(S);
    const float4 b = *(const float4*)(S + 4);
    const float4 c = *(const float4*)(S + 8);
    const float4 d = *(const float4*)(S + 12);
    unsigned short* Tr = &T[rr][cc];
    Tr[0] = f2bf(a.x); Tr[1] = f2bf(a.y); Tr[2]  = f2bf(a.z); Tr[3]  = f2bf(a.w);
    Tr[4] = f2bf(b.x); Tr[5] = f2bf(b.y); Tr[6]  = f2bf(b.z); Tr[7]  = f2bf(b.w);
    Tr[8] = f2bf(c.x); Tr[9] = f2bf(c.y); Tr[10] = f2bf(c.z); Tr[11] = f2bf(c.w);
    Tr[12] = f2bf(d.x); Tr[13] = f2bf(d.y); Tr[14] = f2bf(d.z); Tr[15] = f2bf(d.w);
    __syncthreads();
    unsigned short v[16];
#pragma unroll
    for (int j = 0; j < 16; ++j) v[j] = T[cc + j][rr];
    unsigned q[8];
#pragma unroll
    for (int j = 0; j < 8; ++j) q[j] = (unsigned)v[2 * j] | ((unsigned)v[2 * j + 1] << 16);
    unsigned short* Dp = dst + (long)z * sDz + (long)(c0 + rr) * ldD + r0 + cc;
    *(uint4*)Dp       = make_uint4(q[0], q[1], q[2], q[3]);
    *(uint4*)(Dp + 8) = make_uint4(q[4], q[5], q[6], q[7]);
}

__global__ __launch_bounds__(256)
void tr2bf_h(const unsigned short* __restrict__ src, long sSz, int ldS,
             unsigned short* __restrict__ dst, long sDz, int ldD)
{
    __shared__ unsigned short T[64][65];
    const int t = threadIdx.x;
    const int rr = t >> 2, cc = (t & 3) * 16;
    const int r0 = blockIdx.x * 64, c0 = blockIdx.y * 64, z = blockIdx.z;
    const unsigned short* S = src + (long)z * sSz + (long)(r0 + rr) * ldS + c0 + cc;
    const uint4 qa = *(const uint4*)(S);
    const uint4 qb = *(const uint4*)(S + 8);
    unsigned short* Tr = &T[rr][cc];
    Tr[0]  = qa.x & 0xFFFF; Tr[1]  = qa.x >> 16; Tr[2]  = qa.y & 0xFFFF; Tr[3]  = qa.y >> 16;
    Tr[4]  = qa.z & 0xFFFF; Tr[5]  = qa.z >> 16; Tr[6]  = qa.w & 0xFFFF; Tr[7]  = qa.w >> 16;
    Tr[8]  = qb.x & 0xFFFF; Tr[9]  = qb.x >> 16; Tr[10] = qb.y & 0xFFFF; Tr[11] = qb.y >> 16;
    Tr[12] = qb.z & 0xFFFF; Tr[13] = qb.z >> 16; Tr[14] = qb.w & 0xFFFF; Tr[15] = qb.w >> 16;
    __syncthreads();
    unsigned short v[16];
#pragma unroll
    for (int j = 0; j < 16; ++j) v[j] = T[cc + j][rr];
    unsigned q[8];
#pragma unroll
    for (int j = 0; j < 8; ++j) q[j] = (unsigned)v[2 * j] | ((unsigned)v[2 * j + 1] << 16);
    unsigned short* Dp = dst + (long)z * sDz + (long)(c0 + rr) * ldD + r0 + cc;
    *(uint4*)Dp       = make_uint4(q[0], q[1], q[2], q[3]);
    *(uint4*)(Dp + 8) = make_uint4(q[4], q[5], q[6], q[7]);
}

__global__ __launch_bounds__(256)
void cvt_bf(const float* __restrict__ src, unsigned short* __restrict__ dst, long n)
{
    const long i = ((long)blockIdx.x * 256 + threadIdx.x) * 8;
    if (i >= n) return;
    const float4 a = *(const float4*)(src + i);
    const float4 b = *(const float4*)(src + i + 4);
    *(uint4*)(dst + i) = make_uint4(pk2(a.x, a.y), pk2(a.z, a.w), pk2(b.x, b.y), pk2(b.z, b.w));
}

// ---------------------------------------------------------------------------
extern "C" void kernel_launch(void* const* d_in, const int* in_sizes, int n_in,
                              void* d_out, int out_size, void* d_ws, size_t ws_size,
                              hipStream_t stream)
{
    (void)in_sizes; (void)n_in; (void)out_size;

    const float* V   = (const float*)d_in[0];
    const float* L   = (const float*)d_in[1];
    const float* w1V = (const float*)d_in[4];
    const float* b1V = (const float*)d_in[5];
    const float* w2V = (const float*)d_in[6];
    const float* b2V = (const float*)d_in[7];
    const float* w1L = (const float*)d_in[8];
    const float* b1L = (const float*)d_in[9];
    const float* w2L = (const float*)d_in[10];
    const float* b2L = (const float*)d_in[11];

    float* outA = (float*)d_out;                      // [B, NV, KTOT]
    float* outV = outA + (size_t)B_ * NV_ * KTOT;     // [B, NV, D]

    unsigned short* w1Vt = (unsigned short*)d_ws;                 // [H][D]
    unsigned short* w2Vt = w1Vt + (size_t)H_ * D_;                // [D][H]
    unsigned short* w1Lt = w2Vt + (size_t)D_ * H_;
    unsigned short* w2Lt = w1Lt + (size_t)H_ * D_;
    unsigned short* pool = w2Lt + (size_t)D_ * H_;

    const size_t perb_us = (size_t)NV_ * D_ + (size_t)NL_ * D_ + (size_t)NV_ * H_ +
                           (size_t)NV_ * D_ + (size_t)NL_ * D_ + (size_t)NV_ * D_ +
                           (size_t)D_ * KTOT;
    const size_t perb_bytes = perb_us * 2 + 2 * (size_t)KTOT * sizeof(float);
    const size_t persist_bytes = (size_t)4 * H_ * D_ * 2;
    const size_t avail = (ws_size > persist_bytes + 256) ? ws_size - persist_bytes - 256 : 0;
    int bc = (int)(avail / perb_bytes);
    if (bc > B_) bc = B_;
    if (bc < 1)  bc = 1;

    unsigned short* Vb  = pool;
    unsigned short* Lb  = Vb  + (size_t)bc * NV_ * D_;
    unsigned short* hid = Lb  + (size_t)bc * NL_ * D_;
    unsigned short* fV  = hid + (size_t)bc * NV_ * H_;
    unsigned short* fLL = fV  + (size_t)bc * NV_ * D_;
    unsigned short* fLV = fLL + (size_t)bc * NL_ * D_;
    unsigned short* KVt = fLV + (size_t)bc * NV_ * D_;
    float* Mst = (float*)(KVt + (size_t)bc * D_ * KTOT);
    float* RS  = Mst + (size_t)bc * KTOT;

    const dim3 blk(256);
    const dim3 blk5(512);

    {
        auto* f0 = gemm256<0>;
        auto* f1 = gemm256<1>;
        hipFuncSetAttribute((const void*)f0, hipFuncAttributeMaxDynamicSharedMemorySize, 131072);
        hipFuncSetAttribute((const void*)f1, hipFuncAttributeMaxDynamicSharedMemorySize, 131072);
    }

    tr2bf_f<<<dim3(D_ / 64, H_ / 64, 1), blk, 0, stream>>>(w1V, 0, H_, w1Vt, 0, D_);
    tr2bf_f<<<dim3(H_ / 64, D_ / 64, 1), blk, 0, stream>>>(w2V, 0, D_, w2Vt, 0, H_);
    tr2bf_f<<<dim3(D_ / 64, H_ / 64, 1), blk, 0, stream>>>(w1L, 0, H_, w1Lt, 0, D_);
    tr2bf_f<<<dim3(H_ / 64, D_ / 64, 1), blk, 0, stream>>>(w2L, 0, D_, w2Lt, 0, H_);

    for (int b0 = 0; b0 < B_; b0 += bc) {
        const int cur = (B_ - b0 < bc) ? (B_ - b0) : bc;

        cvt_bf<<<dim3(cur * NV_ * D_ / 2048), blk, 0, stream>>>(
            V + (size_t)b0 * NV_ * D_, Vb, (long)cur * NV_ * D_);
        cvt_bf<<<dim3(cur * NL_ * D_ / 2048), blk, 0, stream>>>(
            L + (size_t)b0 * NL_ * D_, Lb, (long)cur * NL_ * D_);

        #define G256(M, N) dim3((unsigned)(((N) / 256) * ((M) / 256) * cur)), blk5, 131072, stream
        #define P256(M, N) (N) / 256, (((N) / 256) * ((M) / 256)), \
                           ((((N) / 256) * ((M) / 256)) % 8 == 0 ? (((N) / 256) * ((M) / 256)) / 8 : 0)

        // FFN_V(V) -> fV
        gemm256<0><<<G256(NV_, H_)>>>(Vb, (long)NV_ * D_, D_, w1Vt, 0, D_, b1V,
                                      hid, (long)NV_ * H_, H_, D_, P256(NV_, H_));
        gemm256<1><<<G256(NV_, D_)>>>(hid, (long)NV_ * H_, H_, w2Vt, 0, H_, b2V,
                                      fV, (long)NV_ * D_, D_, H_, P256(NV_, D_));
        // FFN_L(L) -> fLL
        gemm256<0><<<G256(NL_, H_)>>>(Lb, (long)NL_ * D_, D_, w1Lt, 0, D_, b1L,
                                      hid, (long)NV_ * H_, H_, D_, P256(NL_, H_));
        gemm256<1><<<G256(NL_, D_)>>>(hid, (long)NV_ * H_, H_, w2Lt, 0, H_, b2L,
                                      fLL, (long)NL_ * D_, D_, H_, P256(NL_, D_));
        // FFN_L(V) -> fLV
        gemm256<0><<<G256(NV_, H_)>>>(Vb, (long)NV_ * D_, D_, w1Lt, 0, D_, b1L,
                                      hid, (long)NV_ * H_, H_, D_, P256(NV_, H_));
        gemm256<1><<<G256(NV_, D_)>>>(hid, (long)NV_ * H_, H_, w2Lt, 0, H_, b2L,
                                      fLV, (long)NV_ * D_, D_, H_, P256(NV_, D_));
        #undef G256
        #undef P256

        #define GRID(nx, ny) dim3((unsigned)((nx) * (ny) * cur)), blk
        #define SWZ(nx, ny)  (nx), ((nx) * (ny) / 8)
        mgemm<2><<<GRID(NL_ / 128, NV_ / 128), 0, stream>>>(
            fV, (long)NV_ * D_, D_, fLL, (long)NL_ * D_, D_, nullptr, SCALE_,
            outA + (size_t)b0 * NV_ * KTOT, (long)NV_ * KTOT, KTOT, D_,
            SWZ(NL_ / 128, NV_ / 128));
        mgemm<2><<<GRID(NV_ / 128, NV_ / 128), 0, stream>>>(
            fV, (long)NV_ * D_, D_, fLV, (long)NV_ * D_, D_, nullptr, SCALE_,
            outA + (size_t)b0 * NV_ * KTOT + NL_, (long)NV_ * KTOT, KTOT, D_,
            SWZ(NV_ / 128, NV_ / 128));

        tr2bf_h<<<dim3(NL_ / 64, D_ / 64, cur), blk, 0, stream>>>(
            fLL, (long)NL_ * D_, D_, KVt, (long)D_ * KTOT, KTOT);
        tr2bf_h<<<dim3(NV_ / 64, D_ / 64, cur), blk, 0, stream>>>(
            fV, (long)NV_ * D_, D_, KVt + NL_, (long)D_ * KTOT, KTOT);

        col_stats<<<dim3(KTOT / 64, cur), blk, 0, stream>>>(
            outA + (size_t)b0 * NV_ * KTOT, Mst, RS);

        attn_mfma<<<GRID(D_ / 128, NV_ / 128), 0, stream>>>(
            outA + (size_t)b0 * NV_ * KTOT, KVt, Mst, RS,
            outV + (size_t)b0 * NV_ * D_, SWZ(D_ / 128, NV_ / 128));
        #undef GRID
        #undef SWZ
    }
}

// Round 7
// 929.711 us; speedup vs baseline: 9.1326x; 1.0079x over previous
//
#include <hip/hip_runtime.h>
#include <stdint.h>

#define B_   32
#define NV_  512
#define NL_  256
#define D_   1024
#define H_   4096
#define KTOT 768
#define SCALE_ 0.03125f   // 1/sqrt(1024)

typedef __attribute__((ext_vector_type(8))) __bf16 bf8_t;
typedef __attribute__((ext_vector_type(4))) float f32x4;

__device__ __forceinline__ unsigned short f2bf(float f) {
    unsigned u = __float_as_uint(f);
    u += 0x7FFFu + ((u >> 16) & 1u);       // round-to-nearest-even
    return (unsigned short)(u >> 16);
}
__device__ __forceinline__ unsigned pk2(float lo, float hi) {
    return (unsigned)f2bf(lo) | ((unsigned)f2bf(hi) << 16);
}

// async global->LDS, 16B per lane. LDS dest = wave-uniform base + lane*16.
__device__ __forceinline__ void gl_lds16(const void* g, const void* lds) {
    __builtin_amdgcn_global_load_lds(
        (const __attribute__((address_space(1))) unsigned int*)(uintptr_t)g,
        (__attribute__((address_space(3))) unsigned int*)(unsigned)(uintptr_t)lds,
        16, 0, 0);
}

#define SBAR() asm volatile("s_barrier" ::: "memory")
#define VMC4() asm volatile("s_waitcnt vmcnt(4)" ::: "memory")
#define VMC0() asm volatile("s_waitcnt vmcnt(0)" ::: "memory")

// ===========================================================================
// 256x256 bf16 MFMA GEMM — round-7 "2-stretch" schedule.
// 512 thr = 8 waves (2Mx4N); per wave 128x64 out; BK=64; LDS 128K double-buf,
// XOR-swizzled (T2), staged via inverse-swizzled global source (rule #21).
//
// All MFMA operands are PRE-READ into registers, so per K-tile we need only:
//   stretch1: {stage(t+1,A0,A1); [read a1,b1 of tile t] 32 MFMA}  SBAR(A)
//   {stage(t+2,B0,B1); VMC4}  SBAR(B)   <- tile t+1 now fully resident
//   stretch2: {[pre-read a0',b0' of tile t+1] 32 MFMA}            SBAR(C)
// 3 barriers + 1 counted vmcnt per K-tile (was 8+1); all 24 ds_read_b128
// overlap the MFMA windows.  Hazard ledger (verified per-region):
//  - a1/b1 reads (buf) consumed (lgkm) before SBAR(A); B[buf] overwritten
//    only after A; A[buf] overwritten at next tile start (after C).
//  - pre-reads of buf^1 sit after SBAR(B) whose VMC4 drains through (t+1,A1).
//  - vmcnt ledger uniform: outstanding at VMC4 = 12 loads, leaves (t+2,B*)=4.
// Epilogue: LDS-repack full-cacheline bf16 stores (round 5).
// EPI: 0 = relu(acc+bias)->bf16 ; 1 = acc+bias->bf16
// ===========================================================================
template<int EPI>
__global__ __launch_bounds__(512, 1)
void gemm256(const unsigned short* __restrict__ Ab, long sAz, int lda,
             const unsigned short* __restrict__ Bb, long sBz, int ldb,
             const float* __restrict__ bias,
             unsigned short* __restrict__ Cp, long sCz, int ldc, int K,
             int nx, int ntile, int tpc)
{
    extern __shared__ unsigned char lds[];
    unsigned char* const ldsA = lds;            // (buf*2+half)*16384
    unsigned char* const ldsB = lds + 65536;    // (buf*2+half)*16384

    const int tid = threadIdx.x;
    const int w = tid >> 6, l = tid & 63;
    const int wr = w >> 2, wc = w & 3;          // 2 x 4 wave grid
    const int lrow = l & 15;
    const int kg = l >> 4;

    int t_, z;
    {
        const int bid = blockIdx.x;
        if (tpc > 0) { const int r = bid >> 3, c = bid & 7; z = r / tpc; t_ = c * tpc + r % tpc; }
        else         { z = bid / ntile; t_ = bid - z * ntile; }
    }
    const int n0 = (t_ % nx) * 256, m0 = (t_ / nx) * 256;

    const unsigned short* A  = Ab + (long)z * sAz;
    const unsigned short* Bg = Bb + (long)z * sBz;

    const int srow = tid >> 3;                               // row 0..63 in 64-row block
    const int scol = ((tid & 7) * 8) ^ ((srow & 7) << 3);    // inverse-swizzled src col
    const int ntk = K >> 6;                                  // # K-tiles (even)

    const int cs0 = (((l >> 4) * 16)) ^ ((l & 7) << 4);
    const int cs1 = (64 + ((l >> 4) * 16)) ^ ((l & 7) << 4);

    const unsigned short* const sp0 = Bg + (long)(n0 +   0 + srow) * ldb + scol;
    const unsigned short* const sp1 = Bg + (long)(n0 + 128 + srow) * ldb + scol;
    const unsigned short* const sp2 = A  + (long)(m0 +   0 + srow) * lda + scol;
    const unsigned short* const sp3 = A  + (long)(m0 + 128 + srow) * lda + scol;
    const long stB = (long)64 * ldb, stA = (long)64 * lda;

    f32x4 acc[8][4];
#pragma unroll
    for (int i = 0; i < 8; ++i)
#pragma unroll
        for (int j = 0; j < 4; ++j) acc[i][j] = (f32x4){0.f, 0.f, 0.f, 0.f};

#define STG(tau, part) do {                                                   \
        const int buf_ = (tau) & 1;                                           \
        const int kt_ = ((tau) < ntk ? (tau) : ntk - 1);                      \
        if ((part) < 2) {                                                     \
            const unsigned short* s_ = ((part) == 0 ? sp0 : sp1) + (long)kt_ * 64; \
            unsigned char* d_ = ldsB + (buf_ * 2 + (part)) * 16384 + w * 1024;\
            gl_lds16(s_, d_); gl_lds16(s_ + stB, d_ + 8192);                  \
        } else {                                                              \
            const unsigned short* s_ = ((part) == 2 ? sp2 : sp3) + (long)kt_ * 64; \
            unsigned char* d_ = ldsA + (buf_ * 2 + (part) - 2) * 16384 + w * 1024; \
            gl_lds16(s_, d_); gl_lds16(s_ + stA, d_ + 8192);                  \
        } } while (0)

    auto rdA = [&](int buf, int mf, int cs) -> bf8_t {
        return *(const bf8_t*)(ldsA + (buf * 2 + wr) * 16384 + (mf * 16 + lrow) * 128 + cs);
    };
    auto rdB = [&](int buf, int nf, int cs) -> bf8_t {
        return *(const bf8_t*)(ldsB + (buf * 2 + (wc >> 1)) * 16384 +
                               ((wc & 1) * 64 + nf * 16 + lrow) * 128 + cs);
    };

#define MQ(MO, NO, AREG, BREG)                                                \
    _Pragma("unroll")                                                         \
    for (int mf = 0; mf < 4; ++mf)                                            \
    _Pragma("unroll")                                                         \
        for (int nf = 0; nf < 2; ++nf) {                                      \
            acc[(MO)+mf][(NO)+nf] = __builtin_amdgcn_mfma_f32_16x16x32_bf16(  \
                AREG[mf][0], BREG[nf][0], acc[(MO)+mf][(NO)+nf], 0, 0, 0);    \
            acc[(MO)+mf][(NO)+nf] = __builtin_amdgcn_mfma_f32_16x16x32_bf16(  \
                AREG[mf][1], BREG[nf][1], acc[(MO)+mf][(NO)+nf], 0, 0, 0);    \
        }

    // ---- prologue: tile0 all parts + tile1 B halves; tile0 resident;
    //      serial pre-read of tile0's first-quadrant operands ----
    STG(0, 0); STG(0, 1); STG(0, 2); STG(0, 3);
    STG(1, 0); STG(1, 1);
    VMC4();
    SBAR();

    bf8_t a0A[4][2], b0A[2][2];     // even-tile pre-read set
    bf8_t a0B[4][2], b0B[2][2];     // odd-tile pre-read set
    bf8_t a1r[4][2], b1r[2][2];     // shared within-tile set

#pragma unroll
    for (int mf = 0; mf < 4; ++mf) { a0A[mf][0] = rdA(0, mf, cs0);
                                     a0A[mf][1] = rdA(0, mf, cs1); }
#pragma unroll
    for (int nf = 0; nf < 2; ++nf) { b0A[nf][0] = rdB(0, nf, cs0);
                                     b0A[nf][1] = rdB(0, nf, cs1); }

#define TILEX(BUF, A0C, B0C, A0N, B0N, TAU)                                   \
    STG((TAU) + 1, 2); STG((TAU) + 1, 3);                                     \
    __builtin_amdgcn_s_setprio(1);                                            \
    _Pragma("unroll")                                                         \
    for (int mf = 0; mf < 4; ++mf) { a1r[mf][0] = rdA(BUF, mf + 4, cs0);      \
                                     a1r[mf][1] = rdA(BUF, mf + 4, cs1); }    \
    _Pragma("unroll")                                                         \
    for (int nf = 0; nf < 2; ++nf) { b1r[nf][0] = rdB(BUF, nf + 2, cs0);      \
                                     b1r[nf][1] = rdB(BUF, nf + 2, cs1); }    \
    MQ(0, 0, A0C, B0C)                                                        \
    MQ(0, 2, A0C, b1r)                                                        \
    __builtin_amdgcn_s_setprio(0);                                            \
    SBAR();                                   /* A: b1/b0 consumed */         \
    STG((TAU) + 2, 0); STG((TAU) + 2, 1);                                     \
    VMC4();                                                                   \
    SBAR();                                   /* B: tile TAU+1 resident */    \
    __builtin_amdgcn_s_setprio(1);                                            \
    _Pragma("unroll")                                                         \
    for (int mf = 0; mf < 4; ++mf) { A0N[mf][0] = rdA((BUF) ^ 1, mf, cs0);    \
                                     A0N[mf][1] = rdA((BUF) ^ 1, mf, cs1); }  \
    _Pragma("unroll")                                                         \
    for (int nf = 0; nf < 2; ++nf) { B0N[nf][0] = rdB((BUF) ^ 1, nf, cs0);    \
                                     B0N[nf][1] = rdB((BUF) ^ 1, nf, cs1); }  \
    MQ(4, 0, a1r, B0C)                                                        \
    MQ(4, 2, a1r, b1r)                                                        \
    __builtin_amdgcn_s_setprio(0);                                            \
    SBAR();                                   /* C: a1 consumed */

    for (int t = 0; t < ntk; t += 2) {
        TILEX(0, a0A, b0A, a0B, b0B, t)
        TILEX(1, a0B, b0B, a0A, b0A, t + 1)
    }
#undef TILEX
#undef MQ
#undef STG

    // ---- epilogue: per-wave LDS repack -> full-cacheline bf16 stores ----
    VMC0();   // drain garbage tail stages
    SBAR();   // all waves drained -> LDS safe to repurpose

    unsigned short* C = Cp + (long)z * sCz;
    unsigned char* const scr = lds + w * 16384;   // 16 KiB per-wave scratch

    float bv[4];
#pragma unroll
    for (int nf = 0; nf < 4; ++nf) bv[nf] = bias[n0 + wc * 64 + nf * 16 + lrow];

#pragma unroll
    for (int p = 0; p < 2; ++p) {
#pragma unroll
        for (int mf = 0; mf < 4; ++mf)
#pragma unroll
            for (int nf = 0; nf < 4; ++nf)
#pragma unroll
                for (int r = 0; r < 4; ++r) {
                    float v = acc[4 * p + mf][nf][r] + bv[nf];
                    if (EPI == 0) v = fmaxf(v, 0.f);
                    *(unsigned short*)(scr + (mf * 16 + kg * 4 + r) * 136 +
                                       (nf * 16 + lrow) * 2) = f2bf(v);
                }
#pragma unroll
        for (int it = 0; it < 8; ++it) {
            const int rr = it * 8 + (l >> 3);
            const uint4 q = *(const uint4*)(scr + rr * 136 + (l & 7) * 16);
            *(uint4*)(C + (long)(m0 + wr * 128 + p * 64 + rr) * ldc +
                      (n0 + wc * 64 + (l & 7) * 8)) = q;
        }
    }
}

// ===========================================================================
// 128-tile kernels (A_LV/A_VV + attn) — unchanged.
// ===========================================================================
__device__ __forceinline__ void supertile(int nx, int tpc, int& n0, int& m0, int& z)
{
    const int bid = blockIdx.x;
    const int r = bid >> 3, c = bid & 7;
    z = r / tpc;
    const int t = c * tpc + (r % tpc);
    n0 = (t % nx) * 128;
    m0 = (t / nx) * 128;
}

template<int EPI>   // only EPI=2 used: C = acc*scale -> f32
__global__ __launch_bounds__(256)
void mgemm(const unsigned short* __restrict__ Ab, long sAz, int lda,
           const unsigned short* __restrict__ Bb, long sBz, int ldb,
           const float* __restrict__ bias, float scale,
           void* __restrict__ Cp, long sCz, int ldc, int K,
           int nx, int tpc)
{
    __shared__ unsigned short As[128 * 32];
    __shared__ unsigned short Bs[128 * 32];

    const int tid = threadIdx.x;
    const int w = tid >> 6, l = tid & 63;
    const int wr = w >> 1, wc = w & 1;
    const int l15 = l & 15, kg = l >> 4;
    const int srow = l >> 2, scol = (l & 3) * 8;
    int n0, m0, z;
    supertile(nx, tpc, n0, m0, z);

    const unsigned short* A  = Ab + (long)z * sAz;
    const unsigned short* Bg = Bb + (long)z * sBz;

    f32x4 acc[4][4];
#pragma unroll
    for (int m = 0; m < 4; ++m)
#pragma unroll
        for (int n = 0; n < 4; ++n) acc[m][n] = (f32x4){0.f, 0.f, 0.f, 0.f};

    for (int k0 = 0; k0 < K; k0 += 32) {
#pragma unroll
        for (int i = 0; i < 2; ++i) {
            const int g = i * 4 + w;
            gl_lds16(A  + (long)(m0 + g * 16 + srow) * lda + (k0 + scol), &As[g * 512]);
            gl_lds16(Bg + (long)(n0 + g * 16 + srow) * ldb + (k0 + scol), &Bs[g * 512]);
        }
        __syncthreads();

        bf8_t af[4], bf[4];
#pragma unroll
        for (int m = 0; m < 4; ++m)
            af[m] = *(const bf8_t*)&As[(wr * 64 + m * 16 + l15) * 32 + kg * 8];
#pragma unroll
        for (int n = 0; n < 4; ++n)
            bf[n] = *(const bf8_t*)&Bs[(wc * 64 + n * 16 + l15) * 32 + kg * 8];
#pragma unroll
        for (int m = 0; m < 4; ++m)
#pragma unroll
            for (int n = 0; n < 4; ++n)
                acc[m][n] = __builtin_amdgcn_mfma_f32_16x16x32_bf16(af[m], bf[n], acc[m][n], 0, 0, 0);
        __syncthreads();
    }

    const int orow = wr * 64 + (l >> 4) * 4;
    const int ocol = wc * 64 + l15;
    if (EPI == 2) {
        float* C = (float*)Cp + (long)z * sCz;
#pragma unroll
        for (int m = 0; m < 4; ++m)
#pragma unroll
            for (int n = 0; n < 4; ++n)
#pragma unroll
                for (int r = 0; r < 4; ++r)
                    C[(long)(m0 + orow + m * 16 + r) * ldc + (n0 + ocol + n * 16)] =
                        acc[m][n][r] * scale;
    } else {
        unsigned short* C = (unsigned short*)Cp + (long)z * sCz;
#pragma unroll
        for (int n = 0; n < 4; ++n) {
            const float bvv = bias[n0 + ocol + n * 16];
#pragma unroll
            for (int m = 0; m < 4; ++m)
#pragma unroll
                for (int r = 0; r < 4; ++r) {
                    float v = acc[m][n][r] + bvv;
                    if (EPI == 0) v = fmaxf(v, 0.f);
                    C[(long)(m0 + orow + m * 16 + r) * ldc + (n0 + ocol + n * 16)] = f2bf(v);
                }
        }
    }
}

__global__ __launch_bounds__(256)
void col_stats(const float* __restrict__ A, float* __restrict__ Mst, float* __restrict__ RS)
{
    __shared__ float red[4][64];
    const int t = threadIdx.x;
    const int kk = t & 63, ng = t >> 6;
    const int k = blockIdx.x * 64 + kk;
    const int z = blockIdx.y;
    const float* base = A + (long)z * NV_ * KTOT + k;
    float m = -3.0e38f;
    for (int n = ng * 128; n < ng * 128 + 128; ++n) m = fmaxf(m, base[(long)n * KTOT]);
    red[ng][kk] = m;
    __syncthreads();
    m = fmaxf(fmaxf(red[0][kk], red[1][kk]), fmaxf(red[2][kk], red[3][kk]));
    float s = 0.f;
    for (int n = ng * 128; n < ng * 128 + 128; ++n) s += __expf(base[(long)n * KTOT] - m);
    __syncthreads();
    red[ng][kk] = s;
    __syncthreads();
    if (ng == 0) {
        s = red[0][kk] + red[1][kk] + red[2][kk] + red[3][kk];
        Mst[(long)z * KTOT + k] = m;
        RS[(long)z * KTOT + k]  = 1.f / s;
    }
}

__global__ __launch_bounds__(256)
void attn_mfma(const float* __restrict__ Ap, const unsigned short* __restrict__ KVt,
               const float* __restrict__ Mstp, const float* __restrict__ RSp,
               float* __restrict__ Cp, int nx, int tpc)
{
    __shared__ unsigned short As[128 * 32];
    __shared__ unsigned short Bs[128 * 32];

    const int tid = threadIdx.x;
    const int w = tid >> 6, l = tid & 63;
    const int wr = w >> 1, wc = w & 1;
    const int l15 = l & 15, kg = l >> 4;
    const int srow = l >> 2, scol = (l & 3) * 8;
    int n0, m0, z;
    supertile(nx, tpc, n0, m0, z);

    const float* A = Ap + (long)z * NV_ * KTOT;
    const unsigned short* Bg = KVt + (long)z * D_ * KTOT;
    const float* Mz = Mstp + (long)z * KTOT;
    const float* Rz = RSp  + (long)z * KTOT;
    float* C = Cp + (long)z * NV_ * D_;

    const int ar = tid >> 1;
    const int ah = (tid & 1) * 16;

    f32x4 acc[4][4];
#pragma unroll
    for (int m = 0; m < 4; ++m)
#pragma unroll
        for (int n = 0; n < 4; ++n) acc[m][n] = (f32x4){0.f, 0.f, 0.f, 0.f};

    for (int k0 = 0; k0 < KTOT; k0 += 32) {
#pragma unroll
        for (int i = 0; i < 2; ++i) {
            const int g = i * 4 + w;
            gl_lds16(Bg + (long)(n0 + g * 16 + srow) * KTOT + (k0 + scol), &Bs[g * 512]);
        }
        const float* arow = A + (long)(m0 + ar) * KTOT + k0 + ah;
        const float4 x0 = *(const float4*)(arow);
        const float4 x1 = *(const float4*)(arow + 4);
        const float4 x2 = *(const float4*)(arow + 8);
        const float4 x3 = *(const float4*)(arow + 12);
        const float4 ma = *(const float4*)(Mz + k0 + ah);
        const float4 mb = *(const float4*)(Mz + k0 + ah + 4);
        const float4 mc = *(const float4*)(Mz + k0 + ah + 8);
        const float4 md = *(const float4*)(Mz + k0 + ah + 12);
        const float4 ra = *(const float4*)(Rz + k0 + ah);
        const float4 rb = *(const float4*)(Rz + k0 + ah + 4);
        const float4 rc = *(const float4*)(Rz + k0 + ah + 8);
        const float4 rd = *(const float4*)(Rz + k0 + ah + 12);
        const unsigned q0 = pk2(__expf(x0.x - ma.x) * ra.x, __expf(x0.y - ma.y) * ra.y);
        const unsigned q1 = pk2(__expf(x0.z - ma.z) * ra.z, __expf(x0.w - ma.w) * ra.w);
        const unsigned q2 = pk2(__expf(x1.x - mb.x) * rb.x, __expf(x1.y - mb.y) * rb.y);
        const unsigned q3 = pk2(__expf(x1.z - mb.z) * rb.z, __expf(x1.w - mb.w) * rb.w);
        const unsigned q4 = pk2(__expf(x2.x - mc.x) * rc.x, __expf(x2.y - mc.y) * rc.y);
        const unsigned q5 = pk2(__expf(x2.z - mc.z) * rc.z, __expf(x2.w - mc.w) * rc.w);
        const unsigned q6 = pk2(__expf(x3.x - md.x) * rd.x, __expf(x3.y - md.y) * rd.y);
        const unsigned q7 = pk2(__expf(x3.z - md.z) * rd.z, __expf(x3.w - md.w) * rd.w);
        *(uint4*)&As[ar * 32 + ah]     = make_uint4(q0, q1, q2, q3);
        *(uint4*)&As[ar * 32 + ah + 8] = make_uint4(q4, q5, q6, q7);
        __syncthreads();

        bf8_t af[4], bf[4];
#pragma unroll
        for (int m = 0; m < 4; ++m)
            af[m] = *(const bf8_t*)&As[(wr * 64 + m * 16 + l15) * 32 + kg * 8];
#pragma unroll
        for (int n = 0; n < 4; ++n)
            bf[n] = *(const bf8_t*)&Bs[(wc * 64 + n * 16 + l15) * 32 + kg * 8];
#pragma unroll
        for (int m = 0; m < 4; ++m)
#pragma unroll
            for (int n = 0; n < 4; ++n)
                acc[m][n] = __builtin_amdgcn_mfma_f32_16x16x32_bf16(af[m], bf[n], acc[m][n], 0, 0, 0);
        __syncthreads();
    }

    const int orow = wr * 64 + (l >> 4) * 4;
    const int ocol = wc * 64 + l15;
#pragma unroll
    for (int m = 0; m < 4; ++m)
#pragma unroll
        for (int n = 0; n < 4; ++n)
#pragma unroll
            for (int r = 0; r < 4; ++r)
                C[(long)(m0 + orow + m * 16 + r) * D_ + (n0 + ocol + n * 16)] = acc[m][n][r];
}

__global__ __launch_bounds__(256)
void tr2bf_f(const float* __restrict__ src, long sSz, int ldS,
             unsigned short* __restrict__ dst, long sDz, int ldD)
{
    __shared__ unsigned short T[64][65];
    const int t = threadIdx.x;
    const int rr = t >> 2, cc = (t & 3) * 16;
    const int r0 = blockIdx.x * 64, c0 = blockIdx.y * 64, z = blockIdx.z;
    const float* S = src + (long)z * sSz + (long)(r0 + rr) * ldS + c0 + cc;
    const float4 a = *(const float4*)(S);
    const float4 b = *(const float4*)(S + 4);
    const float4 c = *(const float4*)(S + 8);
    const float4 d = *(const float4*)(S + 12);
    unsigned short* Tr = &T[rr][cc];
    Tr[0] = f2bf(a.x); Tr[1] = f2bf(a.y); Tr[2]  = f2bf(a.z); Tr[3]  = f2bf(a.w);
    Tr[4] = f2bf(b.x); Tr[5] = f2bf(b.y); Tr[6]  = f2bf(b.z); Tr[7]  = f2bf(b.w);
    Tr[8] = f2bf(c.x); Tr[9] = f2bf(c.y); Tr[10] = f2bf(c.z); Tr[11] = f2bf(c.w);
    Tr[12] = f2bf(d.x); Tr[13] = f2bf(d.y); Tr[14] = f2bf(d.z); Tr[15] = f2bf(d.w);
    __syncthreads();
    unsigned short v[16];
#pragma unroll
    for (int j = 0; j < 16; ++j) v[j] = T[cc + j][rr];
    unsigned q[8];
#pragma unroll
    for (int j = 0; j < 8; ++j) q[j] = (unsigned)v[2 * j] | ((unsigned)v[2 * j + 1] << 16);
    unsigned short* Dp = dst + (long)z * sDz + (long)(c0 + rr) * ldD + r0 + cc;
    *(uint4*)Dp       = make_uint4(q[0], q[1], q[2], q[3]);
    *(uint4*)(Dp + 8) = make_uint4(q[4], q[5], q[6], q[7]);
}

__global__ __launch_bounds__(256)
void tr2bf_h(const unsigned short* __restrict__ src, long sSz, int ldS,
             unsigned short* __restrict__ dst, long sDz, int ldD)
{
    __shared__ unsigned short T[64][65];
    const int t = threadIdx.x;
    const int rr = t >> 2, cc = (t & 3) * 16;
    const int r0 = blockIdx.x * 64, c0 = blockIdx.y * 64, z = blockIdx.z;
    const unsigned short* S = src + (long)z * sSz + (long)(r0 + rr) * ldS + c0 + cc;
    const uint4 qa = *(const uint4*)(S);
    const uint4 qb = *(const uint4*)(S + 8);
    unsigned short* Tr = &T[rr][cc];
    Tr[0]  = qa.x & 0xFFFF; Tr[1]  = qa.x >> 16; Tr[2]  = qa.y & 0xFFFF; Tr[3]  = qa.y >> 16;
    Tr[4]  = qa.z & 0xFFFF; Tr[5]  = qa.z >> 16; Tr[6]  = qa.w & 0xFFFF; Tr[7]  = qa.w >> 16;
    Tr[8]  = qb.x & 0xFFFF; Tr[9]  = qb.x >> 16; Tr[10] = qb.y & 0xFFFF; Tr[11] = qb.y >> 16;
    Tr[12] = qb.z & 0xFFFF; Tr[13] = qb.z >> 16; Tr[14] = qb.w & 0xFFFF; Tr[15] = qb.w >> 16;
    __syncthreads();
    unsigned short v[16];
#pragma unroll
    for (int j = 0; j < 16; ++j) v[j] = T[cc + j][rr];
    unsigned q[8];
#pragma unroll
    for (int j = 0; j < 8; ++j) q[j] = (unsigned)v[2 * j] | ((unsigned)v[2 * j + 1] << 16);
    unsigned short* Dp = dst + (long)z * sDz + (long)(c0 + rr) * ldD + r0 + cc;
    *(uint4*)Dp       = make_uint4(q[0], q[1], q[2], q[3]);
    *(uint4*)(Dp + 8) = make_uint4(q[4], q[5], q[6], q[7]);
}

__global__ __launch_bounds__(256)
void cvt_bf(const float* __restrict__ src, unsigned short* __restrict__ dst, long n)
{
    const long i = ((long)blockIdx.x * 256 + threadIdx.x) * 8;
    if (i >= n) return;
    const float4 a = *(const float4*)(src + i);
    const float4 b = *(const float4*)(src + i + 4);
    *(uint4*)(dst + i) = make_uint4(pk2(a.x, a.y), pk2(a.z, a.w), pk2(b.x, b.y), pk2(b.z, b.w));
}

// ---------------------------------------------------------------------------
extern "C" void kernel_launch(void* const* d_in, const int* in_sizes, int n_in,
                              void* d_out, int out_size, void* d_ws, size_t ws_size,
                              hipStream_t stream)
{
    (void)in_sizes; (void)n_in; (void)out_size;

    const float* V   = (const float*)d_in[0];
    const float* L   = (const float*)d_in[1];
    const float* w1V = (const float*)d_in[4];
    const float* b1V = (const float*)d_in[5];
    const float* w2V = (const float*)d_in[6];
    const float* b2V = (const float*)d_in[7];
    const float* w1L = (const float*)d_in[8];
    const float* b1L = (const float*)d_in[9];
    const float* w2L = (const float*)d_in[10];
    const float* b2L = (const float*)d_in[11];

    float* outA = (float*)d_out;                      // [B, NV, KTOT]
    float* outV = outA + (size_t)B_ * NV_ * KTOT;     // [B, NV, D]

    unsigned short* w1Vt = (unsigned short*)d_ws;                 // [H][D]
    unsigned short* w2Vt = w1Vt + (size_t)H_ * D_;                // [D][H]
    unsigned short* w1Lt = w2Vt + (size_t)D_ * H_;
    unsigned short* w2Lt = w1Lt + (size_t)H_ * D_;
    unsigned short* pool = w2Lt + (size_t)D_ * H_;

    const size_t perb_us = (size_t)NV_ * D_ + (size_t)NL_ * D_ + (size_t)NV_ * H_ +
                           (size_t)NV_ * D_ + (size_t)NL_ * D_ + (size_t)NV_ * D_ +
                           (size_t)D_ * KTOT;
    const size_t perb_bytes = perb_us * 2 + 2 * (size_t)KTOT * sizeof(float);
    const size_t persist_bytes = (size_t)4 * H_ * D_ * 2;
    const size_t avail = (ws_size > persist_bytes + 256) ? ws_size - persist_bytes - 256 : 0;
    int bc = (int)(avail / perb_bytes);
    if (bc > B_) bc = B_;
    if (bc < 1)  bc = 1;

    unsigned short* Vb  = pool;
    unsigned short* Lb  = Vb  + (size_t)bc * NV_ * D_;
    unsigned short* hid = Lb  + (size_t)bc * NL_ * D_;
    unsigned short* fV  = hid + (size_t)bc * NV_ * H_;
    unsigned short* fLL = fV  + (size_t)bc * NV_ * D_;
    unsigned short* fLV = fLL + (size_t)bc * NL_ * D_;
    unsigned short* KVt = fLV + (size_t)bc * NV_ * D_;
    float* Mst = (float*)(KVt + (size_t)bc * D_ * KTOT);
    float* RS  = Mst + (size_t)bc * KTOT;

    const dim3 blk(256);
    const dim3 blk5(512);

    {
        auto* f0 = gemm256<0>;
        auto* f1 = gemm256<1>;
        hipFuncSetAttribute((const void*)f0, hipFuncAttributeMaxDynamicSharedMemorySize, 131072);
        hipFuncSetAttribute((const void*)f1, hipFuncAttributeMaxDynamicSharedMemorySize, 131072);
    }

    tr2bf_f<<<dim3(D_ / 64, H_ / 64, 1), blk, 0, stream>>>(w1V, 0, H_, w1Vt, 0, D_);
    tr2bf_f<<<dim3(H_ / 64, D_ / 64, 1), blk, 0, stream>>>(w2V, 0, D_, w2Vt, 0, H_);
    tr2bf_f<<<dim3(D_ / 64, H_ / 64, 1), blk, 0, stream>>>(w1L, 0, H_, w1Lt, 0, D_);
    tr2bf_f<<<dim3(H_ / 64, D_ / 64, 1), blk, 0, stream>>>(w2L, 0, D_, w2Lt, 0, H_);

    for (int b0 = 0; b0 < B_; b0 += bc) {
        const int cur = (B_ - b0 < bc) ? (B_ - b0) : bc;

        cvt_bf<<<dim3(cur * NV_ * D_ / 2048), blk, 0, stream>>>(
            V + (size_t)b0 * NV_ * D_, Vb, (long)cur * NV_ * D_);
        cvt_bf<<<dim3(cur * NL_ * D_ / 2048), blk, 0, stream>>>(
            L + (size_t)b0 * NL_ * D_, Lb, (long)cur * NL_ * D_);

        #define G256(M, N) dim3((unsigned)(((N) / 256) * ((M) / 256) * cur)), blk5, 131072, stream
        #define P256(M, N) (N) / 256, (((N) / 256) * ((M) / 256)), \
                           ((((N) / 256) * ((M) / 256)) % 8 == 0 ? (((N) / 256) * ((M) / 256)) / 8 : 0)

        // FFN_V(V) -> fV
        gemm256<0><<<G256(NV_, H_)>>>(Vb, (long)NV_ * D_, D_, w1Vt, 0, D_, b1V,
                                      hid, (long)NV_ * H_, H_, D_, P256(NV_, H_));
        gemm256<1><<<G256(NV_, D_)>>>(hid, (long)NV_ * H_, H_, w2Vt, 0, H_, b2V,
                                      fV, (long)NV_ * D_, D_, H_, P256(NV_, D_));
        // FFN_L(L) -> fLL
        gemm256<0><<<G256(NL_, H_)>>>(Lb, (long)NL_ * D_, D_, w1Lt, 0, D_, b1L,
                                      hid, (long)NV_ * H_, H_, D_, P256(NL_, H_));
        gemm256<1><<<G256(NL_, D_)>>>(hid, (long)NV_ * H_, H_, w2Lt, 0, H_, b2L,
                                      fLL, (long)NL_ * D_, D_, H_, P256(NL_, D_));
        // FFN_L(V) -> fLV
        gemm256<0><<<G256(NV_, H_)>>>(Vb, (long)NV_ * D_, D_, w1Lt, 0, D_, b1L,
                                      hid, (long)NV_ * H_, H_, D_, P256(NV_, H_));
        gemm256<1><<<G256(NV_, D_)>>>(hid, (long)NV_ * H_, H_, w2Lt, 0, H_, b2L,
                                      fLV, (long)NV_ * D_, D_, H_, P256(NV_, D_));
        #undef G256
        #undef P256

        #define GRID(nx, ny) dim3((unsigned)((nx) * (ny) * cur)), blk
        #define SWZ(nx, ny)  (nx), ((nx) * (ny) / 8)
        mgemm<2><<<GRID(NL_ / 128, NV_ / 128), 0, stream>>>(
            fV, (long)NV_ * D_, D_, fLL, (long)NL_ * D_, D_, nullptr, SCALE_,
            outA + (size_t)b0 * NV_ * KTOT, (long)NV_ * KTOT, KTOT, D_,
            SWZ(NL_ / 128, NV_ / 128));
        mgemm<2><<<GRID(NV_ / 128, NV_ / 128), 0, stream>>>(
            fV, (long)NV_ * D_, D_, fLV, (long)NV_ * D_, D_, nullptr, SCALE_,
            outA + (size_t)b0 * NV_ * KTOT + NL_, (long)NV_ * KTOT, KTOT, D_,
            SWZ(NV_ / 128, NV_ / 128));

        tr2bf_h<<<dim3(NL_ / 64, D_ / 64, cur), blk, 0, stream>>>(
            fLL, (long)NL_ * D_, D_, KVt, (long)D_ * KTOT, KTOT);
        tr2bf_h<<<dim3(NV_ / 64, D_ / 64, cur), blk, 0, stream>>>(
            fV, (long)NV_ * D_, D_, KVt + NL_, (long)D_ * KTOT, KTOT);

        col_stats<<<dim3(KTOT / 64, cur), blk, 0, stream>>>(
            outA + (size_t)b0 * NV_ * KTOT, Mst, RS);

        attn_mfma<<<GRID(D_ / 128, NV_ / 128), 0, stream>>>(
            outA + (size_t)b0 * NV_ * KTOT, KVt, Mst, RS,
            outV + (size_t)b0 * NV_ * D_, SWZ(D_ / 128, NV_ / 128));
        #undef GRID
        #undef SWZ
    }
}